// Round 1
// baseline (2423.961 us; speedup 1.0000x reference)
//
#include <hip/hip_runtime.h>
#include <math.h>

#define NHEADS 32
#define D_INNER 2048
#define CONV_DIM 2304
#define D_IN_PROJ 4384
#define POOL_N 50
#define BT 2048

__device__ __forceinline__ float sigmoidf_(float x){ return 1.f/(1.f+expf(-x)); }

// ---------------- RMSNorm on x (D=1024) ----------------
__global__ __launch_bounds__(256) void k_rmsnorm_x(const float* __restrict__ x, const float* __restrict__ w, float* __restrict__ xn){
  int r = blockIdx.x;
  const float* xr = x + (size_t)r*1024;
  float v[4]; float ss=0.f;
  for(int i=0;i<4;i++){ v[i]=xr[threadIdx.x+i*256]; ss+=v[i]*v[i]; }
  __shared__ float red[4];
  for(int off=32;off;off>>=1) ss += __shfl_down(ss,off,64);
  int wid=threadIdx.x>>6, lane=threadIdx.x&63;
  if(lane==0) red[wid]=ss;
  __syncthreads();
  float tot=red[0]+red[1]+red[2]+red[3];
  float rs=rsqrtf(tot*(1.f/1024.f)+1e-5f);
  for(int i=0;i<4;i++){ int c=threadIdx.x+i*256; xn[(size_t)r*1024+c]=v[i]*rs*w[c]; }
}

// ---------------- generic f32 GEMM: C[M,N] = act(A[M,K] @ B[K,N]) ----------------
// BM=BN=64, BK=16, 256 threads, 4x4 per thread. K must be multiple of 16.
__global__ __launch_bounds__(256) void gemm_f32(const float* __restrict__ A, const float* __restrict__ B, float* __restrict__ C,
    int M,int N,int K,int lda,int ldb,int ldc,int act){
  __shared__ float As[16][65];
  __shared__ float Bs[16][65];
  int n0 = blockIdx.x*64, m0 = blockIdx.y*64;
  int tid = threadIdx.x;
  int tx = tid&15, ty = tid>>4;
  float acc[4][4]={};
  for(int k0=0;k0<K;k0+=16){
    for(int i=0;i<4;i++){ int e=tid+i*256; int m=e>>4,k=e&15;
      As[k][m] = (m0+m<M) ? A[(size_t)(m0+m)*lda + k0+k] : 0.f; }
    for(int i=0;i<4;i++){ int e=tid+i*256; int k=e>>6,n=e&63;
      Bs[k][n] = (n0+n<N) ? B[(size_t)(k0+k)*ldb + n0+n] : 0.f; }
    __syncthreads();
    for(int k=0;k<16;k++){
      float a[4],b[4];
      for(int i=0;i<4;i++) a[i]=As[k][ty*4+i];
      for(int j=0;j<4;j++) b[j]=Bs[k][tx*4+j];
      for(int i=0;i<4;i++) for(int j=0;j<4;j++) acc[i][j] += a[i]*b[j];
    }
    __syncthreads();
  }
  for(int i=0;i<4;i++){ int m=m0+ty*4+i; if(m>=M) continue;
    for(int j=0;j<4;j++){ int n=n0+tx*4+j; if(n<N){
      float v=acc[i][j]; if(act==1) v=fmaxf(v,0.f);
      C[(size_t)m*ldc+n]=v; } } }
}

// ---------------- dt = softplus(zxb[:, -32:] + bias) ----------------
__global__ void k_dt(const float* __restrict__ zxb, const float* __restrict__ dt_bias, float* __restrict__ dtb){
  int o = blockIdx.x*256+threadIdx.x; // 2048*32
  int r = o>>5, h = o&31;
  float v = zxb[(size_t)r*D_IN_PROJ + 4352 + h] + dt_bias[h];
  dtb[o] = (v>20.f) ? v : log1pf(expf(v));
}

// ---------------- causal depthwise conv (k=4) + silu ----------------
__global__ void k_conv(const float* __restrict__ zxb, const float* __restrict__ cw, const float* __restrict__ cb, float* __restrict__ xbc){
  int o = blockIdx.x*256+threadIdx.x; // 2048*2304
  int ch = o % CONV_DIM; int rt = o / CONV_DIM;
  int b = rt>>10, t = rt&1023;
  float acc = cb[ch];
  for(int k=0;k<4;k++){
    int tt = t-3+k;
    if(tt>=0) acc += zxb[(size_t)(b*1024+tt)*D_IN_PROJ + 2048 + ch]*cw[ch*4+k];
  }
  xbc[o] = acc*sigmoidf_(acc);
}

// ---------------- G^T per (b,c): Gt[s*256+l] = dot(C[l], B[s]) ----------------
__global__ __launch_bounds__(256) void k_gt(const float* __restrict__ xbc, float* __restrict__ Gt){
  int bc = blockIdx.x >> 8;
  int tile = blockIdx.x & 255;
  int l0 = (tile>>4)<<4, s0 = (tile&15)<<4;
  int b = bc>>2, c = bc&3;
  int row0 = b*1024 + c*256;
  __shared__ float Cs[16][130], Bs2[16][130];
  int tid = threadIdx.x;
  for(int i=0;i<8;i++){ int e=tid+i*256; int rr=e>>7, n=e&127;
    Cs[rr][n]  = xbc[(size_t)(row0+l0+rr)*CONV_DIM + 2176 + n];
    Bs2[rr][n] = xbc[(size_t)(row0+s0+rr)*CONV_DIM + 2048 + n];
  }
  __syncthreads();
  int tx = tid&15, ty = tid>>4;
  float acc=0.f;
  for(int n=0;n<128;n++) acc += Cs[tx][n]*Bs2[ty][n];
  Gt[(size_t)bc*65536 + (size_t)(s0+ty)*256 + (l0+tx)] = acc;
}

// ---------------- SSD per (b,c,h): cumsum, y_diag, states ----------------
__global__ __launch_bounds__(256) void k_ssd1(const float* __restrict__ xbc, const float* __restrict__ dtb,
    const float* __restrict__ A_log, const float* __restrict__ Gt,
    float* __restrict__ ybuf, float* __restrict__ states, float* __restrict__ csb, float* __restrict__ sdA){
  int blk = blockIdx.x;      // (b*4+c)*32+h
  int bc = blk>>5, h = blk&31;
  int b = bc>>2, c = bc&3;
  int row0 = b*1024 + c*256;
  int tid = threadIdx.x;
  __shared__ float cs[256], dts[256];
  __shared__ float xd[256*32];
  float dtv = dtb[(size_t)(row0+tid)*32 + h];
  float Ah = -expf(A_log[h]);
  dts[tid]=dtv;
  cs[tid]=dtv*Ah;
  __syncthreads();
  for(int o=1;o<256;o<<=1){
    float add = (tid>=o)? cs[tid-o] : 0.f;
    __syncthreads();
    cs[tid] += add;
    __syncthreads();
  }
  float csl = cs[tid];
  float cslast = cs[255];
  csb[blk*256+tid] = csl;
  if(tid==0) sdA[blk] = cslast;
  const float* gt = Gt + (size_t)bc*65536;
  for(int ph=0; ph<2; ph++){
    __syncthreads();
    for(int i=0;i<32;i++){
      int e = tid + i*256; int l = e>>5, pp = e&31;
      xd[e] = xbc[(size_t)(row0+l)*CONV_DIM + h*64 + ph*32 + pp] * dts[l];
    }
    __syncthreads();
    // y_diag
    float acc[32];
    for(int p=0;p<32;p++) acc[p]=0.f;
    for(int s=0;s<=tid;s++){
      float m = gt[(size_t)s*256+tid] * expf(csl - cs[s]);
      const float* xr = &xd[s*32];
      for(int p=0;p<32;p++) acc[p] += m*xr[p];
    }
    {
      size_t base = (size_t)(row0+tid)*2048 + h*64 + ph*32;
      for(int p=0;p<32;p++) ybuf[base+p] = acc[p];
    }
    // states
    int n = tid&127, pg = tid>>7;
    float acc2[16];
    for(int j=0;j<16;j++) acc2[j]=0.f;
    for(int l=0;l<256;l++){
      float w = xbc[(size_t)(row0+l)*CONV_DIM + 2048 + n] * expf(cslast - cs[l]);
      const float* xr = &xd[l*32 + pg*16];
      for(int j=0;j<16;j++) acc2[j] += w*xr[j];
    }
    size_t sb = (size_t)blk*8192;
    for(int j=0;j<16;j++) states[sb + (size_t)(ph*32+pg*16+j)*128 + n] = acc2[j];
  }
}

// ---------------- chunk scan over c=0..3 ----------------
__global__ __launch_bounds__(256) void k_ssd2(const float* __restrict__ states, const float* __restrict__ sdA, float* __restrict__ prevb){
  int blk = blockIdx.x; // b*32+h
  int b = blk>>5, h = blk&31;
  int tid=threadIdx.x;
  float run[32];
  for(int i=0;i<32;i++) run[i]=0.f;
  for(int c=0;c<4;c++){
    int sblk = (b*4+c)*32+h;
    size_t base = (size_t)sblk*8192;
    float dec = expf(sdA[sblk]);
    for(int i=0;i<32;i++){
      int e = i*256+tid;
      prevb[base+e] = run[i];
      run[i] = (run[i] + states[base+e]) * dec;
    }
  }
}

// ---------------- y_off + xs*D, accumulate into ybuf ----------------
__global__ __launch_bounds__(256) void k_ssd3(const float* __restrict__ xbc, const float* __restrict__ csb,
    const float* __restrict__ prevb, const float* __restrict__ Dp, float* __restrict__ ybuf){
  int blk = blockIdx.x; int bc = blk>>5, h = blk&31; int b=bc>>2, c=bc&3;
  int row0 = b*1024+c*256;
  int tid = threadIdx.x;
  __shared__ float prevs[8192];
  for(int i=0;i<32;i++) prevs[i*256+tid] = prevb[(size_t)blk*8192 + i*256+tid];
  __syncthreads();
  float acc[64];
  for(int p=0;p<64;p++) acc[p]=0.f;
  const float* crow = xbc + (size_t)(row0+tid)*CONV_DIM + 2176;
  for(int n=0;n<128;n++){
    float cv = crow[n];
    for(int p=0;p<64;p++) acc[p] += cv * prevs[p*128+n];
  }
  float e = expf(csb[blk*256+tid]);
  float Dh = Dp[h];
  const float* xsr = xbc + (size_t)(row0+tid)*CONV_DIM + h*64;
  size_t yb = (size_t)(row0+tid)*2048 + h*64;
  for(int p=0;p<64;p++) ybuf[yb+p] += e*acc[p] + xsr[p]*Dh;
}

// ---------------- y = rmsnorm(y * silu(z)) in place (D=2048) ----------------
__global__ __launch_bounds__(256) void k_gate_norm(float* __restrict__ y, const float* __restrict__ zxb, const float* __restrict__ w){
  int r = blockIdx.x;
  const float* zr = zxb + (size_t)r*D_IN_PROJ;
  float* yr = y + (size_t)r*2048;
  float v[8]; float ss=0.f;
  for(int i=0;i<8;i++){ int c=threadIdx.x+i*256; float z=zr[c]; float g=yr[c]*(z*sigmoidf_(z)); v[i]=g; ss+=g*g; }
  __shared__ float red[4];
  for(int off=32;off;off>>=1) ss += __shfl_down(ss,off,64);
  int wid=threadIdx.x>>6, lane=threadIdx.x&63;
  if(lane==0) red[wid]=ss;
  __syncthreads();
  float tot=red[0]+red[1]+red[2]+red[3];
  float rs=rsqrtf(tot*(1.f/2048.f)+1e-5f);
  for(int i=0;i<8;i++){ int c=threadIdx.x+i*256; yr[c]=v[i]*rs*w[c]; }
}

// ---------------- scorer stage 2: sigmoid(h1 @ w2) ----------------
__global__ void k_scorer2(const float* __restrict__ h1, const float* __restrict__ w2, float* __restrict__ scores){
  int r = blockIdx.x; int lane = threadIdx.x; // 64 threads
  float s=0.f;
  for(int k=0;k<4;k++){ int c=lane+k*64; s += h1[(size_t)r*256+c]*w2[c]; }
  for(int off=32;off;off>>=1) s += __shfl_down(s,off,64);
  if(lane==0) scores[r]=sigmoidf_(s);
}

// ---------------- serial pool scan (1 wave) ----------------
__global__ void k_pool(const float* __restrict__ scores, const float* __restrict__ summ,
                       float* __restrict__ poolws, float* __restrict__ priosws, int* __restrict__ countws){
  __shared__ float pool[POOL_N*64];
  int lane = threadIdx.x;
  for(int i=lane;i<POOL_N*64;i+=64) pool[i]=0.f;
  float prio = 0.f;
  int count = 0;
  for(int i=0;i<BT;i++){
    float sc = scores[i];
    float sv = summ[(size_t)i*64 + lane];
    if(sc > 0.5f){
      bool not_full = count < POOL_N;
      float v = (lane < POOL_N)? prio : INFINITY;
      int idx = lane;
      for(int off=32;off;off>>=1){
        float ov = __shfl_xor(v,off,64);
        int oi = __shfl_xor(idx,off,64);
        if(ov < v || (ov==v && oi<idx)){ v=ov; idx=oi; }
      }
      int widx = not_full ? count : idx;
      bool write = not_full || (sc > v);
      if(write){
        pool[widx*64 + lane] = sv;
        if(lane == widx) prio = sc;
      }
      if(not_full) count++;
    }
  }
  for(int i=0;i<POOL_N;i++) poolws[i*64+lane] = pool[i*64+lane];
  if(lane < POOL_N) priosws[lane]=prio;
  if(lane==0) countws[0]=count;
}

// ---------------- mean(scores) & cond flag ----------------
__global__ __launch_bounds__(256) void k_flags(const float* __restrict__ scores, const int* __restrict__ counti, float* __restrict__ condf){
  float s=0.f;
  for(int i=threadIdx.x;i<BT;i+=256) s += scores[i];
  __shared__ float red[4];
  for(int off=32;off;off>>=1) s += __shfl_down(s,off,64);
  int wid=threadIdx.x>>6, lane=threadIdx.x&63;
  if(lane==0) red[wid]=s;
  __syncthreads();
  if(threadIdx.x==0){
    float mean=(red[0]+red[1]+red[2]+red[3])*(1.f/2048.f);
    condf[0] = (mean>0.3f && counti[0]>0)? 1.f : 0.f;
  }
}

// ---------------- kkT[j*64+p] = (pool @ k_w)[p][j] ----------------
__global__ void k_kk(const float* __restrict__ pool, const float* __restrict__ k_w, float* __restrict__ kkT){
  int o = blockIdx.x*256+threadIdx.x;
  if(o >= 64*POOL_N) return;
  int j = o/POOL_N, p = o%POOL_N;
  float s=0.f;
  for(int k=0;k<64;k++) s += pool[p*64+k]*k_w[k*64+j];
  kkT[j*64+p]=s;
}

// ---------------- vv = pool @ v_w (50x1024) ----------------
__global__ void k_vv(const float* __restrict__ pool, const float* __restrict__ v_w, float* __restrict__ vv){
  int o = blockIdx.x*256+threadIdx.x;
  if(o >= POOL_N*1024) return;
  int p = o>>10, d = o&1023;
  float s=0.f;
  for(int k=0;k<64;k++) s += pool[p*64+k]*v_w[(size_t)k*1024+d];
  vv[o]=s;
}

// ---------------- retrieval: softmax(q·kkT/4, masked) @ vv ----------------
__global__ __launch_bounds__(256) void k_retr(const float* __restrict__ qb, const float* __restrict__ kkT,
   const float* __restrict__ vv, const int* __restrict__ counti, float* __restrict__ retr){
  int r = blockIdx.x;
  __shared__ float qs[64];
  __shared__ float probs[64];
  int tid = threadIdx.x;
  if(tid<64) qs[tid] = qb[(size_t)r*64+tid];
  __syncthreads();
  int count = counti[0];
  if(tid<64){
    float logit = -1e9f;
    if(tid < POOL_N && tid < count){
      float s=0.f;
      for(int k=0;k<64;k++) s += qs[k]*kkT[k*64+tid];
      logit = s*0.25f;
    }
    float m = logit;
    for(int off=32;off;off>>=1) m = fmaxf(m, __shfl_xor(m,off,64));
    float e = expf(logit-m);
    float sum = e;
    for(int off=32;off;off>>=1) sum += __shfl_xor(sum,off,64);
    probs[tid] = e/sum;
  }
  __syncthreads();
  for(int d=tid; d<1024; d+=256){
    float acc=0.f;
    for(int p=0;p<POOL_N;p++) acc += probs[p]*vv[(size_t)p*1024+d];
    retr[(size_t)r*1024+d]=acc;
  }
}

// ---------------- concat [yout, retr] ----------------
__global__ void k_concat(const float* __restrict__ yout, const float* __restrict__ retr, float* __restrict__ cc){
  int o = blockIdx.x*256+threadIdx.x; // 2048*2048
  int r = o>>11, c2 = o&2047;
  cc[o] = (c2<1024)? yout[(size_t)r*1024+c2] : retr[(size_t)r*1024+(c2-1024)];
}

// ---------------- out = x + yout + cond*sigmoid(g)*retr ----------------
__global__ void k_final(const float* __restrict__ x, const float* __restrict__ yout, const float* __restrict__ g,
   const float* __restrict__ retr, const float* __restrict__ condf, float* __restrict__ out){
  int o = blockIdx.x*256+threadIdx.x; // 2048*1024
  float gv = sigmoidf_(g[o]);
  out[o] = x[o] + yout[o] + condf[0]*gv*retr[o];
}

static inline void gemm(hipStream_t s, const float*A,const float*B,float*C,int M,int N,int K,int lda,int ldb,int ldc,int act){
  dim3 g((N+63)/64,(M+63)/64);
  hipLaunchKernelGGL(gemm_f32,g,dim3(256),0,s,A,B,C,M,N,K,lda,ldb,ldc,act);
}

extern "C" void kernel_launch(void* const* d_in, const int* in_sizes, int n_in,
                              void* d_out, int out_size, void* d_ws, size_t ws_size,
                              hipStream_t stream) {
  const float* x        = (const float*)d_in[0];
  const float* norm_w   = (const float*)d_in[1];
  const float* in_proj_w= (const float*)d_in[2];
  const float* conv_w   = (const float*)d_in[3];
  const float* conv_b   = (const float*)d_in[4];
  const float* dt_bias  = (const float*)d_in[5];
  const float* A_log    = (const float*)d_in[6];
  const float* Dp       = (const float*)d_in[7];
  const float* ssm_norm_w=(const float*)d_in[8];
  const float* out_proj_w=(const float*)d_in[9];
  const float* scorer_w1= (const float*)d_in[10];
  const float* scorer_w2= (const float*)d_in[11];
  const float* summ_w   = (const float*)d_in[12];
  const float* q_w      = (const float*)d_in[13];
  const float* k_w      = (const float*)d_in[14];
  const float* v_w      = (const float*)d_in[15];
  const float* gate_w   = (const float*)d_in[16];
  float* out = (float*)d_out;

  float* w = (float*)d_ws;
  size_t off = 0;
  auto F = [&](size_t n){ float* p = w+off; off += (n+63)&~(size_t)63; return p; };
  float* xn    = F((size_t)2048*1024);
  float* zxb   = F((size_t)2048*D_IN_PROJ);
  float* dtb   = F((size_t)2048*32);
  float* xbc   = F((size_t)2048*CONV_DIM);
  float* Gt    = F((size_t)8*65536);
  float* csb   = F((size_t)256*256);
  float* sdA   = F(256);
  float* states= F((size_t)256*8192);
  float* prevb = F((size_t)256*8192);
  float* ybuf  = F((size_t)2048*2048);
  float* yout  = F((size_t)2048*1024);
  float* h1    = F((size_t)2048*256);
  float* scores= F(2048);
  float* summ  = F((size_t)2048*64);
  float* qb    = F((size_t)2048*64);
  float* poolb = F(64*64);
  float* prios = F(64);
  float* miscf = F(64);
  int*   counti= (int*)F(64);
  float* kkT   = F(64*64);
  float* vvb   = F((size_t)64*1024);
  // aliased buffers (lifetimes disjoint):
  float* retr   = xn;    // free after in_proj GEMM
  float* concat = zxb;   // free after gate_norm
  float* gbuf   = prevb; // free after ssd3

  k_rmsnorm_x<<<2048,256,0,stream>>>(x, norm_w, xn);
  gemm(stream, xn, in_proj_w, zxb, 2048, D_IN_PROJ, 1024, 1024, D_IN_PROJ, D_IN_PROJ, 0);
  k_dt<<<256,256,0,stream>>>(zxb, dt_bias, dtb);
  k_conv<<<18432,256,0,stream>>>(zxb, conv_w, conv_b, xbc);
  k_gt<<<2048,256,0,stream>>>(xbc, Gt);
  k_ssd1<<<256,256,0,stream>>>(xbc, dtb, A_log, Gt, ybuf, states, csb, sdA);
  k_ssd2<<<64,256,0,stream>>>(states, sdA, prevb);
  k_ssd3<<<256,256,0,stream>>>(xbc, csb, prevb, Dp, ybuf);
  k_gate_norm<<<2048,256,0,stream>>>(ybuf, zxb, ssm_norm_w);
  gemm(stream, ybuf, out_proj_w, yout, 2048, 1024, 2048, 2048, 1024, 1024, 0);
  gemm(stream, yout, scorer_w1, h1, 2048, 256, 1024, 1024, 256, 256, 1);
  k_scorer2<<<2048,64,0,stream>>>(h1, scorer_w2, scores);
  gemm(stream, yout, summ_w, summ, 2048, 64, 1024, 1024, 64, 64, 0);
  gemm(stream, yout, q_w, qb, 2048, 64, 1024, 1024, 64, 64, 0);
  k_pool<<<1,64,0,stream>>>(scores, summ, poolb, prios, counti);
  k_flags<<<1,256,0,stream>>>(scores, counti, miscf);
  k_kk<<<(64*POOL_N+255)/256,256,0,stream>>>(poolb, k_w, kkT);
  k_vv<<<(POOL_N*1024+255)/256,256,0,stream>>>(poolb, v_w, vvb);
  k_retr<<<2048,256,0,stream>>>(qb, kkT, vvb, counti, retr);
  k_concat<<<16384,256,0,stream>>>(yout, retr, concat);
  gemm(stream, concat, gate_w, gbuf, 2048, 1024, 2048, 2048, 1024, 1024, 0);
  k_final<<<8192,256,0,stream>>>(x, yout, gbuf, retr, miscf, out);
  (void)in_sizes; (void)n_in; (void)out_size; (void)ws_size;
}

// Round 3
// 1526.340 us; speedup vs baseline: 1.5881x; 1.5881x over previous
//
#include <hip/hip_runtime.h>
#include <math.h>

#define NHEADS 32
#define D_INNER 2048
#define CONV_DIM 2304
#define D_IN_PROJ 4384
#define POOL_N 50
#define BT 2048

typedef __attribute__((ext_vector_type(8))) short short8;
typedef __attribute__((ext_vector_type(4))) float f32x4;

__device__ __forceinline__ float sigmoidf_(float x){ return 1.f/(1.f+expf(-x)); }
__device__ __forceinline__ ushort f2bf(float f){
  union{float f; unsigned u;} v; v.f=f;
  unsigned r = v.u + 0x7fffu + ((v.u>>16)&1u);
  return (ushort)(r>>16);
}

// ---------------- RMSNorm on x (D=1024) -> bf16 ----------------
__global__ __launch_bounds__(256) void k_rmsnorm_x(const float* __restrict__ x, const float* __restrict__ w, ushort* __restrict__ xn){
  int r = blockIdx.x;
  const float* xr = x + (size_t)r*1024;
  float v[4]; float ss=0.f;
  for(int i=0;i<4;i++){ v[i]=xr[threadIdx.x+i*256]; ss+=v[i]*v[i]; }
  __shared__ float red[4];
  for(int off=32;off;off>>=1) ss += __shfl_down(ss,off,64);
  int wid=threadIdx.x>>6, lane=threadIdx.x&63;
  if(lane==0) red[wid]=ss;
  __syncthreads();
  float tot=red[0]+red[1]+red[2]+red[3];
  float rs=rsqrtf(tot*(1.f/1024.f)+1e-5f);
  for(int i=0;i<4;i++){ int c=threadIdx.x+i*256; xn[(size_t)r*1024+c]=f2bf(v[i]*rs*w[c]); }
}

// ---------------- transpose + cvt: src f32 [R][C] -> dst bf16 [C][R] ----------------
__global__ __launch_bounds__(256) void k_transpose_cvt(const float* __restrict__ src, ushort* __restrict__ dst, int R, int C){
  __shared__ float tile[32][33];
  int c0 = blockIdx.x*32, r0 = blockIdx.y*32;
  int tx = threadIdx.x&31, ty = threadIdx.x>>5;
  for(int i=0;i<4;i++){ int r = r0+ty+i*8; tile[ty+i*8][tx] = src[(size_t)r*C + c0+tx]; }
  __syncthreads();
  for(int i=0;i<4;i++){ int c = c0+ty+i*8; dst[(size_t)c*R + r0+tx] = f2bf(tile[tx][ty+i*8]); }
}

// ---------------- f32 -> bf16 elementwise (n multiple of 4) ----------------
__global__ void k_cvt_bf16(const float* __restrict__ s, ushort* __restrict__ d, int n4){
  int i = blockIdx.x*256+threadIdx.x;
  if(i<n4){
    float4 v = ((const float4*)s)[i];
    ushort4 o; o.x=f2bf(v.x); o.y=f2bf(v.y); o.z=f2bf(v.z); o.w=f2bf(v.w);
    ((ushort4*)d)[i] = o;
  }
}

// ---------------- bf16 MFMA GEMM: C[M,N] f32 = A[M,K]bf16 @ Bt[N,K]bf16^T ----------------
// 128x128 tile, BK=32, 256 threads (4 waves), each wave 64x64 via 4x4 frags of 16x16x32.
// Each thread stages 2 rows x 16B per operand (full 128x32 tile).
__global__ __launch_bounds__(256) void gemm_bf16(const ushort* __restrict__ A, const ushort* __restrict__ Bt,
    float* __restrict__ C, int M, int N, int K, int act){
  __shared__ __align__(16) ushort As[128*32];
  __shared__ __align__(16) ushort Bs[128*32];
  int n0 = blockIdx.x*128, m0 = blockIdx.y*128;
  int tid = threadIdx.x;
  int lane = tid&63, w = tid>>6;
  int wr = (w>>1)*64, wc = (w&1)*64;
  f32x4 acc[4][4];
  for(int i=0;i<4;i++)for(int j=0;j<4;j++)acc[i][j]=(f32x4){0.f,0.f,0.f,0.f};
  int srow = tid>>2, skb = (tid&3)*8;
  const ushort* Ap0 = A + (size_t)(m0+srow)*K + skb;
  const ushort* Ap1 = A + (size_t)(m0+srow+64)*K + skb;
  bool bv0 = (n0+srow) < N, bv1 = (n0+srow+64) < N;
  const ushort* Bp0 = Bt + (size_t)(bv0 ? (n0+srow)    : 0)*K + skb;
  const ushort* Bp1 = Bt + (size_t)(bv1 ? (n0+srow+64) : 0)*K + skb;
  int fr = lane&15, fko = (lane>>4)*8;
  for(int k0=0;k0<K;k0+=32){
    uint4 a0 = *(const uint4*)(Ap0 + k0);
    uint4 a1 = *(const uint4*)(Ap1 + k0);
    uint4 b0 = bv0 ? *(const uint4*)(Bp0 + k0) : make_uint4(0u,0u,0u,0u);
    uint4 b1 = bv1 ? *(const uint4*)(Bp1 + k0) : make_uint4(0u,0u,0u,0u);
    *(uint4*)(As + srow*32 + skb)      = a0;
    *(uint4*)(As + (srow+64)*32 + skb) = a1;
    *(uint4*)(Bs + srow*32 + skb)      = b0;
    *(uint4*)(Bs + (srow+64)*32 + skb) = b1;
    __syncthreads();
    short8 af[4], bfr[4];
    for(int i=0;i<4;i++) af[i]  = *(const short8*)(As + (wr+i*16+fr)*32 + fko);
    for(int j=0;j<4;j++) bfr[j] = *(const short8*)(Bs + (wc+j*16+fr)*32 + fko);
    for(int i=0;i<4;i++)
      for(int j=0;j<4;j++)
        acc[i][j] = __builtin_amdgcn_mfma_f32_16x16x32_bf16(af[i], bfr[j], acc[i][j], 0,0,0);
    __syncthreads();
  }
  int rbase = m0 + wr + (lane>>4)*4;
  for(int i=0;i<4;i++){
    for(int j=0;j<4;j++){
      int col = n0 + wc + j*16 + fr;
      if(col < N){
        for(int r=0;r<4;r++){
          float v = acc[i][j][r];
          if(act) v = fmaxf(v,0.f);
          C[(size_t)(rbase + i*16 + r)*N + col] = v;
        }
      }
    }
  }
}

// ---------------- generic f32 GEMM (kept for scorer stage-1) ----------------
__global__ __launch_bounds__(256) void gemm_f32(const float* __restrict__ A, const float* __restrict__ B, float* __restrict__ C,
    int M,int N,int K,int lda,int ldb,int ldc,int act){
  __shared__ float As[16][65];
  __shared__ float Bs[16][65];
  int n0 = blockIdx.x*64, m0 = blockIdx.y*64;
  int tid = threadIdx.x;
  int tx = tid&15, ty = tid>>4;
  float acc[4][4]={};
  for(int k0=0;k0<K;k0+=16){
    for(int i=0;i<4;i++){ int e=tid+i*256; int m=e>>4,k=e&15;
      As[k][m] = (m0+m<M) ? A[(size_t)(m0+m)*lda + k0+k] : 0.f; }
    for(int i=0;i<4;i++){ int e=tid+i*256; int k=e>>6,n=e&63;
      Bs[k][n] = (n0+n<N) ? B[(size_t)(k0+k)*ldb + n0+n] : 0.f; }
    __syncthreads();
    for(int k=0;k<16;k++){
      float a[4],b[4];
      for(int i=0;i<4;i++) a[i]=As[k][ty*4+i];
      for(int j=0;j<4;j++) b[j]=Bs[k][tx*4+j];
      for(int i=0;i<4;i++) for(int j=0;j<4;j++) acc[i][j] += a[i]*b[j];
    }
    __syncthreads();
  }
  for(int i=0;i<4;i++){ int m=m0+ty*4+i; if(m>=M) continue;
    for(int j=0;j<4;j++){ int n=n0+tx*4+j; if(n<N){
      float v=acc[i][j]; if(act==1) v=fmaxf(v,0.f);
      C[(size_t)m*ldc+n]=v; } } }
}

// ---------------- dt = softplus(zxb[:, -32:] + bias) ----------------
__global__ void k_dt(const float* __restrict__ zxb, const float* __restrict__ dt_bias, float* __restrict__ dtb){
  int o = blockIdx.x*256+threadIdx.x; // 2048*32
  int r = o>>5, h = o&31;
  float v = zxb[(size_t)r*D_IN_PROJ + 4352 + h] + dt_bias[h];
  dtb[o] = (v>20.f) ? v : log1pf(expf(v));
}

// ---------------- causal depthwise conv (k=4) + silu ----------------
__global__ void k_conv(const float* __restrict__ zxb, const float* __restrict__ cw, const float* __restrict__ cb, float* __restrict__ xbc){
  int o = blockIdx.x*256+threadIdx.x; // 2048*2304
  int ch = o % CONV_DIM; int rt = o / CONV_DIM;
  int b = rt>>10, t = rt&1023;
  float acc = cb[ch];
  for(int k=0;k<4;k++){
    int tt = t-3+k;
    if(tt>=0) acc += zxb[(size_t)(b*1024+tt)*D_IN_PROJ + 2048 + ch]*cw[ch*4+k];
  }
  xbc[o] = acc*sigmoidf_(acc);
}

// ---------------- G^T per (b,c): Gt[s*256+l] = dot(C[l], B[s]) ----------------
__global__ __launch_bounds__(256) void k_gt(const float* __restrict__ xbc, float* __restrict__ Gt){
  int bc = blockIdx.x >> 8;
  int tile = blockIdx.x & 255;
  int l0 = (tile>>4)<<4, s0 = (tile&15)<<4;
  int b = bc>>2, c = bc&3;
  int row0 = b*1024 + c*256;
  __shared__ float Cs[16][130], Bs2[16][130];
  int tid = threadIdx.x;
  for(int i=0;i<8;i++){ int e=tid+i*256; int rr=e>>7, n=e&127;
    Cs[rr][n]  = xbc[(size_t)(row0+l0+rr)*CONV_DIM + 2176 + n];
    Bs2[rr][n] = xbc[(size_t)(row0+s0+rr)*CONV_DIM + 2048 + n];
  }
  __syncthreads();
  int tx = tid&15, ty = tid>>4;
  float acc=0.f;
  for(int n=0;n<128;n++) acc += Cs[tx][n]*Bs2[ty][n];
  Gt[(size_t)bc*65536 + (size_t)(s0+ty)*256 + (l0+tx)] = acc;
}

// ---------------- SSD per (b,c,h): cumsum, y_diag, states ----------------
__global__ __launch_bounds__(256) void k_ssd1(const float* __restrict__ xbc, const float* __restrict__ dtb,
    const float* __restrict__ A_log, const float* __restrict__ Gt,
    float* __restrict__ ybuf, float* __restrict__ states, float* __restrict__ csb, float* __restrict__ sdA){
  int blk = blockIdx.x;      // (b*4+c)*32+h
  int bc = blk>>5, h = blk&31;
  int b = bc>>2, c = bc&3;
  int row0 = b*1024 + c*256;
  int tid = threadIdx.x;
  __shared__ float cs[256], dts[256];
  __shared__ float xd[256*32];
  float dtv = dtb[(size_t)(row0+tid)*32 + h];
  float Ah = -expf(A_log[h]);
  dts[tid]=dtv;
  cs[tid]=dtv*Ah;
  __syncthreads();
  for(int o=1;o<256;o<<=1){
    float add = (tid>=o)? cs[tid-o] : 0.f;
    __syncthreads();
    cs[tid] += add;
    __syncthreads();
  }
  float csl = cs[tid];
  float cslast = cs[255];
  csb[blk*256+tid] = csl;
  if(tid==0) sdA[blk] = cslast;
  const float* gt = Gt + (size_t)bc*65536;
  for(int ph=0; ph<2; ph++){
    __syncthreads();
    for(int i=0;i<32;i++){
      int e = tid + i*256; int l = e>>5, pp = e&31;
      xd[e] = xbc[(size_t)(row0+l)*CONV_DIM + h*64 + ph*32 + pp] * dts[l];
    }
    __syncthreads();
    // y_diag
    float acc[32];
    for(int p=0;p<32;p++) acc[p]=0.f;
    for(int s=0;s<=tid;s++){
      float m = gt[(size_t)s*256+tid] * expf(csl - cs[s]);
      const float* xr = &xd[s*32];
      for(int p=0;p<32;p++) acc[p] += m*xr[p];
    }
    {
      size_t base = (size_t)(row0+tid)*2048 + h*64 + ph*32;
      for(int p=0;p<32;p++) ybuf[base+p] = acc[p];
    }
    // states
    int n = tid&127, pg = tid>>7;
    float acc2[16];
    for(int j=0;j<16;j++) acc2[j]=0.f;
    for(int l=0;l<256;l++){
      float w = xbc[(size_t)(row0+l)*CONV_DIM + 2048 + n] * expf(cslast - cs[l]);
      const float* xr = &xd[l*32 + pg*16];
      for(int j=0;j<16;j++) acc2[j] += w*xr[j];
    }
    size_t sb = (size_t)blk*8192;
    for(int j=0;j<16;j++) states[sb + (size_t)(ph*32+pg*16+j)*128 + n] = acc2[j];
  }
}

// ---------------- chunk scan over c=0..3 ----------------
__global__ __launch_bounds__(256) void k_ssd2(const float* __restrict__ states, const float* __restrict__ sdA, float* __restrict__ prevb){
  int blk = blockIdx.x; // b*32+h
  int b = blk>>5, h = blk&31;
  int tid=threadIdx.x;
  float run[32];
  for(int i=0;i<32;i++) run[i]=0.f;
  for(int c=0;c<4;c++){
    int sblk = (b*4+c)*32+h;
    size_t base = (size_t)sblk*8192;
    float dec = expf(sdA[sblk]);
    for(int i=0;i<32;i++){
      int e = i*256+tid;
      prevb[base+e] = run[i];
      run[i] = (run[i] + states[base+e]) * dec;
    }
  }
}

// ---------------- y_off + xs*D, accumulate into ybuf ----------------
__global__ __launch_bounds__(256) void k_ssd3(const float* __restrict__ xbc, const float* __restrict__ csb,
    const float* __restrict__ prevb, const float* __restrict__ Dp, float* __restrict__ ybuf){
  int blk = blockIdx.x; int bc = blk>>5, h = blk&31; int b=bc>>2, c=bc&3;
  int row0 = b*1024+c*256;
  int tid = threadIdx.x;
  __shared__ float prevs[8192];
  for(int i=0;i<32;i++) prevs[i*256+tid] = prevb[(size_t)blk*8192 + i*256+tid];
  __syncthreads();
  float acc[64];
  for(int p=0;p<64;p++) acc[p]=0.f;
  const float* crow = xbc + (size_t)(row0+tid)*CONV_DIM + 2176;
  for(int n=0;n<128;n++){
    float cv = crow[n];
    for(int p=0;p<64;p++) acc[p] += cv * prevs[p*128+n];
  }
  float e = expf(csb[blk*256+tid]);
  float Dh = Dp[h];
  const float* xsr = xbc + (size_t)(row0+tid)*CONV_DIM + h*64;
  size_t yb = (size_t)(row0+tid)*2048 + h*64;
  for(int p=0;p<64;p++) ybuf[yb+p] += e*acc[p] + xsr[p]*Dh;
}

// ---------------- y = rmsnorm(y * silu(z)) -> bf16 (D=2048) ----------------
__global__ __launch_bounds__(256) void k_gate_norm(const float* __restrict__ y, const float* __restrict__ zxb,
    const float* __restrict__ w, ushort* __restrict__ yb16){
  int r = blockIdx.x;
  const float* zr = zxb + (size_t)r*D_IN_PROJ;
  const float* yr = y + (size_t)r*2048;
  float v[8]; float ss=0.f;
  for(int i=0;i<8;i++){ int c=threadIdx.x+i*256; float z=zr[c]; float g=yr[c]*(z*sigmoidf_(z)); v[i]=g; ss+=g*g; }
  __shared__ float red[4];
  for(int off=32;off;off>>=1) ss += __shfl_down(ss,off,64);
  int wid=threadIdx.x>>6, lane=threadIdx.x&63;
  if(lane==0) red[wid]=ss;
  __syncthreads();
  float tot=red[0]+red[1]+red[2]+red[3];
  float rs=rsqrtf(tot*(1.f/2048.f)+1e-5f);
  for(int i=0;i<8;i++){ int c=threadIdx.x+i*256; yb16[(size_t)r*2048+c]=f2bf(v[i]*rs*w[c]); }
}

// ---------------- scorer stage 2: sigmoid(h1 @ w2) ----------------
__global__ void k_scorer2(const float* __restrict__ h1, const float* __restrict__ w2, float* __restrict__ scores){
  int r = blockIdx.x; int lane = threadIdx.x; // 64 threads
  float s=0.f;
  for(int k=0;k<4;k++){ int c=lane+k*64; s += h1[(size_t)r*256+c]*w2[c]; }
  for(int off=32;off;off>>=1) s += __shfl_down(s,off,64);
  if(lane==0) scores[r]=sigmoidf_(s);
}

// ---------------- serial pool scan (1 wave, scores in LDS, prefetched summaries) ----------------
__global__ void k_pool(const float* __restrict__ scores, const float* __restrict__ summ,
                       float* __restrict__ poolws, float* __restrict__ priosws, int* __restrict__ countws){
  __shared__ float pool[POOL_N*64];
  __shared__ float scs[BT];
  int lane = threadIdx.x;
  for(int i=lane;i<POOL_N*64;i+=64) pool[i]=0.f;
  for(int i=lane;i<BT;i+=64) scs[i]=scores[i];
  __syncthreads();
  float prio = 0.f;
  int count = 0;
  float sv = summ[lane];
  for(int i=0;i<BT;i++){
    float svn = (i<BT-1)? summ[(size_t)(i+1)*64+lane] : 0.f;
    float sc = scs[i];
    if(sc > 0.5f){
      bool not_full = count < POOL_N;
      float v = (lane < POOL_N)? prio : INFINITY;
      int idx = lane;
      for(int off=32;off;off>>=1){
        float ov = __shfl_xor(v,off,64);
        int oi = __shfl_xor(idx,off,64);
        if(ov < v || (ov==v && oi<idx)){ v=ov; idx=oi; }
      }
      int widx = not_full ? count : idx;
      bool write = not_full || (sc > v);
      if(write){
        pool[widx*64 + lane] = sv;
        if(lane == widx) prio = sc;
      }
      if(not_full) count++;
    }
    sv = svn;
  }
  for(int i=0;i<POOL_N;i++) poolws[i*64+lane] = pool[i*64+lane];
  if(lane < POOL_N) priosws[lane]=prio;
  if(lane==0) countws[0]=count;
}

// ---------------- mean(scores) & cond flag ----------------
__global__ __launch_bounds__(256) void k_flags(const float* __restrict__ scores, const int* __restrict__ counti, float* __restrict__ condf){
  float s=0.f;
  for(int i=threadIdx.x;i<BT;i+=256) s += scores[i];
  __shared__ float red[4];
  for(int off=32;off;off>>=1) s += __shfl_down(s,off,64);
  int wid=threadIdx.x>>6, lane=threadIdx.x&63;
  if(lane==0) red[wid]=s;
  __syncthreads();
  if(threadIdx.x==0){
    float mean=(red[0]+red[1]+red[2]+red[3])*(1.f/2048.f);
    condf[0] = (mean>0.3f && counti[0]>0)? 1.f : 0.f;
  }
}

// ---------------- kkT[j*64+p] = (pool @ k_w)[p][j] ----------------
__global__ void k_kk(const float* __restrict__ pool, const float* __restrict__ k_w, float* __restrict__ kkT){
  int o = blockIdx.x*256+threadIdx.x;
  if(o >= 64*POOL_N) return;
  int j = o/POOL_N, p = o%POOL_N;
  float s=0.f;
  for(int k=0;k<64;k++) s += pool[p*64+k]*k_w[k*64+j];
  kkT[j*64+p]=s;
}

// ---------------- vv = pool @ v_w (50x1024) ----------------
__global__ void k_vv(const float* __restrict__ pool, const float* __restrict__ v_w, float* __restrict__ vv){
  int o = blockIdx.x*256+threadIdx.x;
  if(o >= POOL_N*1024) return;
  int p = o>>10, d = o&1023;
  float s=0.f;
  for(int k=0;k<64;k++) s += pool[p*64+k]*v_w[(size_t)k*1024+d];
  vv[o]=s;
}

// ---------------- retrieval: softmax(q·kkT/4, masked) @ vv ----------------
__global__ __launch_bounds__(256) void k_retr(const float* __restrict__ qb, const float* __restrict__ kkT,
   const float* __restrict__ vv, const int* __restrict__ counti, float* __restrict__ retr){
  int r = blockIdx.x;
  __shared__ float qs[64];
  __shared__ float probs[64];
  int tid = threadIdx.x;
  if(tid<64) qs[tid] = qb[(size_t)r*64+tid];
  __syncthreads();
  int count = counti[0];
  if(tid<64){
    float logit = -1e9f;
    if(tid < POOL_N && tid < count){
      float s=0.f;
      for(int k=0;k<64;k++) s += qs[k]*kkT[k*64+tid];
      logit = s*0.25f;
    }
    float m = logit;
    for(int off=32;off;off>>=1) m = fmaxf(m, __shfl_xor(m,off,64));
    float e = expf(logit-m);
    float sum = e;
    for(int off=32;off;off>>=1) sum += __shfl_xor(sum,off,64);
    probs[tid] = e/sum;
  }
  __syncthreads();
  for(int d=tid; d<1024; d+=256){
    float acc=0.f;
    for(int p=0;p<POOL_N;p++) acc += probs[p]*vv[(size_t)p*1024+d];
    retr[(size_t)r*1024+d]=acc;
  }
}

// ---------------- concat [yout, retr] -> bf16 ----------------
__global__ void k_concat(const float* __restrict__ yout, const float* __restrict__ retr, ushort* __restrict__ cc){
  int o = blockIdx.x*256+threadIdx.x; // 2048*2048
  int r = o>>11, c2 = o&2047;
  cc[o] = f2bf((c2<1024)? yout[(size_t)r*1024+c2] : retr[(size_t)r*1024+(c2-1024)]);
}

// ---------------- out = x + yout + cond*sigmoid(g)*retr ----------------
__global__ void k_final(const float* __restrict__ x, const float* __restrict__ yout, const float* __restrict__ g,
   const float* __restrict__ retr, const float* __restrict__ condf, float* __restrict__ out){
  int o = blockIdx.x*256+threadIdx.x; // 2048*1024
  float gv = sigmoidf_(g[o]);
  out[o] = x[o] + yout[o] + condf[0]*gv*retr[o];
}

static inline void gemmf(hipStream_t s, const float*A,const float*B,float*C,int M,int N,int K,int lda,int ldb,int ldc,int act){
  dim3 g((N+63)/64,(M+63)/64);
  hipLaunchKernelGGL(gemm_f32,g,dim3(256),0,s,A,B,C,M,N,K,lda,ldb,ldc,act);
}
static inline void gemmb(hipStream_t s, const ushort*A,const ushort*Bt,float*C,int M,int N,int K,int act){
  dim3 g((N+127)/128, M/128);
  hipLaunchKernelGGL(gemm_bf16,g,dim3(256),0,s,A,Bt,C,M,N,K,act);
}

extern "C" void kernel_launch(void* const* d_in, const int* in_sizes, int n_in,
                              void* d_out, int out_size, void* d_ws, size_t ws_size,
                              hipStream_t stream) {
  const float* x        = (const float*)d_in[0];
  const float* norm_w   = (const float*)d_in[1];
  const float* in_proj_w= (const float*)d_in[2];
  const float* conv_w   = (const float*)d_in[3];
  const float* conv_b   = (const float*)d_in[4];
  const float* dt_bias  = (const float*)d_in[5];
  const float* A_log    = (const float*)d_in[6];
  const float* Dp       = (const float*)d_in[7];
  const float* ssm_norm_w=(const float*)d_in[8];
  const float* out_proj_w=(const float*)d_in[9];
  const float* scorer_w1= (const float*)d_in[10];
  const float* scorer_w2= (const float*)d_in[11];
  const float* summ_w   = (const float*)d_in[12];
  const float* q_w      = (const float*)d_in[13];
  const float* k_w      = (const float*)d_in[14];
  const float* v_w      = (const float*)d_in[15];
  const float* gate_w   = (const float*)d_in[16];
  float* out = (float*)d_out;

  unsigned char* base = (unsigned char*)d_ws;
  size_t off = 0;
  auto FB = [&](size_t bytes)->void*{ void* p = base+off; off = (off+bytes+255)&~(size_t)255; return p; };
  float* zxb   = (float*)FB((size_t)2048*D_IN_PROJ*4);
  float* dtb   = (float*)FB((size_t)2048*32*4);
  float* xbc   = (float*)FB((size_t)2048*CONV_DIM*4);
  float* csb   = (float*)FB((size_t)256*256*4);
  float* sdA   = (float*)FB(1024);
  float* states= (float*)FB((size_t)256*8192*4);
  float* prevb = (float*)FB((size_t)256*8192*4);
  float* ybuf  = (float*)FB((size_t)2048*2048*4);
  float* yout  = (float*)FB((size_t)2048*1024*4);
  float* scores= (float*)FB(2048*4);
  float* summ  = (float*)FB((size_t)2048*64*4);
  float* qb    = (float*)FB((size_t)2048*64*4);
  float* poolb = (float*)FB(POOL_N*64*4);
  float* prios = (float*)FB(256);
  float* miscf = (float*)FB(256);
  int*   counti= (int*)FB(256);
  unsigned char* RX = (unsigned char*)FB((size_t)4194304);   // xnb bf16, then summT/qT/h1/kkT/vvb
  unsigned char* W1 = (unsigned char*)FB((size_t)8978432);   // in_projT bf16, then outT/gateT/sc1T

  // RX sub-allocations
  ushort* xnb   = (ushort*)RX;                        // 2048x1024 bf16 (phase 1)
  ushort* summT = (ushort*)RX;                        // 64x1024 bf16   (phase 2)
  ushort* qT    = (ushort*)(RX + 131072);             // 64x1024 bf16
  float*  h1    = (float*) (RX + 262144);             // 2048x256 f32
  float*  kkT   = (float*) (RX + 2359296);            // 64x64 f32
  float*  vvb   = (float*) (RX + 2375680);            // 64x1024 f32
  // W1 sub-allocations
  ushort* inT   = (ushort*)W1;                        // 4384x1024 bf16 (phase 1)
  ushort* outT  = (ushort*)W1;                        // 1024x2048 bf16 (phase 2)
  ushort* gateT = (ushort*)(W1 + 4194304);            // 1024x2048 bf16
  ushort* sc1T  = (ushort*)(W1 + 8388608);            // 256x1024 bf16
  // aliased regions (disjoint lifetimes)
  float*  Gt    = yout;                               // 8x65536 f32, dead before out_proj writes yout
  ushort* ybf   = (ushort*)prevb;                     // 2048x2048 bf16, after ssd3
  float*  gbuf  = prevb;                              // 2048x1024 f32, after out_proj read ybf
  float*  retr  = states;                             // 2048x1024 f32, after ssd2 read states
  ushort* ccb   = (ushort*)ybuf;                      // 2048x2048 bf16, after gate_norm read ybuf
  ushort* youtb = (ushort*)((unsigned char*)ybuf + 8388608); // 2048x1024 bf16

  // phase 1: in_proj
  hipLaunchKernelGGL(k_transpose_cvt, dim3(137,32), dim3(256), 0, stream, in_proj_w, inT, 1024, 4384);
  k_rmsnorm_x<<<2048,256,0,stream>>>(x, norm_w, xnb);
  gemmb(stream, xnb, inT, zxb, 2048, D_IN_PROJ, 1024, 0);
  // phase 2 weight prep (W1/RX phase-1 contents now dead)
  hipLaunchKernelGGL(k_transpose_cvt, dim3(32,64), dim3(256), 0, stream, out_proj_w, outT, 2048, 1024);
  hipLaunchKernelGGL(k_transpose_cvt, dim3(32,64), dim3(256), 0, stream, gate_w, gateT, 2048, 1024);
  hipLaunchKernelGGL(k_transpose_cvt, dim3(8,32), dim3(256), 0, stream, scorer_w1, sc1T, 1024, 256);
  hipLaunchKernelGGL(k_transpose_cvt, dim3(2,32), dim3(256), 0, stream, summ_w, summT, 1024, 64);
  hipLaunchKernelGGL(k_transpose_cvt, dim3(2,32), dim3(256), 0, stream, q_w, qT, 1024, 64);
  // SSD pipeline
  k_dt<<<256,256,0,stream>>>(zxb, dt_bias, dtb);
  k_conv<<<18432,256,0,stream>>>(zxb, conv_w, conv_b, xbc);
  k_gt<<<2048,256,0,stream>>>(xbc, Gt);
  k_ssd1<<<256,256,0,stream>>>(xbc, dtb, A_log, Gt, ybuf, states, csb, sdA);
  k_ssd2<<<64,256,0,stream>>>(states, sdA, prevb);
  k_ssd3<<<256,256,0,stream>>>(xbc, csb, prevb, Dp, ybuf);
  k_gate_norm<<<2048,256,0,stream>>>(ybuf, zxb, ssm_norm_w, ybf);
  gemmb(stream, ybf, outT, yout, 2048, 1024, 2048, 0);
  k_cvt_bf16<<<2048,256,0,stream>>>(yout, youtb, 2048*1024/4);
  // scorer (stage 1 kept f32 for score stability), summaries, queries
  gemmf(stream, yout, scorer_w1, h1, 2048, 256, 1024, 1024, 256, 256, 1);
  k_scorer2<<<2048,64,0,stream>>>(h1, scorer_w2, scores);
  gemmb(stream, youtb, summT, summ, 2048, 64, 1024, 0);
  gemmb(stream, youtb, qT, qb, 2048, 64, 1024, 0);
  // pool + retrieval
  k_pool<<<1,64,0,stream>>>(scores, summ, poolb, prios, counti);
  k_flags<<<1,256,0,stream>>>(scores, counti, miscf);
  k_kk<<<(64*POOL_N+255)/256,256,0,stream>>>(poolb, k_w, kkT);
  k_vv<<<(POOL_N*1024+255)/256,256,0,stream>>>(poolb, v_w, vvb);
  k_retr<<<2048,256,0,stream>>>(qb, kkT, vvb, counti, retr);
  k_concat<<<16384,256,0,stream>>>(yout, retr, ccb);
  gemmb(stream, ccb, gateT, gbuf, 2048, 1024, 2048, 0);
  k_final<<<8192,256,0,stream>>>(x, yout, gbuf, retr, miscf, out);
  (void)in_sizes; (void)n_in; (void)out_size; (void)ws_size;
}

// Round 4
// 1030.771 us; speedup vs baseline: 2.3516x; 1.4808x over previous
//
#include <hip/hip_runtime.h>
#include <math.h>

#define NHEADS 32
#define D_INNER 2048
#define CONV_DIM 2304
#define D_IN_PROJ 4384
#define POOL_N 50
#define BT 2048

typedef __attribute__((ext_vector_type(8))) short short8;
typedef __attribute__((ext_vector_type(4))) float f32x4;

__device__ __forceinline__ float sigmoidf_(float x){ return 1.f/(1.f+expf(-x)); }
__device__ __forceinline__ ushort f2bf(float f){
  union{float f; unsigned u;} v; v.f=f;
  unsigned r = v.u + 0x7fffu + ((v.u>>16)&1u);
  return (ushort)(r>>16);
}

// ---------------- RMSNorm on x (D=1024) -> bf16 ----------------
__global__ __launch_bounds__(256) void k_rmsnorm_x(const float* __restrict__ x, const float* __restrict__ w, ushort* __restrict__ xn){
  int r = blockIdx.x;
  const float* xr = x + (size_t)r*1024;
  float v[4]; float ss=0.f;
  for(int i=0;i<4;i++){ v[i]=xr[threadIdx.x+i*256]; ss+=v[i]*v[i]; }
  __shared__ float red[4];
  for(int off=32;off;off>>=1) ss += __shfl_down(ss,off,64);
  int wid=threadIdx.x>>6, lane=threadIdx.x&63;
  if(lane==0) red[wid]=ss;
  __syncthreads();
  float tot=red[0]+red[1]+red[2]+red[3];
  float rs=rsqrtf(tot*(1.f/1024.f)+1e-5f);
  for(int i=0;i<4;i++){ int c=threadIdx.x+i*256; xn[(size_t)r*1024+c]=f2bf(v[i]*rs*w[c]); }
}

// ---------------- transpose + cvt: src f32 [R][C] -> dst bf16 [C][R] ----------------
__global__ __launch_bounds__(256) void k_transpose_cvt(const float* __restrict__ src, ushort* __restrict__ dst, int R, int C){
  __shared__ float tile[32][33];
  int c0 = blockIdx.x*32, r0 = blockIdx.y*32;
  int tx = threadIdx.x&31, ty = threadIdx.x>>5;
  for(int i=0;i<4;i++){ int r = r0+ty+i*8; tile[ty+i*8][tx] = src[(size_t)r*C + c0+tx]; }
  __syncthreads();
  for(int i=0;i<4;i++){ int c = c0+ty+i*8; dst[(size_t)c*R + r0+tx] = f2bf(tile[tx][ty+i*8]); }
}

// ---------------- f32 -> bf16 elementwise (n multiple of 4) ----------------
__global__ void k_cvt_bf16(const float* __restrict__ s, ushort* __restrict__ d, int n4){
  int i = blockIdx.x*256+threadIdx.x;
  if(i<n4){
    float4 v = ((const float4*)s)[i];
    ushort4 o; o.x=f2bf(v.x); o.y=f2bf(v.y); o.z=f2bf(v.z); o.w=f2bf(v.w);
    ((ushort4*)d)[i] = o;
  }
}

// ---------------- bf16 MFMA GEMM: C[M,N] f32 = A[M,K]bf16 @ Bt[N,K]bf16^T ----------------
__global__ __launch_bounds__(256) void gemm_bf16(const ushort* __restrict__ A, const ushort* __restrict__ Bt,
    float* __restrict__ C, int M, int N, int K, int act){
  __shared__ __align__(16) ushort As[128*32];
  __shared__ __align__(16) ushort Bs[128*32];
  int n0 = blockIdx.x*128, m0 = blockIdx.y*128;
  int tid = threadIdx.x;
  int lane = tid&63, w = tid>>6;
  int wr = (w>>1)*64, wc = (w&1)*64;
  f32x4 acc[4][4];
  for(int i=0;i<4;i++)for(int j=0;j<4;j++)acc[i][j]=(f32x4){0.f,0.f,0.f,0.f};
  int srow = tid>>2, skb = (tid&3)*8;
  const ushort* Ap0 = A + (size_t)(m0+srow)*K + skb;
  const ushort* Ap1 = A + (size_t)(m0+srow+64)*K + skb;
  bool bv0 = (n0+srow) < N, bv1 = (n0+srow+64) < N;
  const ushort* Bp0 = Bt + (size_t)(bv0 ? (n0+srow)    : 0)*K + skb;
  const ushort* Bp1 = Bt + (size_t)(bv1 ? (n0+srow+64) : 0)*K + skb;
  int fr = lane&15, fko = (lane>>4)*8;
  for(int k0=0;k0<K;k0+=32){
    uint4 a0 = *(const uint4*)(Ap0 + k0);
    uint4 a1 = *(const uint4*)(Ap1 + k0);
    uint4 b0 = bv0 ? *(const uint4*)(Bp0 + k0) : make_uint4(0u,0u,0u,0u);
    uint4 b1 = bv1 ? *(const uint4*)(Bp1 + k0) : make_uint4(0u,0u,0u,0u);
    *(uint4*)(As + srow*32 + skb)      = a0;
    *(uint4*)(As + (srow+64)*32 + skb) = a1;
    *(uint4*)(Bs + srow*32 + skb)      = b0;
    *(uint4*)(Bs + (srow+64)*32 + skb) = b1;
    __syncthreads();
    short8 af[4], bfr[4];
    for(int i=0;i<4;i++) af[i]  = *(const short8*)(As + (wr+i*16+fr)*32 + fko);
    for(int j=0;j<4;j++) bfr[j] = *(const short8*)(Bs + (wc+j*16+fr)*32 + fko);
    for(int i=0;i<4;i++)
      for(int j=0;j<4;j++)
        acc[i][j] = __builtin_amdgcn_mfma_f32_16x16x32_bf16(af[i], bfr[j], acc[i][j], 0,0,0);
    __syncthreads();
  }
  int rbase = m0 + wr + (lane>>4)*4;
  for(int i=0;i<4;i++){
    for(int j=0;j<4;j++){
      int col = n0 + wc + j*16 + fr;
      if(col < N){
        for(int r=0;r<4;r++){
          float v = acc[i][j][r];
          if(act) v = fmaxf(v,0.f);
          C[(size_t)(rbase + i*16 + r)*N + col] = v;
        }
      }
    }
  }
}

// ---------------- generic f32 GEMM (kept for scorer stage-1) ----------------
__global__ __launch_bounds__(256) void gemm_f32(const float* __restrict__ A, const float* __restrict__ B, float* __restrict__ C,
    int M,int N,int K,int lda,int ldb,int ldc,int act){
  __shared__ float As[16][65];
  __shared__ float Bs[16][65];
  int n0 = blockIdx.x*64, m0 = blockIdx.y*64;
  int tid = threadIdx.x;
  int tx = tid&15, ty = tid>>4;
  float acc[4][4]={};
  for(int k0=0;k0<K;k0+=16){
    for(int i=0;i<4;i++){ int e=tid+i*256; int m=e>>4,k=e&15;
      As[k][m] = (m0+m<M) ? A[(size_t)(m0+m)*lda + k0+k] : 0.f; }
    for(int i=0;i<4;i++){ int e=tid+i*256; int k=e>>6,n=e&63;
      Bs[k][n] = (n0+n<N) ? B[(size_t)(k0+k)*ldb + n0+n] : 0.f; }
    __syncthreads();
    for(int k=0;k<16;k++){
      float a[4],b[4];
      for(int i=0;i<4;i++) a[i]=As[k][ty*4+i];
      for(int j=0;j<4;j++) b[j]=Bs[k][tx*4+j];
      for(int i=0;i<4;i++) for(int j=0;j<4;j++) acc[i][j] += a[i]*b[j];
    }
    __syncthreads();
  }
  for(int i=0;i<4;i++){ int m=m0+ty*4+i; if(m>=M) continue;
    for(int j=0;j<4;j++){ int n=n0+tx*4+j; if(n<N){
      float v=acc[i][j]; if(act==1) v=fmaxf(v,0.f);
      C[(size_t)m*ldc+n]=v; } } }
}

// ---------------- dt = softplus(zxb[:, -32:] + bias) ----------------
__global__ void k_dt(const float* __restrict__ zxb, const float* __restrict__ dt_bias, float* __restrict__ dtb){
  int o = blockIdx.x*256+threadIdx.x; // 2048*32
  int r = o>>5, h = o&31;
  float v = zxb[(size_t)r*D_IN_PROJ + 4352 + h] + dt_bias[h];
  dtb[o] = (v>20.f) ? v : log1pf(expf(v));
}

// ---------------- causal depthwise conv (k=4) + silu ----------------
__global__ void k_conv(const float* __restrict__ zxb, const float* __restrict__ cw, const float* __restrict__ cb, float* __restrict__ xbc){
  int o = blockIdx.x*256+threadIdx.x; // 2048*2304
  int ch = o % CONV_DIM; int rt = o / CONV_DIM;
  int b = rt>>10, t = rt&1023;
  float acc = cb[ch];
  for(int k=0;k<4;k++){
    int tt = t-3+k;
    if(tt>=0) acc += zxb[(size_t)(b*1024+tt)*D_IN_PROJ + 2048 + ch]*cw[ch*4+k];
  }
  xbc[o] = acc*sigmoidf_(acc);
}

// ---------------- G^T per (b,c): Gt[s*256+l] = dot(C[l], B[s]) ----------------
__global__ __launch_bounds__(256) void k_gt(const float* __restrict__ xbc, float* __restrict__ Gt){
  int bc = blockIdx.x >> 8;
  int tile = blockIdx.x & 255;
  int l0 = (tile>>4)<<4, s0 = (tile&15)<<4;
  int b = bc>>2, c = bc&3;
  int row0 = b*1024 + c*256;
  __shared__ float Cs[16][130], Bs2[16][130];
  int tid = threadIdx.x;
  for(int i=0;i<8;i++){ int e=tid+i*256; int rr=e>>7, n=e&127;
    Cs[rr][n]  = xbc[(size_t)(row0+l0+rr)*CONV_DIM + 2176 + n];
    Bs2[rr][n] = xbc[(size_t)(row0+s0+rr)*CONV_DIM + 2048 + n];
  }
  __syncthreads();
  int tx = tid&15, ty = tid>>4;
  float acc=0.f;
  for(int n=0;n<128;n++) acc += Cs[tx][n]*Bs2[ty][n];
  Gt[(size_t)bc*65536 + (size_t)(s0+ty)*256 + (l0+tx)] = acc;
}

// ---------------- SSD per (b,c,h): cumsum, y_diag, states ----------------
__global__ __launch_bounds__(256) void k_ssd1(const float* __restrict__ xbc, const float* __restrict__ dtb,
    const float* __restrict__ A_log, const float* __restrict__ Gt,
    float* __restrict__ ybuf, float* __restrict__ states, float* __restrict__ csb, float* __restrict__ sdA){
  int blk = blockIdx.x;      // (b*4+c)*32+h
  int bc = blk>>5, h = blk&31;
  int b = bc>>2, c = bc&3;
  int row0 = b*1024 + c*256;
  int tid = threadIdx.x;
  __shared__ float cs[256], dts[256];
  __shared__ float xd[256*32];
  float dtv = dtb[(size_t)(row0+tid)*32 + h];
  float Ah = -expf(A_log[h]);
  dts[tid]=dtv;
  cs[tid]=dtv*Ah;
  __syncthreads();
  for(int o=1;o<256;o<<=1){
    float add = (tid>=o)? cs[tid-o] : 0.f;
    __syncthreads();
    cs[tid] += add;
    __syncthreads();
  }
  float csl = cs[tid];
  float cslast = cs[255];
  csb[blk*256+tid] = csl;
  if(tid==0) sdA[blk] = cslast;
  const float* gt = Gt + (size_t)bc*65536;
  for(int ph=0; ph<2; ph++){
    __syncthreads();
    for(int i=0;i<32;i++){
      int e = tid + i*256; int l = e>>5, pp = e&31;
      xd[e] = xbc[(size_t)(row0+l)*CONV_DIM + h*64 + ph*32 + pp] * dts[l];
    }
    __syncthreads();
    // y_diag
    float acc[32];
    for(int p=0;p<32;p++) acc[p]=0.f;
    for(int s=0;s<=tid;s++){
      float m = gt[(size_t)s*256+tid] * expf(csl - cs[s]);
      const float* xr = &xd[s*32];
      for(int p=0;p<32;p++) acc[p] += m*xr[p];
    }
    {
      size_t base = (size_t)(row0+tid)*2048 + h*64 + ph*32;
      for(int p=0;p<32;p++) ybuf[base+p] = acc[p];
    }
    // states
    int n = tid&127, pg = tid>>7;
    float acc2[16];
    for(int j=0;j<16;j++) acc2[j]=0.f;
    for(int l=0;l<256;l++){
      float w = xbc[(size_t)(row0+l)*CONV_DIM + 2048 + n] * expf(cslast - cs[l]);
      const float* xr = &xd[l*32 + pg*16];
      for(int j=0;j<16;j++) acc2[j] += w*xr[j];
    }
    size_t sb = (size_t)blk*8192;
    for(int j=0;j<16;j++) states[sb + (size_t)(ph*32+pg*16+j)*128 + n] = acc2[j];
  }
}

// ---------------- chunk scan over c=0..3 ----------------
__global__ __launch_bounds__(256) void k_ssd2(const float* __restrict__ states, const float* __restrict__ sdA, float* __restrict__ prevb){
  int blk = blockIdx.x; // b*32+h
  int b = blk>>5, h = blk&31;
  int tid=threadIdx.x;
  float run[32];
  for(int i=0;i<32;i++) run[i]=0.f;
  for(int c=0;c<4;c++){
    int sblk = (b*4+c)*32+h;
    size_t base = (size_t)sblk*8192;
    float dec = expf(sdA[sblk]);
    for(int i=0;i<32;i++){
      int e = i*256+tid;
      prevb[base+e] = run[i];
      run[i] = (run[i] + states[base+e]) * dec;
    }
  }
}

// ---------------- y_off + xs*D, accumulate into ybuf ----------------
__global__ __launch_bounds__(256) void k_ssd3(const float* __restrict__ xbc, const float* __restrict__ csb,
    const float* __restrict__ prevb, const float* __restrict__ Dp, float* __restrict__ ybuf){
  int blk = blockIdx.x; int bc = blk>>5, h = blk&31; int b=bc>>2, c=bc&3;
  int row0 = b*1024+c*256;
  int tid = threadIdx.x;
  __shared__ float prevs[8192];
  for(int i=0;i<32;i++) prevs[i*256+tid] = prevb[(size_t)blk*8192 + i*256+tid];
  __syncthreads();
  float acc[64];
  for(int p=0;p<64;p++) acc[p]=0.f;
  const float* crow = xbc + (size_t)(row0+tid)*CONV_DIM + 2176;
  for(int n=0;n<128;n++){
    float cv = crow[n];
    for(int p=0;p<64;p++) acc[p] += cv * prevs[p*128+n];
  }
  float e = expf(csb[blk*256+tid]);
  float Dh = Dp[h];
  const float* xsr = xbc + (size_t)(row0+tid)*CONV_DIM + h*64;
  size_t yb = (size_t)(row0+tid)*2048 + h*64;
  for(int p=0;p<64;p++) ybuf[yb+p] += e*acc[p] + xsr[p]*Dh;
}

// ---------------- y = rmsnorm(y * silu(z)) -> bf16 (D=2048) ----------------
__global__ __launch_bounds__(256) void k_gate_norm(const float* __restrict__ y, const float* __restrict__ zxb,
    const float* __restrict__ w, ushort* __restrict__ yb16){
  int r = blockIdx.x;
  const float* zr = zxb + (size_t)r*D_IN_PROJ;
  const float* yr = y + (size_t)r*2048;
  float v[8]; float ss=0.f;
  for(int i=0;i<8;i++){ int c=threadIdx.x+i*256; float z=zr[c]; float g=yr[c]*(z*sigmoidf_(z)); v[i]=g; ss+=g*g; }
  __shared__ float red[4];
  for(int off=32;off;off>>=1) ss += __shfl_down(ss,off,64);
  int wid=threadIdx.x>>6, lane=threadIdx.x&63;
  if(lane==0) red[wid]=ss;
  __syncthreads();
  float tot=red[0]+red[1]+red[2]+red[3];
  float rs=rsqrtf(tot*(1.f/2048.f)+1e-5f);
  for(int i=0;i<8;i++){ int c=threadIdx.x+i*256; yb16[(size_t)r*2048+c]=f2bf(v[i]*rs*w[c]); }
}

// ---------------- scorer stage 2: sigmoid(h1 @ w2) ----------------
__global__ void k_scorer2(const float* __restrict__ h1, const float* __restrict__ w2, float* __restrict__ scores){
  int r = blockIdx.x; int lane = threadIdx.x; // 64 threads
  float s=0.f;
  for(int k=0;k<4;k++){ int c=lane+k*64; s += h1[(size_t)r*256+c]*w2[c]; }
  for(int off=32;off;off>>=1) s += __shfl_down(s,off,64);
  if(lane==0) scores[r]=sigmoidf_(s);
}

// ---------------- serial pool scan: scalars only, record winners ----------------
// State: lane p owns prios[p]; curmin/curargmin cached, recomputed only after a write.
__global__ void k_pool(const float* __restrict__ scores,
                       float* __restrict__ priosws, int* __restrict__ countws, int* __restrict__ winners){
  __shared__ float scs[BT];
  int lane = threadIdx.x;
  for(int i=lane;i<BT;i+=64) scs[i]=scores[i];
  __syncthreads();
  float prio = 0.f;
  int winner = -1;
  int count = 0;
  float curmin = 0.f; int curargmin = 0;
  for(int b0=0;b0<BT;b0+=64){
    float ownsc = scs[b0+lane];
    for(int j=0;j<64;j++){
      float sc = __shfl(ownsc, j, 64);
      if(sc > 0.5f){
        bool recompute = false;
        if(count < POOL_N){
          if(lane == count){ prio = sc; winner = b0+j; }
          count++;
          if(count == POOL_N) recompute = true;
        } else if(sc > curmin){
          if(lane == curargmin){ prio = sc; winner = b0+j; }
          recompute = true;
        }
        if(recompute){
          float v = (lane < POOL_N)? prio : INFINITY; int idx = lane;
          for(int off=32;off;off>>=1){
            float ov = __shfl_xor(v,off,64);
            int oi = __shfl_xor(idx,off,64);
            if(ov < v || (ov==v && oi<idx)){ v=ov; idx=oi; }
          }
          curmin = v; curargmin = idx;
        }
      }
    }
  }
  if(lane < POOL_N){ winners[lane]=winner; priosws[lane]=prio; }
  if(lane==0) countws[0]=count;
}

// ---------------- gather pool rows from summaries ----------------
__global__ void k_poolg(const float* __restrict__ summ, const int* __restrict__ winners, float* __restrict__ poolb){
  int p = blockIdx.x; int lane = threadIdx.x;
  int wi = winners[p];
  poolb[p*64+lane] = (wi>=0)? summ[(size_t)wi*64+lane] : 0.f;
}

// ---------------- mean(scores) & cond flag ----------------
__global__ __launch_bounds__(256) void k_flags(const float* __restrict__ scores, const int* __restrict__ counti, float* __restrict__ condf){
  float s=0.f;
  for(int i=threadIdx.x;i<BT;i+=256) s += scores[i];
  __shared__ float red[4];
  for(int off=32;off;off>>=1) s += __shfl_down(s,off,64);
  int wid=threadIdx.x>>6, lane=threadIdx.x&63;
  if(lane==0) red[wid]=s;
  __syncthreads();
  if(threadIdx.x==0){
    float mean=(red[0]+red[1]+red[2]+red[3])*(1.f/2048.f);
    condf[0] = (mean>0.3f && counti[0]>0)? 1.f : 0.f;
  }
}

// ---------------- kkT[j*64+p] = (pool @ k_w)[p][j] ----------------
__global__ void k_kk(const float* __restrict__ pool, const float* __restrict__ k_w, float* __restrict__ kkT){
  int o = blockIdx.x*256+threadIdx.x;
  if(o >= 64*POOL_N) return;
  int j = o/POOL_N, p = o%POOL_N;
  float s=0.f;
  for(int k=0;k<64;k++) s += pool[p*64+k]*k_w[k*64+j];
  kkT[j*64+p]=s;
}

// ---------------- vv = pool @ v_w (50x1024) ----------------
__global__ void k_vv(const float* __restrict__ pool, const float* __restrict__ v_w, float* __restrict__ vv){
  int o = blockIdx.x*256+threadIdx.x;
  if(o >= POOL_N*1024) return;
  int p = o>>10, d = o&1023;
  float s=0.f;
  for(int k=0;k<64;k++) s += pool[p*64+k]*v_w[(size_t)k*1024+d];
  vv[o]=s;
}

// ---------------- retrieval: softmax(q·kkT/4, masked) @ vv ----------------
__global__ __launch_bounds__(256) void k_retr(const float* __restrict__ qb, const float* __restrict__ kkT,
   const float* __restrict__ vv, const int* __restrict__ counti, float* __restrict__ retr){
  int r = blockIdx.x;
  __shared__ float qs[64];
  __shared__ float probs[64];
  int tid = threadIdx.x;
  if(tid<64) qs[tid] = qb[(size_t)r*64+tid];
  __syncthreads();
  int count = counti[0];
  if(tid<64){
    float logit = -1e9f;
    if(tid < POOL_N && tid < count){
      float s=0.f;
      for(int k=0;k<64;k++) s += qs[k]*kkT[k*64+tid];
      logit = s*0.25f;
    }
    float m = logit;
    for(int off=32;off;off>>=1) m = fmaxf(m, __shfl_xor(m,off,64));
    float e = expf(logit-m);
    float sum = e;
    for(int off=32;off;off>>=1) sum += __shfl_xor(sum,off,64);
    probs[tid] = e/sum;
  }
  __syncthreads();
  for(int d=tid; d<1024; d+=256){
    float acc=0.f;
    for(int p=0;p<POOL_N;p++) acc += probs[p]*vv[(size_t)p*1024+d];
    retr[(size_t)r*1024+d]=acc;
  }
}

// ---------------- concat [yout, retr] -> bf16 ----------------
__global__ void k_concat(const float* __restrict__ yout, const float* __restrict__ retr, ushort* __restrict__ cc){
  int o = blockIdx.x*256+threadIdx.x; // 2048*2048
  int r = o>>11, c2 = o&2047;
  cc[o] = f2bf((c2<1024)? yout[(size_t)r*1024+c2] : retr[(size_t)r*1024+(c2-1024)]);
}

// ---------------- out = x + yout + cond*sigmoid(g)*retr ----------------
__global__ void k_final(const float* __restrict__ x, const float* __restrict__ yout, const float* __restrict__ g,
   const float* __restrict__ retr, const float* __restrict__ condf, float* __restrict__ out){
  int o = blockIdx.x*256+threadIdx.x; // 2048*1024
  float gv = sigmoidf_(g[o]);
  out[o] = x[o] + yout[o] + condf[0]*gv*retr[o];
}

static inline void gemmf(hipStream_t s, const float*A,const float*B,float*C,int M,int N,int K,int lda,int ldb,int ldc,int act){
  dim3 g((N+63)/64,(M+63)/64);
  hipLaunchKernelGGL(gemm_f32,g,dim3(256),0,s,A,B,C,M,N,K,lda,ldb,ldc,act);
}
static inline void gemmb(hipStream_t s, const ushort*A,const ushort*Bt,float*C,int M,int N,int K,int act){
  dim3 g((N+127)/128, M/128);
  hipLaunchKernelGGL(gemm_bf16,g,dim3(256),0,s,A,Bt,C,M,N,K,act);
}

extern "C" void kernel_launch(void* const* d_in, const int* in_sizes, int n_in,
                              void* d_out, int out_size, void* d_ws, size_t ws_size,
                              hipStream_t stream) {
  const float* x        = (const float*)d_in[0];
  const float* norm_w   = (const float*)d_in[1];
  const float* in_proj_w= (const float*)d_in[2];
  const float* conv_w   = (const float*)d_in[3];
  const float* conv_b   = (const float*)d_in[4];
  const float* dt_bias  = (const float*)d_in[5];
  const float* A_log    = (const float*)d_in[6];
  const float* Dp       = (const float*)d_in[7];
  const float* ssm_norm_w=(const float*)d_in[8];
  const float* out_proj_w=(const float*)d_in[9];
  const float* scorer_w1= (const float*)d_in[10];
  const float* scorer_w2= (const float*)d_in[11];
  const float* summ_w   = (const float*)d_in[12];
  const float* q_w      = (const float*)d_in[13];
  const float* k_w      = (const float*)d_in[14];
  const float* v_w      = (const float*)d_in[15];
  const float* gate_w   = (const float*)d_in[16];
  float* out = (float*)d_out;

  unsigned char* base = (unsigned char*)d_ws;
  size_t off = 0;
  auto FB = [&](size_t bytes)->void*{ void* p = base+off; off = (off+bytes+255)&~(size_t)255; return p; };
  float* zxb   = (float*)FB((size_t)2048*D_IN_PROJ*4);
  float* dtb   = (float*)FB((size_t)2048*32*4);
  float* xbc   = (float*)FB((size_t)2048*CONV_DIM*4);
  float* csb   = (float*)FB((size_t)256*256*4);
  float* sdA   = (float*)FB(1024);
  float* states= (float*)FB((size_t)256*8192*4);
  float* prevb = (float*)FB((size_t)256*8192*4);
  float* ybuf  = (float*)FB((size_t)2048*2048*4);
  float* yout  = (float*)FB((size_t)2048*1024*4);
  float* scores= (float*)FB(2048*4);
  float* summ  = (float*)FB((size_t)2048*64*4);
  float* qb    = (float*)FB((size_t)2048*64*4);
  float* poolb = (float*)FB(POOL_N*64*4);
  float* prios = (float*)FB(256);
  float* miscf = (float*)FB(256);
  int*   counti= (int*)FB(256);
  int*   winners=(int*)FB(256);
  unsigned char* RX = (unsigned char*)FB((size_t)4194304);   // xnb bf16, then summT/qT/h1/kkT/vvb
  unsigned char* W1 = (unsigned char*)FB((size_t)8978432);   // in_projT bf16, then outT/gateT/sc1T

  // RX sub-allocations
  ushort* xnb   = (ushort*)RX;                        // 2048x1024 bf16 (phase 1)
  ushort* summT = (ushort*)RX;                        // 64x1024 bf16   (phase 2)
  ushort* qT    = (ushort*)(RX + 131072);             // 64x1024 bf16
  float*  h1    = (float*) (RX + 262144);             // 2048x256 f32
  float*  kkT   = (float*) (RX + 2359296);            // 64x64 f32
  float*  vvb   = (float*) (RX + 2375680);            // 64x1024 f32
  // W1 sub-allocations
  ushort* inT   = (ushort*)W1;                        // 4384x1024 bf16 (phase 1)
  ushort* outT  = (ushort*)W1;                        // 1024x2048 bf16 (phase 2)
  ushort* gateT = (ushort*)(W1 + 4194304);            // 1024x2048 bf16
  ushort* sc1T  = (ushort*)(W1 + 8388608);            // 256x1024 bf16
  // aliased regions (disjoint lifetimes)
  float*  Gt    = yout;                               // 8x65536 f32, dead before out_proj writes yout
  ushort* ybf   = (ushort*)prevb;                     // 2048x2048 bf16, after ssd3
  float*  gbuf  = prevb;                              // 2048x1024 f32, after out_proj read ybf
  float*  retr  = states;                             // 2048x1024 f32, after ssd2 read states
  ushort* ccb   = (ushort*)ybuf;                      // 2048x2048 bf16, after gate_norm read ybuf
  ushort* youtb = (ushort*)((unsigned char*)ybuf + 8388608); // 2048x1024 bf16

  // phase 1: in_proj
  hipLaunchKernelGGL(k_transpose_cvt, dim3(137,32), dim3(256), 0, stream, in_proj_w, inT, 1024, 4384);
  k_rmsnorm_x<<<2048,256,0,stream>>>(x, norm_w, xnb);
  gemmb(stream, xnb, inT, zxb, 2048, D_IN_PROJ, 1024, 0);
  // phase 2 weight prep (W1/RX phase-1 contents now dead)
  hipLaunchKernelGGL(k_transpose_cvt, dim3(32,64), dim3(256), 0, stream, out_proj_w, outT, 2048, 1024);
  hipLaunchKernelGGL(k_transpose_cvt, dim3(32,64), dim3(256), 0, stream, gate_w, gateT, 2048, 1024);
  hipLaunchKernelGGL(k_transpose_cvt, dim3(8,32), dim3(256), 0, stream, scorer_w1, sc1T, 1024, 256);
  hipLaunchKernelGGL(k_transpose_cvt, dim3(2,32), dim3(256), 0, stream, summ_w, summT, 1024, 64);
  hipLaunchKernelGGL(k_transpose_cvt, dim3(2,32), dim3(256), 0, stream, q_w, qT, 1024, 64);
  // SSD pipeline
  k_dt<<<256,256,0,stream>>>(zxb, dt_bias, dtb);
  k_conv<<<18432,256,0,stream>>>(zxb, conv_w, conv_b, xbc);
  k_gt<<<2048,256,0,stream>>>(xbc, Gt);
  k_ssd1<<<256,256,0,stream>>>(xbc, dtb, A_log, Gt, ybuf, states, csb, sdA);
  k_ssd2<<<64,256,0,stream>>>(states, sdA, prevb);
  k_ssd3<<<256,256,0,stream>>>(xbc, csb, prevb, Dp, ybuf);
  k_gate_norm<<<2048,256,0,stream>>>(ybuf, zxb, ssm_norm_w, ybf);
  gemmb(stream, ybf, outT, yout, 2048, 1024, 2048, 0);
  k_cvt_bf16<<<2048,256,0,stream>>>(yout, youtb, 2048*1024/4);
  // scorer (stage 1 kept f32 for score stability), summaries, queries
  gemmf(stream, yout, scorer_w1, h1, 2048, 256, 1024, 1024, 256, 256, 1);
  k_scorer2<<<2048,64,0,stream>>>(h1, scorer_w2, scores);
  gemmb(stream, youtb, summT, summ, 2048, 64, 1024, 0);
  gemmb(stream, youtb, qT, qb, 2048, 64, 1024, 0);
  // pool + retrieval
  k_pool<<<1,64,0,stream>>>(scores, prios, counti, winners);
  k_poolg<<<POOL_N,64,0,stream>>>(summ, winners, poolb);
  k_flags<<<1,256,0,stream>>>(scores, counti, miscf);
  k_kk<<<(64*POOL_N+255)/256,256,0,stream>>>(poolb, k_w, kkT);
  k_vv<<<(POOL_N*1024+255)/256,256,0,stream>>>(poolb, v_w, vvb);
  k_retr<<<2048,256,0,stream>>>(qb, kkT, vvb, counti, retr);
  k_concat<<<16384,256,0,stream>>>(yout, retr, ccb);
  gemmb(stream, ccb, gateT, gbuf, 2048, 1024, 2048, 0);
  k_final<<<8192,256,0,stream>>>(x, yout, gbuf, retr, miscf, out);
  (void)in_sizes; (void)n_in; (void)out_size; (void)ws_size;
}

// Round 5
// 881.081 us; speedup vs baseline: 2.7511x; 1.1699x over previous
//
#include <hip/hip_runtime.h>
#include <math.h>

#define NHEADS 32
#define D_INNER 2048
#define CONV_DIM 2304
#define D_IN_PROJ 4384
#define POOL_N 50
#define BT 2048

typedef __attribute__((ext_vector_type(8))) short short8;
typedef __attribute__((ext_vector_type(4))) float f32x4;

__device__ __forceinline__ float sigmoidf_(float x){ return 1.f/(1.f+expf(-x)); }
__device__ __forceinline__ ushort f2bf(float f){
  union{float f; unsigned u;} v; v.f=f;
  unsigned r = v.u + 0x7fffu + ((v.u>>16)&1u);
  return (ushort)(r>>16);
}

// ---------------- RMSNorm on x (D=1024) -> bf16 ----------------
__global__ __launch_bounds__(256) void k_rmsnorm_x(const float* __restrict__ x, const float* __restrict__ w, ushort* __restrict__ xn){
  int r = blockIdx.x;
  const float* xr = x + (size_t)r*1024;
  float v[4]; float ss=0.f;
  for(int i=0;i<4;i++){ v[i]=xr[threadIdx.x+i*256]; ss+=v[i]*v[i]; }
  __shared__ float red[4];
  for(int off=32;off;off>>=1) ss += __shfl_down(ss,off,64);
  int wid=threadIdx.x>>6, lane=threadIdx.x&63;
  if(lane==0) red[wid]=ss;
  __syncthreads();
  float tot=red[0]+red[1]+red[2]+red[3];
  float rs=rsqrtf(tot*(1.f/1024.f)+1e-5f);
  for(int i=0;i<4;i++){ int c=threadIdx.x+i*256; xn[(size_t)r*1024+c]=f2bf(v[i]*rs*w[c]); }
}

// ---------------- transpose + cvt: src f32 [R][C] -> dst bf16 [C][R] ----------------
__global__ __launch_bounds__(256) void k_transpose_cvt(const float* __restrict__ src, ushort* __restrict__ dst, int R, int C){
  __shared__ float tile[32][33];
  int c0 = blockIdx.x*32, r0 = blockIdx.y*32;
  int tx = threadIdx.x&31, ty = threadIdx.x>>5;
  for(int i=0;i<4;i++){ int r = r0+ty+i*8; tile[ty+i*8][tx] = src[(size_t)r*C + c0+tx]; }
  __syncthreads();
  for(int i=0;i<4;i++){ int c = c0+ty+i*8; dst[(size_t)c*R + r0+tx] = f2bf(tile[tx][ty+i*8]); }
}

// ---------------- f32 -> bf16 elementwise (n multiple of 4) ----------------
__global__ void k_cvt_bf16(const float* __restrict__ s, ushort* __restrict__ d, int n4){
  int i = blockIdx.x*256+threadIdx.x;
  if(i<n4){
    float4 v = ((const float4*)s)[i];
    ushort4 o; o.x=f2bf(v.x); o.y=f2bf(v.y); o.z=f2bf(v.z); o.w=f2bf(v.w);
    ((ushort4*)d)[i] = o;
  }
}

// ---------------- bf16 MFMA GEMM: C[M,N] f32 = A[M,K]bf16 @ Bt[N,K]bf16^T ----------------
__global__ __launch_bounds__(256) void gemm_bf16(const ushort* __restrict__ A, const ushort* __restrict__ Bt,
    float* __restrict__ C, int M, int N, int K, int act){
  __shared__ __align__(16) ushort As[128*32];
  __shared__ __align__(16) ushort Bs[128*32];
  int n0 = blockIdx.x*128, m0 = blockIdx.y*128;
  int tid = threadIdx.x;
  int lane = tid&63, w = tid>>6;
  int wr = (w>>1)*64, wc = (w&1)*64;
  f32x4 acc[4][4];
  for(int i=0;i<4;i++)for(int j=0;j<4;j++)acc[i][j]=(f32x4){0.f,0.f,0.f,0.f};
  int srow = tid>>2, skb = (tid&3)*8;
  const ushort* Ap0 = A + (size_t)(m0+srow)*K + skb;
  const ushort* Ap1 = A + (size_t)(m0+srow+64)*K + skb;
  bool bv0 = (n0+srow) < N, bv1 = (n0+srow+64) < N;
  const ushort* Bp0 = Bt + (size_t)(bv0 ? (n0+srow)    : 0)*K + skb;
  const ushort* Bp1 = Bt + (size_t)(bv1 ? (n0+srow+64) : 0)*K + skb;
  int fr = lane&15, fko = (lane>>4)*8;
  for(int k0=0;k0<K;k0+=32){
    uint4 a0 = *(const uint4*)(Ap0 + k0);
    uint4 a1 = *(const uint4*)(Ap1 + k0);
    uint4 b0 = bv0 ? *(const uint4*)(Bp0 + k0) : make_uint4(0u,0u,0u,0u);
    uint4 b1 = bv1 ? *(const uint4*)(Bp1 + k0) : make_uint4(0u,0u,0u,0u);
    *(uint4*)(As + srow*32 + skb)      = a0;
    *(uint4*)(As + (srow+64)*32 + skb) = a1;
    *(uint4*)(Bs + srow*32 + skb)      = b0;
    *(uint4*)(Bs + (srow+64)*32 + skb) = b1;
    __syncthreads();
    short8 af[4], bfr[4];
    for(int i=0;i<4;i++) af[i]  = *(const short8*)(As + (wr+i*16+fr)*32 + fko);
    for(int j=0;j<4;j++) bfr[j] = *(const short8*)(Bs + (wc+j*16+fr)*32 + fko);
    for(int i=0;i<4;i++)
      for(int j=0;j<4;j++)
        acc[i][j] = __builtin_amdgcn_mfma_f32_16x16x32_bf16(af[i], bfr[j], acc[i][j], 0,0,0);
    __syncthreads();
  }
  int rbase = m0 + wr + (lane>>4)*4;
  for(int i=0;i<4;i++){
    for(int j=0;j<4;j++){
      int col = n0 + wc + j*16 + fr;
      if(col < N){
        for(int r=0;r<4;r++){
          float v = acc[i][j][r];
          if(act) v = fmaxf(v,0.f);
          C[(size_t)(rbase + i*16 + r)*N + col] = v;
        }
      }
    }
  }
}

// ---------------- generic f32 GEMM (kept for scorer stage-1) ----------------
__global__ __launch_bounds__(256) void gemm_f32(const float* __restrict__ A, const float* __restrict__ B, float* __restrict__ C,
    int M,int N,int K,int lda,int ldb,int ldc,int act){
  __shared__ float As[16][65];
  __shared__ float Bs[16][65];
  int n0 = blockIdx.x*64, m0 = blockIdx.y*64;
  int tid = threadIdx.x;
  int tx = tid&15, ty = tid>>4;
  float acc[4][4]={};
  for(int k0=0;k0<K;k0+=16){
    for(int i=0;i<4;i++){ int e=tid+i*256; int m=e>>4,k=e&15;
      As[k][m] = (m0+m<M) ? A[(size_t)(m0+m)*lda + k0+k] : 0.f; }
    for(int i=0;i<4;i++){ int e=tid+i*256; int k=e>>6,n=e&63;
      Bs[k][n] = (n0+n<N) ? B[(size_t)(k0+k)*ldb + n0+n] : 0.f; }
    __syncthreads();
    for(int k=0;k<16;k++){
      float a[4],b[4];
      for(int i=0;i<4;i++) a[i]=As[k][ty*4+i];
      for(int j=0;j<4;j++) b[j]=Bs[k][tx*4+j];
      for(int i=0;i<4;i++) for(int j=0;j<4;j++) acc[i][j] += a[i]*b[j];
    }
    __syncthreads();
  }
  for(int i=0;i<4;i++){ int m=m0+ty*4+i; if(m>=M) continue;
    for(int j=0;j<4;j++){ int n=n0+tx*4+j; if(n<N){
      float v=acc[i][j]; if(act==1) v=fmaxf(v,0.f);
      C[(size_t)m*ldc+n]=v; } } }
}

// ---------------- dt = softplus(zxb[:, -32:] + bias) ----------------
__global__ void k_dt(const float* __restrict__ zxb, const float* __restrict__ dt_bias, float* __restrict__ dtb){
  int o = blockIdx.x*256+threadIdx.x; // 2048*32
  int r = o>>5, h = o&31;
  float v = zxb[(size_t)r*D_IN_PROJ + 4352 + h] + dt_bias[h];
  dtb[o] = (v>20.f) ? v : log1pf(expf(v));
}

// ---------------- causal depthwise conv (k=4) + silu ----------------
__global__ void k_conv(const float* __restrict__ zxb, const float* __restrict__ cw, const float* __restrict__ cb, float* __restrict__ xbc){
  int o = blockIdx.x*256+threadIdx.x; // 2048*2304
  int ch = o % CONV_DIM; int rt = o / CONV_DIM;
  int b = rt>>10, t = rt&1023;
  float acc = cb[ch];
  for(int k=0;k<4;k++){
    int tt = t-3+k;
    if(tt>=0) acc += zxb[(size_t)(b*1024+tt)*D_IN_PROJ + 2048 + ch]*cw[ch*4+k];
  }
  xbc[o] = acc*sigmoidf_(acc);
}

// ---------------- G^T per (b,c): Gt[s*256+l] = dot(C[l], B[s]) ----------------
__global__ __launch_bounds__(256) void k_gt(const float* __restrict__ xbc, float* __restrict__ Gt){
  int bc = blockIdx.x >> 8;
  int tile = blockIdx.x & 255;
  int l0 = (tile>>4)<<4, s0 = (tile&15)<<4;
  int b = bc>>2, c = bc&3;
  int row0 = b*1024 + c*256;
  __shared__ float Cs[16][130], Bs2[16][130];
  int tid = threadIdx.x;
  for(int i=0;i<8;i++){ int e=tid+i*256; int rr=e>>7, n=e&127;
    Cs[rr][n]  = xbc[(size_t)(row0+l0+rr)*CONV_DIM + 2176 + n];
    Bs2[rr][n] = xbc[(size_t)(row0+s0+rr)*CONV_DIM + 2048 + n];
  }
  __syncthreads();
  int tx = tid&15, ty = tid>>4;
  float acc=0.f;
  for(int n=0;n<128;n++) acc += Cs[tx][n]*Bs2[ty][n];
  Gt[(size_t)bc*65536 + (size_t)(s0+ty)*256 + (l0+tx)] = acc;
}

// ---------------- SSD per (b,c,h) via MFMA: y_diag = M@Xd, states = Xd^T@Bw ----------------
// LDS: xdT[p][l] (64x256 bf16, XOR-swizzled), msb = Ms[l][s'] (256x32) union Bw-chunk[n][l] (32x256)
__global__ __launch_bounds__(256) void k_ssd1m(const float* __restrict__ xbc, const float* __restrict__ dtb,
    const float* __restrict__ A_log, const float* __restrict__ Gt,
    float* __restrict__ ybuf, float* __restrict__ states, float* __restrict__ csb, float* __restrict__ sdA){
  int blk = blockIdx.x;      // (b*4+c)*32+h
  int bc = blk>>5, h = blk&31;
  int b = bc>>2, c = bc&3;
  int row0 = b*1024 + c*256;
  int tid = threadIdx.x;
  __shared__ float cs[256];
  __shared__ float aux[256];                     // dts, then dec
  __shared__ __align__(16) ushort xdT[64*256];   // 32KB
  __shared__ __align__(16) ushort msb[256*32];   // 16KB (union: Ms / Bw chunk)
  float dtv = dtb[(size_t)(row0+tid)*32 + h];
  float Ah = -expf(A_log[h]);
  aux[tid] = dtv;
  cs[tid] = dtv*Ah;
  __syncthreads();
  for(int o=1;o<256;o<<=1){
    float add = (tid>=o)? cs[tid-o] : 0.f;
    __syncthreads();
    cs[tid] += add;
    __syncthreads();
  }
  float csl = cs[tid];
  float cslast = cs[255];
  csb[blk*256+tid] = csl;
  if(tid==0) sdA[blk] = cslast;
  // stage xdT[p][l] = bf16(xs[l,p]*dt[l]), swizzled
  {
    int p = tid&63, g = tid>>6;
    for(int i=0;i<64;i++){
      int l = g + 4*i;
      float v = xbc[(size_t)(row0+l)*CONV_DIM + h*64 + p] * aux[l];
      int off = ((p<<9) + (l<<1)) ^ ((p&7)<<4);
      *(ushort*)((char*)xdT + off) = f2bf(v);
    }
  }
  __syncthreads();
  aux[tid] = expf(cslast - csl);   // dec[l] (dts dead)
  int lane = tid&63, w = tid>>6;
  int fr = lane&15, fq = lane>>4;
  const float* gt = Gt + (size_t)bc*65536;
  f32x4 accY[4][4];
  for(int i=0;i<4;i++)for(int j=0;j<4;j++)accY[i][j]=(f32x4){0.f,0.f,0.f,0.f};
  int nk = 2*(w+1);   // triangular: wave w (rows 64w..) needs k-steps s0<=64w+63
  for(int ks=0;ks<8;ks++){
    int s0 = ks*32;
    // generate Ms[l=tid][s2] for s2=0..31
    for(int s2=0;s2<32;s2++){
      int s = s0+s2;
      float gv = gt[(size_t)s*256 + tid];
      float m = (s<=tid) ? gv*expf(csl - cs[s]) : 0.f;
      int off = ((tid<<6) + (s2<<1)) ^ ((tid&7)<<4);
      *(ushort*)((char*)msb + off) = f2bf(m);
    }
    __syncthreads();
    if(ks < nk){
      short8 af[4], bv[4];
      for(int i=0;i<4;i++){
        int l = w*64 + i*16 + fr;
        int off = ((l<<6) + (fq<<4)) ^ ((l&7)<<4);
        af[i] = *(const short8*)((char*)msb + off);
      }
      for(int j=0;j<4;j++){
        int p = j*16 + fr;
        int off = ((p<<9) + ((s0 + fq*8)<<1)) ^ ((p&7)<<4);
        bv[j] = *(const short8*)((char*)xdT + off);
      }
      for(int i=0;i<4;i++)
        for(int j=0;j<4;j++)
          accY[i][j] = __builtin_amdgcn_mfma_f32_16x16x32_bf16(af[i], bv[j], accY[i][j], 0,0,0);
    }
    __syncthreads();
  }
  // write y_diag
  for(int i=0;i<4;i++){
    int l = 64*w + i*16 + fq*4;
    for(int j=0;j<4;j++){
      int p = j*16 + fr;
      for(int r=0;r<4;r++)
        ybuf[(size_t)(row0+l+r)*2048 + h*64 + p] = accY[i][j][r];
    }
  }
  // states: S[p][n] = sum_l xd[l,p]*dec[l]*B[l,n]; 4 n-chunks of 32
  for(int q=0;q<4;q++){
    __syncthreads();
    {
      int nn = tid&31, g = tid>>5;
      for(int i=0;i<32;i++){
        int l = g + 8*i;
        float v = xbc[(size_t)(row0+l)*CONV_DIM + 2048 + 32*q + nn] * aux[l];
        int off = ((nn<<9) + (l<<1)) ^ ((nn&7)<<4);
        *(ushort*)((char*)msb + off) = f2bf(v);
      }
    }
    __syncthreads();
    f32x4 accS[2];
    accS[0]=(f32x4){0.f,0.f,0.f,0.f}; accS[1]=(f32x4){0.f,0.f,0.f,0.f};
    for(int ks=0;ks<8;ks++){
      int l0 = ks*32;
      short8 aS[2], bS;
      for(int i2=0;i2<2;i2++){
        int p = 32*(w>>1) + i2*16 + fr;
        int off = ((p<<9) + ((l0+fq*8)<<1)) ^ ((p&7)<<4);
        aS[i2] = *(const short8*)((char*)xdT + off);
      }
      {
        int nn = 16*(w&1) + fr;
        int off = ((nn<<9) + ((l0+fq*8)<<1)) ^ ((nn&7)<<4);
        bS = *(const short8*)((char*)msb + off);
      }
      for(int i2=0;i2<2;i2++)
        accS[i2] = __builtin_amdgcn_mfma_f32_16x16x32_bf16(aS[i2], bS, accS[i2], 0,0,0);
    }
    for(int i2=0;i2<2;i2++){
      int p = 32*(w>>1) + i2*16 + fq*4;
      int n = 32*q + 16*(w&1) + fr;
      for(int r=0;r<4;r++)
        states[(size_t)blk*8192 + (size_t)(p+r)*128 + n] = accS[i2][r];
    }
  }
}

// ---------------- chunk scan over c=0..3 ----------------
__global__ __launch_bounds__(256) void k_ssd2(const float* __restrict__ states, const float* __restrict__ sdA, float* __restrict__ prevb){
  int blk = blockIdx.x; // b*32+h
  int b = blk>>5, h = blk&31;
  int tid=threadIdx.x;
  float run[32];
  for(int i=0;i<32;i++) run[i]=0.f;
  for(int c=0;c<4;c++){
    int sblk = (b*4+c)*32+h;
    size_t base = (size_t)sblk*8192;
    float dec = expf(sdA[sblk]);
    for(int i=0;i<32;i++){
      int e = i*256+tid;
      prevb[base+e] = run[i];
      run[i] = (run[i] + states[base+e]) * dec;
    }
  }
}

// ---------------- y_off + xs*D, accumulate into ybuf ----------------
__global__ __launch_bounds__(256) void k_ssd3(const float* __restrict__ xbc, const float* __restrict__ csb,
    const float* __restrict__ prevb, const float* __restrict__ Dp, float* __restrict__ ybuf){
  int blk = blockIdx.x; int bc = blk>>5, h = blk&31; int b=bc>>2, c=bc&3;
  int row0 = b*1024+c*256;
  int tid = threadIdx.x;
  __shared__ float prevs[8192];
  for(int i=0;i<32;i++) prevs[i*256+tid] = prevb[(size_t)blk*8192 + i*256+tid];
  __syncthreads();
  float acc[64];
  for(int p=0;p<64;p++) acc[p]=0.f;
  const float* crow = xbc + (size_t)(row0+tid)*CONV_DIM + 2176;
  for(int n=0;n<128;n++){
    float cv = crow[n];
    for(int p=0;p<64;p++) acc[p] += cv * prevs[p*128+n];
  }
  float e = expf(csb[blk*256+tid]);
  float Dh = Dp[h];
  const float* xsr = xbc + (size_t)(row0+tid)*CONV_DIM + h*64;
  size_t yb = (size_t)(row0+tid)*2048 + h*64;
  for(int p=0;p<64;p++) ybuf[yb+p] += e*acc[p] + xsr[p]*Dh;
}

// ---------------- y = rmsnorm(y * silu(z)) -> bf16 (D=2048) ----------------
__global__ __launch_bounds__(256) void k_gate_norm(const float* __restrict__ y, const float* __restrict__ zxb,
    const float* __restrict__ w, ushort* __restrict__ yb16){
  int r = blockIdx.x;
  const float* zr = zxb + (size_t)r*D_IN_PROJ;
  const float* yr = y + (size_t)r*2048;
  float v[8]; float ss=0.f;
  for(int i=0;i<8;i++){ int c=threadIdx.x+i*256; float z=zr[c]; float g=yr[c]*(z*sigmoidf_(z)); v[i]=g; ss+=g*g; }
  __shared__ float red[4];
  for(int off=32;off;off>>=1) ss += __shfl_down(ss,off,64);
  int wid=threadIdx.x>>6, lane=threadIdx.x&63;
  if(lane==0) red[wid]=ss;
  __syncthreads();
  float tot=red[0]+red[1]+red[2]+red[3];
  float rs=rsqrtf(tot*(1.f/2048.f)+1e-5f);
  for(int i=0;i<8;i++){ int c=threadIdx.x+i*256; yb16[(size_t)r*2048+c]=f2bf(v[i]*rs*w[c]); }
}

// ---------------- scorer stage 2: sigmoid(h1 @ w2) ----------------
__global__ void k_scorer2(const float* __restrict__ h1, const float* __restrict__ w2, float* __restrict__ scores){
  int r = blockIdx.x; int lane = threadIdx.x; // 64 threads
  float s=0.f;
  for(int k=0;k<4;k++){ int c=lane+k*64; s += h1[(size_t)r*256+c]*w2[c]; }
  for(int off=32;off;off>>=1) s += __shfl_down(s,off,64);
  if(lane==0) scores[r]=sigmoidf_(s);
}

// ---------------- serial pool scan: scalars only, record winners ----------------
__global__ void k_pool(const float* __restrict__ scores,
                       float* __restrict__ priosws, int* __restrict__ countws, int* __restrict__ winners){
  __shared__ float scs[BT];
  int lane = threadIdx.x;
  for(int i=lane;i<BT;i+=64) scs[i]=scores[i];
  __syncthreads();
  float prio = 0.f;
  int winner = -1;
  int count = 0;
  float curmin = 0.f; int curargmin = 0;
  for(int b0=0;b0<BT;b0+=64){
    float ownsc = scs[b0+lane];
    for(int j=0;j<64;j++){
      float sc = __shfl(ownsc, j, 64);
      if(sc > 0.5f){
        bool recompute = false;
        if(count < POOL_N){
          if(lane == count){ prio = sc; winner = b0+j; }
          count++;
          if(count == POOL_N) recompute = true;
        } else if(sc > curmin){
          if(lane == curargmin){ prio = sc; winner = b0+j; }
          recompute = true;
        }
        if(recompute){
          float v = (lane < POOL_N)? prio : INFINITY; int idx = lane;
          for(int off=32;off;off>>=1){
            float ov = __shfl_xor(v,off,64);
            int oi = __shfl_xor(idx,off,64);
            if(ov < v || (ov==v && oi<idx)){ v=ov; idx=oi; }
          }
          curmin = v; curargmin = idx;
        }
      }
    }
  }
  if(lane < POOL_N){ winners[lane]=winner; priosws[lane]=prio; }
  if(lane==0) countws[0]=count;
}

// ---------------- gather pool rows from summaries ----------------
__global__ void k_poolg(const float* __restrict__ summ, const int* __restrict__ winners, float* __restrict__ poolb){
  int p = blockIdx.x; int lane = threadIdx.x;
  int wi = winners[p];
  poolb[p*64+lane] = (wi>=0)? summ[(size_t)wi*64+lane] : 0.f;
}

// ---------------- mean(scores) & cond flag ----------------
__global__ __launch_bounds__(256) void k_flags(const float* __restrict__ scores, const int* __restrict__ counti, float* __restrict__ condf){
  float s=0.f;
  for(int i=threadIdx.x;i<BT;i+=256) s += scores[i];
  __shared__ float red[4];
  for(int off=32;off;off>>=1) s += __shfl_down(s,off,64);
  int wid=threadIdx.x>>6, lane=threadIdx.x&63;
  if(lane==0) red[wid]=s;
  __syncthreads();
  if(threadIdx.x==0){
    float mean=(red[0]+red[1]+red[2]+red[3])*(1.f/2048.f);
    condf[0] = (mean>0.3f && counti[0]>0)? 1.f : 0.f;
  }
}

// ---------------- kkT[j*64+p] = (pool @ k_w)[p][j] ----------------
__global__ void k_kk(const float* __restrict__ pool, const float* __restrict__ k_w, float* __restrict__ kkT){
  int o = blockIdx.x*256+threadIdx.x;
  if(o >= 64*POOL_N) return;
  int j = o/POOL_N, p = o%POOL_N;
  float s=0.f;
  for(int k=0;k<64;k++) s += pool[p*64+k]*k_w[k*64+j];
  kkT[j*64+p]=s;
}

// ---------------- vv = pool @ v_w (50x1024) ----------------
__global__ void k_vv(const float* __restrict__ pool, const float* __restrict__ v_w, float* __restrict__ vv){
  int o = blockIdx.x*256+threadIdx.x;
  if(o >= POOL_N*1024) return;
  int p = o>>10, d = o&1023;
  float s=0.f;
  for(int k=0;k<64;k++) s += pool[p*64+k]*v_w[(size_t)k*1024+d];
  vv[o]=s;
}

// ---------------- retrieval: softmax(q·kkT/4, masked) @ vv ----------------
__global__ __launch_bounds__(256) void k_retr(const float* __restrict__ qb, const float* __restrict__ kkT,
   const float* __restrict__ vv, const int* __restrict__ counti, float* __restrict__ retr){
  int r = blockIdx.x;
  __shared__ float qs[64];
  __shared__ float probs[64];
  int tid = threadIdx.x;
  if(tid<64) qs[tid] = qb[(size_t)r*64+tid];
  __syncthreads();
  int count = counti[0];
  if(tid<64){
    float logit = -1e9f;
    if(tid < POOL_N && tid < count){
      float s=0.f;
      for(int k=0;k<64;k++) s += qs[k]*kkT[k*64+tid];
      logit = s*0.25f;
    }
    float m = logit;
    for(int off=32;off;off>>=1) m = fmaxf(m, __shfl_xor(m,off,64));
    float e = expf(logit-m);
    float sum = e;
    for(int off=32;off;off>>=1) sum += __shfl_xor(sum,off,64);
    probs[tid] = e/sum;
  }
  __syncthreads();
  for(int d=tid; d<1024; d+=256){
    float acc=0.f;
    for(int p=0;p<POOL_N;p++) acc += probs[p]*vv[(size_t)p*1024+d];
    retr[(size_t)r*1024+d]=acc;
  }
}

// ---------------- concat [yout, retr] -> bf16 ----------------
__global__ void k_concat(const float* __restrict__ yout, const float* __restrict__ retr, ushort* __restrict__ cc){
  int o = blockIdx.x*256+threadIdx.x; // 2048*2048
  int r = o>>11, c2 = o&2047;
  cc[o] = f2bf((c2<1024)? yout[(size_t)r*1024+c2] : retr[(size_t)r*1024+(c2-1024)]);
}

// ---------------- out = x + yout + cond*sigmoid(g)*retr ----------------
__global__ void k_final(const float* __restrict__ x, const float* __restrict__ yout, const float* __restrict__ g,
   const float* __restrict__ retr, const float* __restrict__ condf, float* __restrict__ out){
  int o = blockIdx.x*256+threadIdx.x; // 2048*1024
  float gv = sigmoidf_(g[o]);
  out[o] = x[o] + yout[o] + condf[0]*gv*retr[o];
}

static inline void gemmf(hipStream_t s, const float*A,const float*B,float*C,int M,int N,int K,int lda,int ldb,int ldc,int act){
  dim3 g((N+63)/64,(M+63)/64);
  hipLaunchKernelGGL(gemm_f32,g,dim3(256),0,s,A,B,C,M,N,K,lda,ldb,ldc,act);
}
static inline void gemmb(hipStream_t s, const ushort*A,const ushort*Bt,float*C,int M,int N,int K,int act){
  dim3 g((N+127)/128, M/128);
  hipLaunchKernelGGL(gemm_bf16,g,dim3(256),0,s,A,Bt,C,M,N,K,act);
}

extern "C" void kernel_launch(void* const* d_in, const int* in_sizes, int n_in,
                              void* d_out, int out_size, void* d_ws, size_t ws_size,
                              hipStream_t stream) {
  const float* x        = (const float*)d_in[0];
  const float* norm_w   = (const float*)d_in[1];
  const float* in_proj_w= (const float*)d_in[2];
  const float* conv_w   = (const float*)d_in[3];
  const float* conv_b   = (const float*)d_in[4];
  const float* dt_bias  = (const float*)d_in[5];
  const float* A_log    = (const float*)d_in[6];
  const float* Dp       = (const float*)d_in[7];
  const float* ssm_norm_w=(const float*)d_in[8];
  const float* out_proj_w=(const float*)d_in[9];
  const float* scorer_w1= (const float*)d_in[10];
  const float* scorer_w2= (const float*)d_in[11];
  const float* summ_w   = (const float*)d_in[12];
  const float* q_w      = (const float*)d_in[13];
  const float* k_w      = (const float*)d_in[14];
  const float* v_w      = (const float*)d_in[15];
  const float* gate_w   = (const float*)d_in[16];
  float* out = (float*)d_out;

  unsigned char* base = (unsigned char*)d_ws;
  size_t off = 0;
  auto FB = [&](size_t bytes)->void*{ void* p = base+off; off = (off+bytes+255)&~(size_t)255; return p; };
  float* zxb   = (float*)FB((size_t)2048*D_IN_PROJ*4);
  float* dtb   = (float*)FB((size_t)2048*32*4);
  float* xbc   = (float*)FB((size_t)2048*CONV_DIM*4);
  float* csb   = (float*)FB((size_t)256*256*4);
  float* sdA   = (float*)FB(1024);
  float* states= (float*)FB((size_t)256*8192*4);
  float* prevb = (float*)FB((size_t)256*8192*4);
  float* ybuf  = (float*)FB((size_t)2048*2048*4);
  float* yout  = (float*)FB((size_t)2048*1024*4);
  float* scores= (float*)FB(2048*4);
  float* summ  = (float*)FB((size_t)2048*64*4);
  float* qb    = (float*)FB((size_t)2048*64*4);
  float* poolb = (float*)FB(POOL_N*64*4);
  float* prios = (float*)FB(256);
  float* miscf = (float*)FB(256);
  int*   counti= (int*)FB(256);
  int*   winners=(int*)FB(256);
  unsigned char* RX = (unsigned char*)FB((size_t)4194304);
  unsigned char* W1 = (unsigned char*)FB((size_t)8978432);

  ushort* xnb   = (ushort*)RX;
  ushort* summT = (ushort*)RX;
  ushort* qT    = (ushort*)(RX + 131072);
  float*  h1    = (float*) (RX + 262144);
  float*  kkT   = (float*) (RX + 2359296);
  float*  vvb   = (float*) (RX + 2375680);
  ushort* inT   = (ushort*)W1;
  ushort* outT  = (ushort*)W1;
  ushort* gateT = (ushort*)(W1 + 4194304);
  ushort* sc1T  = (ushort*)(W1 + 8388608);
  float*  Gt    = yout;
  ushort* ybf   = (ushort*)prevb;
  float*  gbuf  = prevb;
  float*  retr  = states;
  ushort* ccb   = (ushort*)ybuf;
  ushort* youtb = (ushort*)((unsigned char*)ybuf + 8388608);

  hipLaunchKernelGGL(k_transpose_cvt, dim3(137,32), dim3(256), 0, stream, in_proj_w, inT, 1024, 4384);
  k_rmsnorm_x<<<2048,256,0,stream>>>(x, norm_w, xnb);
  gemmb(stream, xnb, inT, zxb, 2048, D_IN_PROJ, 1024, 0);
  hipLaunchKernelGGL(k_transpose_cvt, dim3(32,64), dim3(256), 0, stream, out_proj_w, outT, 2048, 1024);
  hipLaunchKernelGGL(k_transpose_cvt, dim3(32,64), dim3(256), 0, stream, gate_w, gateT, 2048, 1024);
  hipLaunchKernelGGL(k_transpose_cvt, dim3(8,32), dim3(256), 0, stream, scorer_w1, sc1T, 1024, 256);
  hipLaunchKernelGGL(k_transpose_cvt, dim3(2,32), dim3(256), 0, stream, summ_w, summT, 1024, 64);
  hipLaunchKernelGGL(k_transpose_cvt, dim3(2,32), dim3(256), 0, stream, q_w, qT, 1024, 64);
  k_dt<<<256,256,0,stream>>>(zxb, dt_bias, dtb);
  k_conv<<<18432,256,0,stream>>>(zxb, conv_w, conv_b, xbc);
  k_gt<<<2048,256,0,stream>>>(xbc, Gt);
  k_ssd1m<<<256,256,0,stream>>>(xbc, dtb, A_log, Gt, ybuf, states, csb, sdA);
  k_ssd2<<<64,256,0,stream>>>(states, sdA, prevb);
  k_ssd3<<<256,256,0,stream>>>(xbc, csb, prevb, Dp, ybuf);
  k_gate_norm<<<2048,256,0,stream>>>(ybuf, zxb, ssm_norm_w, ybf);
  gemmb(stream, ybf, outT, yout, 2048, 1024, 2048, 0);
  k_cvt_bf16<<<2048,256,0,stream>>>(yout, youtb, 2048*1024/4);
  gemmf(stream, yout, scorer_w1, h1, 2048, 256, 1024, 1024, 256, 256, 1);
  k_scorer2<<<2048,64,0,stream>>>(h1, scorer_w2, scores);
  gemmb(stream, youtb, summT, summ, 2048, 64, 1024, 0);
  gemmb(stream, youtb, qT, qb, 2048, 64, 1024, 0);
  k_pool<<<1,64,0,stream>>>(scores, prios, counti, winners);
  k_poolg<<<POOL_N,64,0,stream>>>(summ, winners, poolb);
  k_flags<<<1,256,0,stream>>>(scores, counti, miscf);
  k_kk<<<(64*POOL_N+255)/256,256,0,stream>>>(poolb, k_w, kkT);
  k_vv<<<(POOL_N*1024+255)/256,256,0,stream>>>(poolb, v_w, vvb);
  k_retr<<<2048,256,0,stream>>>(qb, kkT, vvb, counti, retr);
  k_concat<<<16384,256,0,stream>>>(yout, retr, ccb);
  gemmb(stream, ccb, gateT, gbuf, 2048, 1024, 2048, 0);
  k_final<<<8192,256,0,stream>>>(x, yout, gbuf, retr, miscf, out);
  (void)in_sizes; (void)n_in; (void)out_size; (void)ws_size;
}

// Round 6
// 721.998 us; speedup vs baseline: 3.3573x; 1.2203x over previous
//
#include <hip/hip_runtime.h>
#include <math.h>

#define NHEADS 32
#define D_INNER 2048
#define CONV_DIM 2304
#define D_IN_PROJ 4384
#define POOL_N 50
#define BT 2048

typedef __attribute__((ext_vector_type(8))) short short8;
typedef __attribute__((ext_vector_type(4))) float f32x4;

__device__ __forceinline__ float sigmoidf_(float x){ return 1.f/(1.f+expf(-x)); }
__device__ __forceinline__ ushort f2bf(float f){
  union{float f; unsigned u;} v; v.f=f;
  unsigned r = v.u + 0x7fffu + ((v.u>>16)&1u);
  return (ushort)(r>>16);
}

// ---------------- RMSNorm on x (D=1024) -> bf16 ----------------
__global__ __launch_bounds__(256) void k_rmsnorm_x(const float* __restrict__ x, const float* __restrict__ w, ushort* __restrict__ xn){
  int r = blockIdx.x;
  const float* xr = x + (size_t)r*1024;
  float v[4]; float ss=0.f;
  for(int i=0;i<4;i++){ v[i]=xr[threadIdx.x+i*256]; ss+=v[i]*v[i]; }
  __shared__ float red[4];
  for(int off=32;off;off>>=1) ss += __shfl_down(ss,off,64);
  int wid=threadIdx.x>>6, lane=threadIdx.x&63;
  if(lane==0) red[wid]=ss;
  __syncthreads();
  float tot=red[0]+red[1]+red[2]+red[3];
  float rs=rsqrtf(tot*(1.f/1024.f)+1e-5f);
  for(int i=0;i<4;i++){ int c=threadIdx.x+i*256; xn[(size_t)r*1024+c]=f2bf(v[i]*rs*w[c]); }
}

// ---------------- transpose + cvt: src f32 [R][C] -> dst bf16 [C][R] ----------------
__global__ __launch_bounds__(256) void k_transpose_cvt(const float* __restrict__ src, ushort* __restrict__ dst, int R, int C){
  __shared__ float tile[32][33];
  int c0 = blockIdx.x*32, r0 = blockIdx.y*32;
  int tx = threadIdx.x&31, ty = threadIdx.x>>5;
  for(int i=0;i<4;i++){ int r = r0+ty+i*8; tile[ty+i*8][tx] = src[(size_t)r*C + c0+tx]; }
  __syncthreads();
  for(int i=0;i<4;i++){ int c = c0+ty+i*8; dst[(size_t)c*R + r0+tx] = f2bf(tile[tx][ty+i*8]); }
}

// ---------------- f32 -> bf16 elementwise (n multiple of 4) ----------------
__global__ void k_cvt_bf16(const float* __restrict__ s, ushort* __restrict__ d, int n4){
  int i = blockIdx.x*256+threadIdx.x;
  if(i<n4){
    float4 v = ((const float4*)s)[i];
    ushort4 o; o.x=f2bf(v.x); o.y=f2bf(v.y); o.z=f2bf(v.z); o.w=f2bf(v.w);
    ((ushort4*)d)[i] = o;
  }
}

// ---------------- bf16 MFMA GEMM: C[M,N] f32 = A[M,K]bf16 @ Bt[N,K]bf16^T ----------------
__global__ __launch_bounds__(256) void gemm_bf16(const ushort* __restrict__ A, const ushort* __restrict__ Bt,
    float* __restrict__ C, int M, int N, int K, int act){
  __shared__ __align__(16) ushort As[128*32];
  __shared__ __align__(16) ushort Bs[128*32];
  int n0 = blockIdx.x*128, m0 = blockIdx.y*128;
  int tid = threadIdx.x;
  int lane = tid&63, w = tid>>6;
  int wr = (w>>1)*64, wc = (w&1)*64;
  f32x4 acc[4][4];
  for(int i=0;i<4;i++)for(int j=0;j<4;j++)acc[i][j]=(f32x4){0.f,0.f,0.f,0.f};
  int srow = tid>>2, skb = (tid&3)*8;
  const ushort* Ap0 = A + (size_t)(m0+srow)*K + skb;
  const ushort* Ap1 = A + (size_t)(m0+srow+64)*K + skb;
  bool bv0 = (n0+srow) < N, bv1 = (n0+srow+64) < N;
  const ushort* Bp0 = Bt + (size_t)(bv0 ? (n0+srow)    : 0)*K + skb;
  const ushort* Bp1 = Bt + (size_t)(bv1 ? (n0+srow+64) : 0)*K + skb;
  int fr = lane&15, fko = (lane>>4)*8;
  for(int k0=0;k0<K;k0+=32){
    uint4 a0 = *(const uint4*)(Ap0 + k0);
    uint4 a1 = *(const uint4*)(Ap1 + k0);
    uint4 b0 = bv0 ? *(const uint4*)(Bp0 + k0) : make_uint4(0u,0u,0u,0u);
    uint4 b1 = bv1 ? *(const uint4*)(Bp1 + k0) : make_uint4(0u,0u,0u,0u);
    *(uint4*)(As + srow*32 + skb)      = a0;
    *(uint4*)(As + (srow+64)*32 + skb) = a1;
    *(uint4*)(Bs + srow*32 + skb)      = b0;
    *(uint4*)(Bs + (srow+64)*32 + skb) = b1;
    __syncthreads();
    short8 af[4], bfr[4];
    for(int i=0;i<4;i++) af[i]  = *(const short8*)(As + (wr+i*16+fr)*32 + fko);
    for(int j=0;j<4;j++) bfr[j] = *(const short8*)(Bs + (wc+j*16+fr)*32 + fko);
    for(int i=0;i<4;i++)
      for(int j=0;j<4;j++)
        acc[i][j] = __builtin_amdgcn_mfma_f32_16x16x32_bf16(af[i], bfr[j], acc[i][j], 0,0,0);
    __syncthreads();
  }
  int rbase = m0 + wr + (lane>>4)*4;
  for(int i=0;i<4;i++){
    for(int j=0;j<4;j++){
      int col = n0 + wc + j*16 + fr;
      if(col < N){
        for(int r=0;r<4;r++){
          float v = acc[i][j][r];
          if(act) v = fmaxf(v,0.f);
          C[(size_t)(rbase + i*16 + r)*N + col] = v;
        }
      }
    }
  }
}

// ---------------- generic f32 GEMM (kept for scorer stage-1) ----------------
__global__ __launch_bounds__(256) void gemm_f32(const float* __restrict__ A, const float* __restrict__ B, float* __restrict__ C,
    int M,int N,int K,int lda,int ldb,int ldc,int act){
  __shared__ float As[16][65];
  __shared__ float Bs[16][65];
  int n0 = blockIdx.x*64, m0 = blockIdx.y*64;
  int tid = threadIdx.x;
  int tx = tid&15, ty = tid>>4;
  float acc[4][4]={};
  for(int k0=0;k0<K;k0+=16){
    for(int i=0;i<4;i++){ int e=tid+i*256; int m=e>>4,k=e&15;
      As[k][m] = (m0+m<M) ? A[(size_t)(m0+m)*lda + k0+k] : 0.f; }
    for(int i=0;i<4;i++){ int e=tid+i*256; int k=e>>6,n=e&63;
      Bs[k][n] = (n0+n<N) ? B[(size_t)(k0+k)*ldb + n0+n] : 0.f; }
    __syncthreads();
    for(int k=0;k<16;k++){
      float a[4],b[4];
      for(int i=0;i<4;i++) a[i]=As[k][ty*4+i];
      for(int j=0;j<4;j++) b[j]=Bs[k][tx*4+j];
      for(int i=0;i<4;i++) for(int j=0;j<4;j++) acc[i][j] += a[i]*b[j];
    }
    __syncthreads();
  }
  for(int i=0;i<4;i++){ int m=m0+ty*4+i; if(m>=M) continue;
    for(int j=0;j<4;j++){ int n=n0+tx*4+j; if(n<N){
      float v=acc[i][j]; if(act==1) v=fmaxf(v,0.f);
      C[(size_t)m*ldc+n]=v; } } }
}

// ---------------- dt = softplus(zxb[:, -32:] + bias) ----------------
__global__ void k_dt(const float* __restrict__ zxb, const float* __restrict__ dt_bias, float* __restrict__ dtb){
  int o = blockIdx.x*256+threadIdx.x; // 2048*32
  int r = o>>5, h = o&31;
  float v = zxb[(size_t)r*D_IN_PROJ + 4352 + h] + dt_bias[h];
  dtb[o] = (v>20.f) ? v : log1pf(expf(v));
}

// ---------------- causal depthwise conv (k=4) + silu ----------------
__global__ void k_conv(const float* __restrict__ zxb, const float* __restrict__ cw, const float* __restrict__ cb, float* __restrict__ xbc){
  int o = blockIdx.x*256+threadIdx.x; // 2048*2304
  int ch = o % CONV_DIM; int rt = o / CONV_DIM;
  int b = rt>>10, t = rt&1023;
  float acc = cb[ch];
  for(int k=0;k<4;k++){
    int tt = t-3+k;
    if(tt>=0) acc += zxb[(size_t)(b*1024+tt)*D_IN_PROJ + 2048 + ch]*cw[ch*4+k];
  }
  xbc[o] = acc*sigmoidf_(acc);
}

// ---------------- G^T per (b,c): Gt[s*256+l] = dot(C[l], B[s]) ----------------
__global__ __launch_bounds__(256) void k_gt(const float* __restrict__ xbc, float* __restrict__ Gt){
  int bc = blockIdx.x >> 8;
  int tile = blockIdx.x & 255;
  int l0 = (tile>>4)<<4, s0 = (tile&15)<<4;
  int b = bc>>2, c = bc&3;
  int row0 = b*1024 + c*256;
  __shared__ float Cs[16][130], Bs2[16][130];
  int tid = threadIdx.x;
  for(int i=0;i<8;i++){ int e=tid+i*256; int rr=e>>7, n=e&127;
    Cs[rr][n]  = xbc[(size_t)(row0+l0+rr)*CONV_DIM + 2176 + n];
    Bs2[rr][n] = xbc[(size_t)(row0+s0+rr)*CONV_DIM + 2048 + n];
  }
  __syncthreads();
  int tx = tid&15, ty = tid>>4;
  float acc=0.f;
  for(int n=0;n<128;n++) acc += Cs[tx][n]*Bs2[ty][n];
  Gt[(size_t)bc*65536 + (size_t)(s0+ty)*256 + (l0+tx)] = acc;
}

// ---------------- SSD per (b,c,h) via MFMA ----------------
__global__ __launch_bounds__(256) void k_ssd1m(const float* __restrict__ xbc, const float* __restrict__ dtb,
    const float* __restrict__ A_log, const float* __restrict__ Gt,
    float* __restrict__ ybuf, float* __restrict__ states, float* __restrict__ csb, float* __restrict__ sdA){
  int blk = blockIdx.x;      // (b*4+c)*32+h
  int bc = blk>>5, h = blk&31;
  int b = bc>>2, c = bc&3;
  int row0 = b*1024 + c*256;
  int tid = threadIdx.x;
  __shared__ float cs[256];
  __shared__ float aux[256];
  __shared__ __align__(16) ushort xdT[64*256];
  __shared__ __align__(16) ushort msb[256*32];
  float dtv = dtb[(size_t)(row0+tid)*32 + h];
  float Ah = -expf(A_log[h]);
  aux[tid] = dtv;
  cs[tid] = dtv*Ah;
  __syncthreads();
  for(int o=1;o<256;o<<=1){
    float add = (tid>=o)? cs[tid-o] : 0.f;
    __syncthreads();
    cs[tid] += add;
    __syncthreads();
  }
  float csl = cs[tid];
  float cslast = cs[255];
  csb[blk*256+tid] = csl;
  if(tid==0) sdA[blk] = cslast;
  {
    int p = tid&63, g = tid>>6;
    for(int i=0;i<64;i++){
      int l = g + 4*i;
      float v = xbc[(size_t)(row0+l)*CONV_DIM + h*64 + p] * aux[l];
      int off = ((p<<9) + (l<<1)) ^ ((p&7)<<4);
      *(ushort*)((char*)xdT + off) = f2bf(v);
    }
  }
  __syncthreads();
  aux[tid] = expf(cslast - csl);
  int lane = tid&63, w = tid>>6;
  int fr = lane&15, fq = lane>>4;
  const float* gt = Gt + (size_t)bc*65536;
  f32x4 accY[4][4];
  for(int i=0;i<4;i++)for(int j=0;j<4;j++)accY[i][j]=(f32x4){0.f,0.f,0.f,0.f};
  int nk = 2*(w+1);
  for(int ks=0;ks<8;ks++){
    int s0 = ks*32;
    for(int s2=0;s2<32;s2++){
      int s = s0+s2;
      float gv = gt[(size_t)s*256 + tid];
      float m = (s<=tid) ? gv*expf(csl - cs[s]) : 0.f;
      int off = ((tid<<6) + (s2<<1)) ^ ((tid&7)<<4);
      *(ushort*)((char*)msb + off) = f2bf(m);
    }
    __syncthreads();
    if(ks < nk){
      short8 af[4], bv[4];
      for(int i=0;i<4;i++){
        int l = w*64 + i*16 + fr;
        int off = ((l<<6) + (fq<<4)) ^ ((l&7)<<4);
        af[i] = *(const short8*)((char*)msb + off);
      }
      for(int j=0;j<4;j++){
        int p = j*16 + fr;
        int off = ((p<<9) + ((s0 + fq*8)<<1)) ^ ((p&7)<<4);
        bv[j] = *(const short8*)((char*)xdT + off);
      }
      for(int i=0;i<4;i++)
        for(int j=0;j<4;j++)
          accY[i][j] = __builtin_amdgcn_mfma_f32_16x16x32_bf16(af[i], bv[j], accY[i][j], 0,0,0);
    }
    __syncthreads();
  }
  for(int i=0;i<4;i++){
    int l = 64*w + i*16 + fq*4;
    for(int j=0;j<4;j++){
      int p = j*16 + fr;
      for(int r=0;r<4;r++)
        ybuf[(size_t)(row0+l+r)*2048 + h*64 + p] = accY[i][j][r];
    }
  }
  for(int q=0;q<4;q++){
    __syncthreads();
    {
      int nn = tid&31, g = tid>>5;
      for(int i=0;i<32;i++){
        int l = g + 8*i;
        float v = xbc[(size_t)(row0+l)*CONV_DIM + 2048 + 32*q + nn] * aux[l];
        int off = ((nn<<9) + (l<<1)) ^ ((nn&7)<<4);
        *(ushort*)((char*)msb + off) = f2bf(v);
      }
    }
    __syncthreads();
    f32x4 accS[2];
    accS[0]=(f32x4){0.f,0.f,0.f,0.f}; accS[1]=(f32x4){0.f,0.f,0.f,0.f};
    for(int ks=0;ks<8;ks++){
      int l0 = ks*32;
      short8 aS[2], bS;
      for(int i2=0;i2<2;i2++){
        int p = 32*(w>>1) + i2*16 + fr;
        int off = ((p<<9) + ((l0+fq*8)<<1)) ^ ((p&7)<<4);
        aS[i2] = *(const short8*)((char*)xdT + off);
      }
      {
        int nn = 16*(w&1) + fr;
        int off = ((nn<<9) + ((l0+fq*8)<<1)) ^ ((nn&7)<<4);
        bS = *(const short8*)((char*)msb + off);
      }
      for(int i2=0;i2<2;i2++)
        accS[i2] = __builtin_amdgcn_mfma_f32_16x16x32_bf16(aS[i2], bS, accS[i2], 0,0,0);
    }
    for(int i2=0;i2<2;i2++){
      int p = 32*(w>>1) + i2*16 + fq*4;
      int n = 32*q + 16*(w&1) + fr;
      for(int r=0;r<4;r++)
        states[(size_t)blk*8192 + (size_t)(p+r)*128 + n] = accS[i2][r];
    }
  }
}

// ---------------- chunk scan over c=0..3 (1 element per thread, full grid) ----------------
__global__ __launch_bounds__(256) void k_ssd2(const float* __restrict__ states, const float* __restrict__ sdA, float* __restrict__ prevb){
  int idx = blockIdx.x*256 + threadIdx.x;   // 2*32*8192 = 524288 total
  int e = idx & 8191;
  int h = (idx >> 13) & 31;
  int b = idx >> 18;
  float run = 0.f;
  for(int c=0;c<4;c++){
    int sblk = (b*4+c)*32 + h;
    size_t base = (size_t)sblk*8192 + e;
    prevb[base] = run;
    run = (run + states[base]) * expf(sdA[sblk]);
  }
}

// ---------------- y_off + xs*D, accumulate into ybuf ----------------
__global__ __launch_bounds__(256) void k_ssd3(const float* __restrict__ xbc, const float* __restrict__ csb,
    const float* __restrict__ prevb, const float* __restrict__ Dp, float* __restrict__ ybuf){
  int blk = blockIdx.x; int bc = blk>>5, h = blk&31; int b=bc>>2, c=bc&3;
  int row0 = b*1024+c*256;
  int tid = threadIdx.x;
  __shared__ float prevs[8192];
  for(int i=0;i<32;i++) prevs[i*256+tid] = prevb[(size_t)blk*8192 + i*256+tid];
  __syncthreads();
  float acc[64];
  for(int p=0;p<64;p++) acc[p]=0.f;
  const float* crow = xbc + (size_t)(row0+tid)*CONV_DIM + 2176;
  for(int n=0;n<128;n++){
    float cv = crow[n];
    for(int p=0;p<64;p++) acc[p] += cv * prevs[p*128+n];
  }
  float e = expf(csb[blk*256+tid]);
  float Dh = Dp[h];
  const float* xsr = xbc + (size_t)(row0+tid)*CONV_DIM + h*64;
  size_t yb = (size_t)(row0+tid)*2048 + h*64;
  for(int p=0;p<64;p++) ybuf[yb+p] += e*acc[p] + xsr[p]*Dh;
}

// ---------------- y = rmsnorm(y * silu(z)) -> bf16 (D=2048) ----------------
__global__ __launch_bounds__(256) void k_gate_norm(const float* __restrict__ y, const float* __restrict__ zxb,
    const float* __restrict__ w, ushort* __restrict__ yb16){
  int r = blockIdx.x;
  const float* zr = zxb + (size_t)r*D_IN_PROJ;
  const float* yr = y + (size_t)r*2048;
  float v[8]; float ss=0.f;
  for(int i=0;i<8;i++){ int c=threadIdx.x+i*256; float z=zr[c]; float g=yr[c]*(z*sigmoidf_(z)); v[i]=g; ss+=g*g; }
  __shared__ float red[4];
  for(int off=32;off;off>>=1) ss += __shfl_down(ss,off,64);
  int wid=threadIdx.x>>6, lane=threadIdx.x&63;
  if(lane==0) red[wid]=ss;
  __syncthreads();
  float tot=red[0]+red[1]+red[2]+red[3];
  float rs=rsqrtf(tot*(1.f/2048.f)+1e-5f);
  for(int i=0;i<8;i++){ int c=threadIdx.x+i*256; yb16[(size_t)r*2048+c]=f2bf(v[i]*rs*w[c]); }
}

// ---------------- scorer stage 2: sigmoid(h1 @ w2) ----------------
__global__ void k_scorer2(const float* __restrict__ h1, const float* __restrict__ w2, float* __restrict__ scores){
  int r = blockIdx.x; int lane = threadIdx.x; // 64 threads
  float s=0.f;
  for(int k=0;k<4;k++){ int c=lane+k*64; s += h1[(size_t)r*256+c]*w2[c]; }
  for(int off=32;off;off>>=1) s += __shfl_down(s,off,64);
  if(lane==0) scores[r]=sigmoidf_(s);
}

// ---------------- serial pool scan: ballot-filtered, exact semantics; + flags ----------------
__global__ void k_pool(const float* __restrict__ scores,
                       float* __restrict__ priosws, int* __restrict__ countws, int* __restrict__ winners,
                       float* __restrict__ condf){
  __shared__ float scs[BT];
  int lane = threadIdx.x;
  float ssum = 0.f;
  for(int i=lane;i<BT;i+=64){ float s0 = scores[i]; scs[i]=s0; ssum += s0; }
  __syncthreads();
  float prio = 0.f;
  int winner = -1;
  int count = 0;
  float curmin = 0.f; int curargmin = 0;    // valid once count==POOL_N
  for(int b0=0;b0<BT;b0+=64){
    float own = scs[b0+lane];
    unsigned long long mask = (count < POOL_N) ? __ballot(own > 0.5f)
                                               : __ballot(own > curmin);
    while(mask){
      int j = __ffsll(mask) - 1;
      mask &= mask - 1ull;
      float sc = __shfl(own, j, 64);
      if(count < POOL_N){
        if(lane == count){ prio = sc; winner = b0+j; }
        count++;
        if(count == POOL_N){
          float v = (lane < POOL_N)? prio : INFINITY; int idx = lane;
          for(int off=32;off;off>>=1){
            float ov = __shfl_xor(v,off,64);
            int oi = __shfl_xor(idx,off,64);
            if(ov < v || (ov==v && oi<idx)){ v=ov; idx=oi; }
          }
          curmin = v; curargmin = idx;
        }
      } else if(sc > curmin){
        if(lane == curargmin){ prio = sc; winner = b0+j; }
        float v = (lane < POOL_N)? prio : INFINITY; int idx = lane;
        for(int off=32;off;off>>=1){
          float ov = __shfl_xor(v,off,64);
          int oi = __shfl_xor(idx,off,64);
          if(ov < v || (ov==v && oi<idx)){ v=ov; idx=oi; }
        }
        curmin = v; curargmin = idx;
      }
    }
  }
  if(lane < POOL_N){ winners[lane]=winner; priosws[lane]=prio; }
  for(int off=32;off;off>>=1) ssum += __shfl_xor(ssum,off,64);
  if(lane==0){
    countws[0]=count;
    float mean = ssum*(1.f/2048.f);
    condf[0] = (mean>0.3f && count>0)? 1.f : 0.f;
  }
}

// ---------------- gather pool rows from summaries ----------------
__global__ void k_poolg(const float* __restrict__ summ, const int* __restrict__ winners, float* __restrict__ poolb){
  int p = blockIdx.x; int lane = threadIdx.x;
  int wi = winners[p];
  poolb[p*64+lane] = (wi>=0)? summ[(size_t)wi*64+lane] : 0.f;
}

// ---------------- kkT[j*64+p] = (pool @ k_w)[p][j] ----------------
__global__ void k_kk(const float* __restrict__ pool, const float* __restrict__ k_w, float* __restrict__ kkT){
  int o = blockIdx.x*256+threadIdx.x;
  if(o >= 64*POOL_N) return;
  int j = o/POOL_N, p = o%POOL_N;
  float s=0.f;
  for(int k=0;k<64;k++) s += pool[p*64+k]*k_w[k*64+j];
  kkT[j*64+p]=s;
}

// ---------------- vv = pool @ v_w (50x1024) ----------------
__global__ void k_vv(const float* __restrict__ pool, const float* __restrict__ v_w, float* __restrict__ vv){
  int o = blockIdx.x*256+threadIdx.x;
  if(o >= POOL_N*1024) return;
  int p = o>>10, d = o&1023;
  float s=0.f;
  for(int k=0;k<64;k++) s += pool[p*64+k]*v_w[(size_t)k*1024+d];
  vv[o]=s;
}

// ---------------- retrieval: softmax(q·kkT/4, masked) @ vv ----------------
__global__ __launch_bounds__(256) void k_retr(const float* __restrict__ qb, const float* __restrict__ kkT,
   const float* __restrict__ vv, const int* __restrict__ counti, float* __restrict__ retr){
  int r = blockIdx.x;
  __shared__ float qs[64];
  __shared__ float probs[64];
  int tid = threadIdx.x;
  if(tid<64) qs[tid] = qb[(size_t)r*64+tid];
  __syncthreads();
  int count = counti[0];
  if(tid<64){
    float logit = -1e9f;
    if(tid < POOL_N && tid < count){
      float s=0.f;
      for(int k=0;k<64;k++) s += qs[k]*kkT[k*64+tid];
      logit = s*0.25f;
    }
    float m = logit;
    for(int off=32;off;off>>=1) m = fmaxf(m, __shfl_xor(m,off,64));
    float e = expf(logit-m);
    float sum = e;
    for(int off=32;off;off>>=1) sum += __shfl_xor(sum,off,64);
    probs[tid] = e/sum;
  }
  __syncthreads();
  for(int d=tid; d<1024; d+=256){
    float acc=0.f;
    for(int p=0;p<POOL_N;p++) acc += probs[p]*vv[(size_t)p*1024+d];
    retr[(size_t)r*1024+d]=acc;
  }
}

// ---------------- concat [yout, retr] -> bf16 ----------------
__global__ void k_concat(const float* __restrict__ yout, const float* __restrict__ retr, ushort* __restrict__ cc){
  int o = blockIdx.x*256+threadIdx.x; // 2048*2048
  int r = o>>11, c2 = o&2047;
  cc[o] = f2bf((c2<1024)? yout[(size_t)r*1024+c2] : retr[(size_t)r*1024+(c2-1024)]);
}

// ---------------- out = x + yout + cond*sigmoid(g)*retr ----------------
__global__ void k_final(const float* __restrict__ x, const float* __restrict__ yout, const float* __restrict__ g,
   const float* __restrict__ retr, const float* __restrict__ condf, float* __restrict__ out){
  int o = blockIdx.x*256+threadIdx.x; // 2048*1024
  float gv = sigmoidf_(g[o]);
  out[o] = x[o] + yout[o] + condf[0]*gv*retr[o];
}

static inline void gemmf(hipStream_t s, const float*A,const float*B,float*C,int M,int N,int K,int lda,int ldb,int ldc,int act){
  dim3 g((N+63)/64,(M+63)/64);
  hipLaunchKernelGGL(gemm_f32,g,dim3(256),0,s,A,B,C,M,N,K,lda,ldb,ldc,act);
}
static inline void gemmb(hipStream_t s, const ushort*A,const ushort*Bt,float*C,int M,int N,int K,int act){
  dim3 g((N+127)/128, M/128);
  hipLaunchKernelGGL(gemm_bf16,g,dim3(256),0,s,A,Bt,C,M,N,K,act);
}

extern "C" void kernel_launch(void* const* d_in, const int* in_sizes, int n_in,
                              void* d_out, int out_size, void* d_ws, size_t ws_size,
                              hipStream_t stream) {
  const float* x        = (const float*)d_in[0];
  const float* norm_w   = (const float*)d_in[1];
  const float* in_proj_w= (const float*)d_in[2];
  const float* conv_w   = (const float*)d_in[3];
  const float* conv_b   = (const float*)d_in[4];
  const float* dt_bias  = (const float*)d_in[5];
  const float* A_log    = (const float*)d_in[6];
  const float* Dp       = (const float*)d_in[7];
  const float* ssm_norm_w=(const float*)d_in[8];
  const float* out_proj_w=(const float*)d_in[9];
  const float* scorer_w1= (const float*)d_in[10];
  const float* scorer_w2= (const float*)d_in[11];
  const float* summ_w   = (const float*)d_in[12];
  const float* q_w      = (const float*)d_in[13];
  const float* k_w      = (const float*)d_in[14];
  const float* v_w      = (const float*)d_in[15];
  const float* gate_w   = (const float*)d_in[16];
  float* out = (float*)d_out;

  unsigned char* base = (unsigned char*)d_ws;
  size_t off = 0;
  auto FB = [&](size_t bytes)->void*{ void* p = base+off; off = (off+bytes+255)&~(size_t)255; return p; };
  float* zxb   = (float*)FB((size_t)2048*D_IN_PROJ*4);
  float* dtb   = (float*)FB((size_t)2048*32*4);
  float* xbc   = (float*)FB((size_t)2048*CONV_DIM*4);
  float* csb   = (float*)FB((size_t)256*256*4);
  float* sdA   = (float*)FB(1024);
  float* states= (float*)FB((size_t)256*8192*4);
  float* prevb = (float*)FB((size_t)256*8192*4);
  float* ybuf  = (float*)FB((size_t)2048*2048*4);
  float* yout  = (float*)FB((size_t)2048*1024*4);
  float* scores= (float*)FB(2048*4);
  float* summ  = (float*)FB((size_t)2048*64*4);
  float* qb    = (float*)FB((size_t)2048*64*4);
  float* poolb = (float*)FB(POOL_N*64*4);
  float* prios = (float*)FB(256);
  float* miscf = (float*)FB(256);
  int*   counti= (int*)FB(256);
  int*   winners=(int*)FB(256);
  unsigned char* RX = (unsigned char*)FB((size_t)4194304);
  unsigned char* W1 = (unsigned char*)FB((size_t)8978432);

  ushort* xnb   = (ushort*)RX;
  ushort* summT = (ushort*)RX;
  ushort* qT    = (ushort*)(RX + 131072);
  float*  h1    = (float*) (RX + 262144);
  float*  kkT   = (float*) (RX + 2359296);
  float*  vvb   = (float*) (RX + 2375680);
  ushort* inT   = (ushort*)W1;
  ushort* outT  = (ushort*)W1;
  ushort* gateT = (ushort*)(W1 + 4194304);
  ushort* sc1T  = (ushort*)(W1 + 8388608);
  float*  Gt    = yout;
  ushort* ybf   = (ushort*)prevb;
  float*  gbuf  = prevb;
  float*  retr  = states;
  ushort* ccb   = (ushort*)ybuf;
  ushort* youtb = (ushort*)((unsigned char*)ybuf + 8388608);

  hipLaunchKernelGGL(k_transpose_cvt, dim3(137,32), dim3(256), 0, stream, in_proj_w, inT, 1024, 4384);
  k_rmsnorm_x<<<2048,256,0,stream>>>(x, norm_w, xnb);
  gemmb(stream, xnb, inT, zxb, 2048, D_IN_PROJ, 1024, 0);
  hipLaunchKernelGGL(k_transpose_cvt, dim3(32,64), dim3(256), 0, stream, out_proj_w, outT, 2048, 1024);
  hipLaunchKernelGGL(k_transpose_cvt, dim3(32,64), dim3(256), 0, stream, gate_w, gateT, 2048, 1024);
  hipLaunchKernelGGL(k_transpose_cvt, dim3(8,32), dim3(256), 0, stream, scorer_w1, sc1T, 1024, 256);
  hipLaunchKernelGGL(k_transpose_cvt, dim3(2,32), dim3(256), 0, stream, summ_w, summT, 1024, 64);
  hipLaunchKernelGGL(k_transpose_cvt, dim3(2,32), dim3(256), 0, stream, q_w, qT, 1024, 64);
  k_dt<<<256,256,0,stream>>>(zxb, dt_bias, dtb);
  k_conv<<<18432,256,0,stream>>>(zxb, conv_w, conv_b, xbc);
  k_gt<<<2048,256,0,stream>>>(xbc, Gt);
  k_ssd1m<<<256,256,0,stream>>>(xbc, dtb, A_log, Gt, ybuf, states, csb, sdA);
  k_ssd2<<<2048,256,0,stream>>>(states, sdA, prevb);
  k_ssd3<<<256,256,0,stream>>>(xbc, csb, prevb, Dp, ybuf);
  k_gate_norm<<<2048,256,0,stream>>>(ybuf, zxb, ssm_norm_w, ybf);
  gemmb(stream, ybf, outT, yout, 2048, 1024, 2048, 0);
  k_cvt_bf16<<<2048,256,0,stream>>>(yout, youtb, 2048*1024/4);
  gemmf(stream, yout, scorer_w1, h1, 2048, 256, 1024, 1024, 256, 256, 1);
  k_scorer2<<<2048,64,0,stream>>>(h1, scorer_w2, scores);
  gemmb(stream, youtb, summT, summ, 2048, 64, 1024, 0);
  gemmb(stream, youtb, qT, qb, 2048, 64, 1024, 0);
  k_pool<<<1,64,0,stream>>>(scores, prios, counti, winners, miscf);
  k_poolg<<<POOL_N,64,0,stream>>>(summ, winners, poolb);
  k_kk<<<(64*POOL_N+255)/256,256,0,stream>>>(poolb, k_w, kkT);
  k_vv<<<(POOL_N*1024+255)/256,256,0,stream>>>(poolb, v_w, vvb);
  k_retr<<<2048,256,0,stream>>>(qb, kkT, vvb, counti, retr);
  k_concat<<<16384,256,0,stream>>>(yout, retr, ccb);
  gemmb(stream, ccb, gateT, gbuf, 2048, 1024, 2048, 0);
  k_final<<<8192,256,0,stream>>>(x, yout, gbuf, retr, miscf, out);
  (void)in_sizes; (void)n_in; (void)out_size; (void)ws_size;
}

// Round 7
// 599.160 us; speedup vs baseline: 4.0456x; 1.2050x over previous
//
#include <hip/hip_runtime.h>
#include <math.h>

#define NHEADS 32
#define D_INNER 2048
#define CONV_DIM 2304
#define D_IN_PROJ 4384
#define POOL_N 50
#define BT 2048

typedef __attribute__((ext_vector_type(8))) short short8;
typedef __attribute__((ext_vector_type(4))) float f32x4;

__device__ __forceinline__ float sigmoidf_(float x){ return 1.f/(1.f+expf(-x)); }
__device__ __forceinline__ ushort f2bf(float f){
  union{float f; unsigned u;} v; v.f=f;
  unsigned r = v.u + 0x7fffu + ((v.u>>16)&1u);
  return (ushort)(r>>16);
}

// ---------------- RMSNorm on x (D=1024) -> bf16 ----------------
__global__ __launch_bounds__(256) void k_rmsnorm_x(const float* __restrict__ x, const float* __restrict__ w, ushort* __restrict__ xn){
  int r = blockIdx.x;
  const float* xr = x + (size_t)r*1024;
  float v[4]; float ss=0.f;
  for(int i=0;i<4;i++){ v[i]=xr[threadIdx.x+i*256]; ss+=v[i]*v[i]; }
  __shared__ float red[4];
  for(int off=32;off;off>>=1) ss += __shfl_down(ss,off,64);
  int wid=threadIdx.x>>6, lane=threadIdx.x&63;
  if(lane==0) red[wid]=ss;
  __syncthreads();
  float tot=red[0]+red[1]+red[2]+red[3];
  float rs=rsqrtf(tot*(1.f/1024.f)+1e-5f);
  for(int i=0;i<4;i++){ int c=threadIdx.x+i*256; xn[(size_t)r*1024+c]=f2bf(v[i]*rs*w[c]); }
}

// ---------------- transpose + cvt: src f32 [R][C] -> dst bf16 [C][R] ----------------
__global__ __launch_bounds__(256) void k_transpose_cvt(const float* __restrict__ src, ushort* __restrict__ dst, int R, int C){
  __shared__ float tile[32][33];
  int c0 = blockIdx.x*32, r0 = blockIdx.y*32;
  int tx = threadIdx.x&31, ty = threadIdx.x>>5;
  for(int i=0;i<4;i++){ int r = r0+ty+i*8; tile[ty+i*8][tx] = src[(size_t)r*C + c0+tx]; }
  __syncthreads();
  for(int i=0;i<4;i++){ int c = c0+ty+i*8; dst[(size_t)c*R + r0+tx] = f2bf(tile[tx][ty+i*8]); }
}

// ---------------- bf16 MFMA GEMM: C[M,N] f32 = A[M,K]bf16 @ Bt[N,K]bf16^T ----------------
// optional Cb: bf16 copy of C written in epilogue.
__global__ __launch_bounds__(256) void gemm_bf16(const ushort* __restrict__ A, const ushort* __restrict__ Bt,
    float* __restrict__ C, ushort* __restrict__ Cb, int M, int N, int K, int act){
  __shared__ __align__(16) ushort As[128*32];
  __shared__ __align__(16) ushort Bs[128*32];
  int n0 = blockIdx.x*128, m0 = blockIdx.y*128;
  int tid = threadIdx.x;
  int lane = tid&63, w = tid>>6;
  int wr = (w>>1)*64, wc = (w&1)*64;
  f32x4 acc[4][4];
  for(int i=0;i<4;i++)for(int j=0;j<4;j++)acc[i][j]=(f32x4){0.f,0.f,0.f,0.f};
  int srow = tid>>2, skb = (tid&3)*8;
  const ushort* Ap0 = A + (size_t)(m0+srow)*K + skb;
  const ushort* Ap1 = A + (size_t)(m0+srow+64)*K + skb;
  bool bv0 = (n0+srow) < N, bv1 = (n0+srow+64) < N;
  const ushort* Bp0 = Bt + (size_t)(bv0 ? (n0+srow)    : 0)*K + skb;
  const ushort* Bp1 = Bt + (size_t)(bv1 ? (n0+srow+64) : 0)*K + skb;
  int fr = lane&15, fko = (lane>>4)*8;
  for(int k0=0;k0<K;k0+=32){
    uint4 a0 = *(const uint4*)(Ap0 + k0);
    uint4 a1 = *(const uint4*)(Ap1 + k0);
    uint4 b0 = bv0 ? *(const uint4*)(Bp0 + k0) : make_uint4(0u,0u,0u,0u);
    uint4 b1 = bv1 ? *(const uint4*)(Bp1 + k0) : make_uint4(0u,0u,0u,0u);
    *(uint4*)(As + srow*32 + skb)      = a0;
    *(uint4*)(As + (srow+64)*32 + skb) = a1;
    *(uint4*)(Bs + srow*32 + skb)      = b0;
    *(uint4*)(Bs + (srow+64)*32 + skb) = b1;
    __syncthreads();
    short8 af[4], bfr[4];
    for(int i=0;i<4;i++) af[i]  = *(const short8*)(As + (wr+i*16+fr)*32 + fko);
    for(int j=0;j<4;j++) bfr[j] = *(const short8*)(Bs + (wc+j*16+fr)*32 + fko);
    for(int i=0;i<4;i++)
      for(int j=0;j<4;j++)
        acc[i][j] = __builtin_amdgcn_mfma_f32_16x16x32_bf16(af[i], bfr[j], acc[i][j], 0,0,0);
    __syncthreads();
  }
  int rbase = m0 + wr + (lane>>4)*4;
  for(int i=0;i<4;i++){
    for(int j=0;j<4;j++){
      int col = n0 + wc + j*16 + fr;
      if(col < N){
        for(int r=0;r<4;r++){
          float v = acc[i][j][r];
          if(act) v = fmaxf(v,0.f);
          size_t idx = (size_t)(rbase + i*16 + r)*N + col;
          C[idx] = v;
          if(Cb) Cb[idx] = f2bf(v);
        }
      }
    }
  }
}

// ---------------- dt = softplus(zxb[:, -32:] + bias) ----------------
__global__ void k_dt(const float* __restrict__ zxb, const float* __restrict__ dt_bias, float* __restrict__ dtb){
  int o = blockIdx.x*256+threadIdx.x; // 2048*32
  int r = o>>5, h = o&31;
  float v = zxb[(size_t)r*D_IN_PROJ + 4352 + h] + dt_bias[h];
  dtb[o] = (v>20.f) ? v : log1pf(expf(v));
}

// ---------------- causal depthwise conv (k=4) + silu ----------------
__global__ void k_conv(const float* __restrict__ zxb, const float* __restrict__ cw, const float* __restrict__ cb, float* __restrict__ xbc){
  int o = blockIdx.x*256+threadIdx.x; // 2048*2304
  int ch = o % CONV_DIM; int rt = o / CONV_DIM;
  int b = rt>>10, t = rt&1023;
  float acc = cb[ch];
  for(int k=0;k<4;k++){
    int tt = t-3+k;
    if(tt>=0) acc += zxb[(size_t)(b*1024+tt)*D_IN_PROJ + 2048 + ch]*cw[ch*4+k];
  }
  xbc[o] = acc*sigmoidf_(acc);
}

// ---------------- G^T per (b,c): Gt[s*256+l] = dot(C[l], B[s]) ----------------
__global__ __launch_bounds__(256) void k_gt(const float* __restrict__ xbc, float* __restrict__ Gt){
  int bc = blockIdx.x >> 8;
  int tile = blockIdx.x & 255;
  int l0 = (tile>>4)<<4, s0 = (tile&15)<<4;
  int b = bc>>2, c = bc&3;
  int row0 = b*1024 + c*256;
  __shared__ float Cs[16][130], Bs2[16][130];
  int tid = threadIdx.x;
  for(int i=0;i<8;i++){ int e=tid+i*256; int rr=e>>7, n=e&127;
    Cs[rr][n]  = xbc[(size_t)(row0+l0+rr)*CONV_DIM + 2176 + n];
    Bs2[rr][n] = xbc[(size_t)(row0+s0+rr)*CONV_DIM + 2048 + n];
  }
  __syncthreads();
  int tx = tid&15, ty = tid>>4;
  float acc=0.f;
  for(int n=0;n<128;n++) acc += Cs[tx][n]*Bs2[ty][n];
  Gt[(size_t)bc*65536 + (size_t)(s0+ty)*256 + (l0+tx)] = acc;
}

// ---------------- SSD per (b,c,h) via MFMA ----------------
__global__ __launch_bounds__(256) void k_ssd1m(const float* __restrict__ xbc, const float* __restrict__ dtb,
    const float* __restrict__ A_log, const float* __restrict__ Gt,
    float* __restrict__ ybuf, float* __restrict__ states, float* __restrict__ csb, float* __restrict__ sdA){
  int blk = blockIdx.x;      // (b*4+c)*32+h
  int bc = blk>>5, h = blk&31;
  int b = bc>>2, c = bc&3;
  int row0 = b*1024 + c*256;
  int tid = threadIdx.x;
  __shared__ float cs[256];
  __shared__ float aux[256];
  __shared__ __align__(16) ushort xdT[64*256];
  __shared__ __align__(16) ushort msb[256*32];
  float dtv = dtb[(size_t)(row0+tid)*32 + h];
  float Ah = -expf(A_log[h]);
  aux[tid] = dtv;
  cs[tid] = dtv*Ah;
  __syncthreads();
  for(int o=1;o<256;o<<=1){
    float add = (tid>=o)? cs[tid-o] : 0.f;
    __syncthreads();
    cs[tid] += add;
    __syncthreads();
  }
  float csl = cs[tid];
  float cslast = cs[255];
  csb[blk*256+tid] = csl;
  if(tid==0) sdA[blk] = cslast;
  {
    int p = tid&63, g = tid>>6;
    for(int i=0;i<64;i++){
      int l = g + 4*i;
      float v = xbc[(size_t)(row0+l)*CONV_DIM + h*64 + p] * aux[l];
      int off = ((p<<9) + (l<<1)) ^ ((p&7)<<4);
      *(ushort*)((char*)xdT + off) = f2bf(v);
    }
  }
  __syncthreads();
  aux[tid] = expf(cslast - csl);
  int lane = tid&63, w = tid>>6;
  int fr = lane&15, fq = lane>>4;
  const float* gt = Gt + (size_t)bc*65536;
  f32x4 accY[4][4];
  for(int i=0;i<4;i++)for(int j=0;j<4;j++)accY[i][j]=(f32x4){0.f,0.f,0.f,0.f};
  int nk = 2*(w+1);
  for(int ks=0;ks<8;ks++){
    int s0 = ks*32;
    for(int s2=0;s2<32;s2++){
      int s = s0+s2;
      float gv = gt[(size_t)s*256 + tid];
      float m = (s<=tid) ? gv*expf(csl - cs[s]) : 0.f;
      int off = ((tid<<6) + (s2<<1)) ^ ((tid&7)<<4);
      *(ushort*)((char*)msb + off) = f2bf(m);
    }
    __syncthreads();
    if(ks < nk){
      short8 af[4], bv[4];
      for(int i=0;i<4;i++){
        int l = w*64 + i*16 + fr;
        int off = ((l<<6) + (fq<<4)) ^ ((l&7)<<4);
        af[i] = *(const short8*)((char*)msb + off);
      }
      for(int j=0;j<4;j++){
        int p = j*16 + fr;
        int off = ((p<<9) + ((s0 + fq*8)<<1)) ^ ((p&7)<<4);
        bv[j] = *(const short8*)((char*)xdT + off);
      }
      for(int i=0;i<4;i++)
        for(int j=0;j<4;j++)
          accY[i][j] = __builtin_amdgcn_mfma_f32_16x16x32_bf16(af[i], bv[j], accY[i][j], 0,0,0);
    }
    __syncthreads();
  }
  for(int i=0;i<4;i++){
    int l = 64*w + i*16 + fq*4;
    for(int j=0;j<4;j++){
      int p = j*16 + fr;
      for(int r=0;r<4;r++)
        ybuf[(size_t)(row0+l+r)*2048 + h*64 + p] = accY[i][j][r];
    }
  }
  for(int q=0;q<4;q++){
    __syncthreads();
    {
      int nn = tid&31, g = tid>>5;
      for(int i=0;i<32;i++){
        int l = g + 8*i;
        float v = xbc[(size_t)(row0+l)*CONV_DIM + 2048 + 32*q + nn] * aux[l];
        int off = ((nn<<9) + (l<<1)) ^ ((nn&7)<<4);
        *(ushort*)((char*)msb + off) = f2bf(v);
      }
    }
    __syncthreads();
    f32x4 accS[2];
    accS[0]=(f32x4){0.f,0.f,0.f,0.f}; accS[1]=(f32x4){0.f,0.f,0.f,0.f};
    for(int ks=0;ks<8;ks++){
      int l0 = ks*32;
      short8 aS[2], bS;
      for(int i2=0;i2<2;i2++){
        int p = 32*(w>>1) + i2*16 + fr;
        int off = ((p<<9) + ((l0+fq*8)<<1)) ^ ((p&7)<<4);
        aS[i2] = *(const short8*)((char*)xdT + off);
      }
      {
        int nn = 16*(w&1) + fr;
        int off = ((nn<<9) + ((l0+fq*8)<<1)) ^ ((nn&7)<<4);
        bS = *(const short8*)((char*)msb + off);
      }
      for(int i2=0;i2<2;i2++)
        accS[i2] = __builtin_amdgcn_mfma_f32_16x16x32_bf16(aS[i2], bS, accS[i2], 0,0,0);
    }
    for(int i2=0;i2<2;i2++){
      int p = 32*(w>>1) + i2*16 + fq*4;
      int n = 32*q + 16*(w&1) + fr;
      for(int r=0;r<4;r++)
        states[(size_t)blk*8192 + (size_t)(p+r)*128 + n] = accS[i2][r];
    }
  }
}

// ---------------- chunk scan over c=0..3 (1 element per thread, full grid) ----------------
__global__ __launch_bounds__(256) void k_ssd2(const float* __restrict__ states, const float* __restrict__ sdA, float* __restrict__ prevb){
  int idx = blockIdx.x*256 + threadIdx.x;   // 2*32*8192 = 524288 total
  int e = idx & 8191;
  int h = (idx >> 13) & 31;
  int b = idx >> 18;
  float run = 0.f;
  for(int c=0;c<4;c++){
    int sblk = (b*4+c)*32 + h;
    size_t base = (size_t)sblk*8192 + e;
    prevb[base] = run;
    run = (run + states[base]) * expf(sdA[sblk]);
  }
}

// ---------------- y_off + xs*D, accumulate into ybuf ----------------
__global__ __launch_bounds__(256) void k_ssd3(const float* __restrict__ xbc, const float* __restrict__ csb,
    const float* __restrict__ prevb, const float* __restrict__ Dp, float* __restrict__ ybuf){
  int blk = blockIdx.x; int bc = blk>>5, h = blk&31; int b=bc>>2, c=bc&3;
  int row0 = b*1024+c*256;
  int tid = threadIdx.x;
  __shared__ float prevs[8192];
  for(int i=0;i<32;i++) prevs[i*256+tid] = prevb[(size_t)blk*8192 + i*256+tid];
  __syncthreads();
  float acc[64];
  for(int p=0;p<64;p++) acc[p]=0.f;
  const float* crow = xbc + (size_t)(row0+tid)*CONV_DIM + 2176;
  for(int n=0;n<128;n++){
    float cv = crow[n];
    for(int p=0;p<64;p++) acc[p] += cv * prevs[p*128+n];
  }
  float e = expf(csb[blk*256+tid]);
  float Dh = Dp[h];
  const float* xsr = xbc + (size_t)(row0+tid)*CONV_DIM + h*64;
  size_t yb = (size_t)(row0+tid)*2048 + h*64;
  for(int p=0;p<64;p++) ybuf[yb+p] += e*acc[p] + xsr[p]*Dh;
}

// ---------------- y = rmsnorm(y * silu(z)) -> bf16 (D=2048) ----------------
__global__ __launch_bounds__(256) void k_gate_norm(const float* __restrict__ y, const float* __restrict__ zxb,
    const float* __restrict__ w, ushort* __restrict__ yb16){
  int r = blockIdx.x;
  const float* zr = zxb + (size_t)r*D_IN_PROJ;
  const float* yr = y + (size_t)r*2048;
  float v[8]; float ss=0.f;
  for(int i=0;i<8;i++){ int c=threadIdx.x+i*256; float z=zr[c]; float g=yr[c]*(z*sigmoidf_(z)); v[i]=g; ss+=g*g; }
  __shared__ float red[4];
  for(int off=32;off;off>>=1) ss += __shfl_down(ss,off,64);
  int wid=threadIdx.x>>6, lane=threadIdx.x&63;
  if(lane==0) red[wid]=ss;
  __syncthreads();
  float tot=red[0]+red[1]+red[2]+red[3];
  float rs=rsqrtf(tot*(1.f/2048.f)+1e-5f);
  for(int i=0;i<8;i++){ int c=threadIdx.x+i*256; yb16[(size_t)r*2048+c]=f2bf(v[i]*rs*w[c]); }
}

// ---------------- scorer stage 2: sigmoid(h1 @ w2) ----------------
__global__ void k_scorer2(const float* __restrict__ h1, const float* __restrict__ w2, float* __restrict__ scores){
  int r = blockIdx.x; int lane = threadIdx.x; // 64 threads
  float s=0.f;
  for(int k=0;k<4;k++){ int c=lane+k*64; s += h1[(size_t)r*256+c]*w2[c]; }
  for(int off=32;off;off>>=1) s += __shfl_down(s,off,64);
  if(lane==0) scores[r]=sigmoidf_(s);
}

// ---------------- serial pool scan: ballot-filtered, exact semantics; + flags ----------------
__global__ void k_pool(const float* __restrict__ scores,
                       float* __restrict__ priosws, int* __restrict__ countws, int* __restrict__ winners,
                       float* __restrict__ condf){
  __shared__ float scs[BT];
  int lane = threadIdx.x;
  float ssum = 0.f;
  for(int i=lane;i<BT;i+=64){ float s0 = scores[i]; scs[i]=s0; ssum += s0; }
  __syncthreads();
  float prio = 0.f;
  int winner = -1;
  int count = 0;
  float curmin = 0.f; int curargmin = 0;    // valid once count==POOL_N
  for(int b0=0;b0<BT;b0+=64){
    float own = scs[b0+lane];
    unsigned long long mask = (count < POOL_N) ? __ballot(own > 0.5f)
                                               : __ballot(own > curmin);
    while(mask){
      int j = __ffsll(mask) - 1;
      mask &= mask - 1ull;
      float sc = __shfl(own, j, 64);
      if(count < POOL_N){
        if(lane == count){ prio = sc; winner = b0+j; }
        count++;
        if(count == POOL_N){
          float v = (lane < POOL_N)? prio : INFINITY; int idx = lane;
          for(int off=32;off;off>>=1){
            float ov = __shfl_xor(v,off,64);
            int oi = __shfl_xor(idx,off,64);
            if(ov < v || (ov==v && oi<idx)){ v=ov; idx=oi; }
          }
          curmin = v; curargmin = idx;
        }
      } else if(sc > curmin){
        if(lane == curargmin){ prio = sc; winner = b0+j; }
        float v = (lane < POOL_N)? prio : INFINITY; int idx = lane;
        for(int off=32;off;off>>=1){
          float ov = __shfl_xor(v,off,64);
          int oi = __shfl_xor(idx,off,64);
          if(ov < v || (ov==v && oi<idx)){ v=ov; idx=oi; }
        }
        curmin = v; curargmin = idx;
      }
    }
  }
  if(lane < POOL_N){ winners[lane]=winner; priosws[lane]=prio; }
  for(int off=32;off;off>>=1) ssum += __shfl_xor(ssum,off,64);
  if(lane==0){
    countws[0]=count;
    float mean = ssum*(1.f/2048.f);
    condf[0] = (mean>0.3f && count>0)? 1.f : 0.f;
  }
}

// ---------------- gather pool rows from sq (stride 128, cols 0..63) ----------------
__global__ void k_poolg(const float* __restrict__ sq, const int* __restrict__ winners, float* __restrict__ poolb){
  int p = blockIdx.x; int lane = threadIdx.x;
  int wi = winners[p];
  poolb[p*64+lane] = (wi>=0)? sq[(size_t)wi*128+lane] : 0.f;
}

// ---------------- kkT[j*64+p] = (pool @ k_w)[p][j] ----------------
__global__ void k_kk(const float* __restrict__ pool, const float* __restrict__ k_w, float* __restrict__ kkT){
  int o = blockIdx.x*256+threadIdx.x;
  if(o >= 64*POOL_N) return;
  int j = o/POOL_N, p = o%POOL_N;
  float s=0.f;
  for(int k=0;k<64;k++) s += pool[p*64+k]*k_w[k*64+j];
  kkT[j*64+p]=s;
}

// ---------------- vv = pool @ v_w (50x1024) ----------------
__global__ void k_vv(const float* __restrict__ pool, const float* __restrict__ v_w, float* __restrict__ vv){
  int o = blockIdx.x*256+threadIdx.x;
  if(o >= POOL_N*1024) return;
  int p = o>>10, d = o&1023;
  float s=0.f;
  for(int k=0;k<64;k++) s += pool[p*64+k]*v_w[(size_t)k*1024+d];
  vv[o]=s;
}

// ---------------- retrieval: softmax(q·kkT/4, masked) @ vv; q from sq cols 64..127 ----------------
__global__ __launch_bounds__(256) void k_retr(const float* __restrict__ sq, const float* __restrict__ kkT,
   const float* __restrict__ vv, const int* __restrict__ counti, float* __restrict__ retr){
  int r = blockIdx.x;
  __shared__ float qs[64];
  __shared__ float probs[64];
  int tid = threadIdx.x;
  if(tid<64) qs[tid] = sq[(size_t)r*128 + 64 + tid];
  __syncthreads();
  int count = counti[0];
  if(tid<64){
    float logit = -1e9f;
    if(tid < POOL_N && tid < count){
      float s=0.f;
      for(int k=0;k<64;k++) s += qs[k]*kkT[k*64+tid];
      logit = s*0.25f;
    }
    float m = logit;
    for(int off=32;off;off>>=1) m = fmaxf(m, __shfl_xor(m,off,64));
    float e = expf(logit-m);
    float sum = e;
    for(int off=32;off;off>>=1) sum += __shfl_xor(sum,off,64);
    probs[tid] = e/sum;
  }
  __syncthreads();
  for(int d=tid; d<1024; d+=256){
    float acc=0.f;
    for(int p=0;p<POOL_N;p++) acc += probs[p]*vv[(size_t)p*1024+d];
    retr[(size_t)r*1024+d]=acc;
  }
}

// ---------------- concat [yout, retr] -> bf16 ----------------
__global__ void k_concat(const float* __restrict__ yout, const float* __restrict__ retr, ushort* __restrict__ cc){
  int o = blockIdx.x*256+threadIdx.x; // 2048*2048
  int r = o>>11, c2 = o&2047;
  cc[o] = f2bf((c2<1024)? yout[(size_t)r*1024+c2] : retr[(size_t)r*1024+(c2-1024)]);
}

// ---------------- out = x + yout + cond*sigmoid(g)*retr ----------------
__global__ void k_final(const float* __restrict__ x, const float* __restrict__ yout, const float* __restrict__ g,
   const float* __restrict__ retr, const float* __restrict__ condf, float* __restrict__ out){
  int o = blockIdx.x*256+threadIdx.x; // 2048*1024
  float gv = sigmoidf_(g[o]);
  out[o] = x[o] + yout[o] + condf[0]*gv*retr[o];
}

static inline void gemmb(hipStream_t s, const ushort*A,const ushort*Bt,float*C,ushort*Cb,int M,int N,int K,int act){
  dim3 g((N+127)/128, M/128);
  hipLaunchKernelGGL(gemm_bf16,g,dim3(256),0,s,A,Bt,C,Cb,M,N,K,act);
}

extern "C" void kernel_launch(void* const* d_in, const int* in_sizes, int n_in,
                              void* d_out, int out_size, void* d_ws, size_t ws_size,
                              hipStream_t stream) {
  const float* x        = (const float*)d_in[0];
  const float* norm_w   = (const float*)d_in[1];
  const float* in_proj_w= (const float*)d_in[2];
  const float* conv_w   = (const float*)d_in[3];
  const float* conv_b   = (const float*)d_in[4];
  const float* dt_bias  = (const float*)d_in[5];
  const float* A_log    = (const float*)d_in[6];
  const float* Dp       = (const float*)d_in[7];
  const float* ssm_norm_w=(const float*)d_in[8];
  const float* out_proj_w=(const float*)d_in[9];
  const float* scorer_w1= (const float*)d_in[10];
  const float* scorer_w2= (const float*)d_in[11];
  const float* summ_w   = (const float*)d_in[12];
  const float* q_w      = (const float*)d_in[13];
  const float* k_w      = (const float*)d_in[14];
  const float* v_w      = (const float*)d_in[15];
  const float* gate_w   = (const float*)d_in[16];
  float* out = (float*)d_out;

  unsigned char* base = (unsigned char*)d_ws;
  size_t off = 0;
  auto FB = [&](size_t bytes)->void*{ void* p = base+off; off = (off+bytes+255)&~(size_t)255; return p; };
  float* zxb   = (float*)FB((size_t)2048*D_IN_PROJ*4);
  float* dtb   = (float*)FB((size_t)2048*32*4);
  float* xbc   = (float*)FB((size_t)2048*CONV_DIM*4);
  float* csb   = (float*)FB((size_t)256*256*4);
  float* sdA   = (float*)FB(1024);
  float* states= (float*)FB((size_t)256*8192*4);
  float* prevb = (float*)FB((size_t)256*8192*4);
  float* ybuf  = (float*)FB((size_t)2048*2048*4);
  float* yout  = (float*)FB((size_t)2048*1024*4);
  float* scores= (float*)FB(2048*4);
  float* summ  = (float*)FB((size_t)2048*64*4);
  float* qb    = (float*)FB((size_t)2048*64*4);
  float* poolb = (float*)FB(POOL_N*64*4);
  float* prios = (float*)FB(256);
  float* miscf = (float*)FB(256);
  int*   counti= (int*)FB(256);
  int*   winners=(int*)FB(256);
  unsigned char* RX = (unsigned char*)FB((size_t)4194304);
  unsigned char* W1 = (unsigned char*)FB((size_t)8978432);

  ushort* xnb   = (ushort*)RX;
  ushort* sqT   = (ushort*)RX;                 // [128][1024] bf16: summT rows 0..63, qT rows 64..127
  ushort* summT = (ushort*)RX;
  ushort* qT    = (ushort*)(RX + 131072);
  float*  h1    = (float*) (RX + 262144);
  float*  kkT   = (float*) (RX + 2359296);
  float*  vvb   = (float*) (RX + 2375680);
  ushort* inT   = (ushort*)W1;
  ushort* outT  = (ushort*)W1;
  ushort* gateT = (ushort*)(W1 + 4194304);
  ushort* sc1T  = (ushort*)(W1 + 8388608);
  float*  Gt    = yout;
  ushort* ybf   = (ushort*)prevb;
  float*  gbuf  = prevb;
  float*  retr  = states;
  ushort* ccb   = (ushort*)ybuf;
  ushort* youtb = (ushort*)((unsigned char*)ybuf + 8388608);
  float*  sq    = summ;                        // [2048][128] f32 spans summ+qb (1 MB)
  (void)qb;

  hipLaunchKernelGGL(k_transpose_cvt, dim3(137,32), dim3(256), 0, stream, in_proj_w, inT, 1024, 4384);
  k_rmsnorm_x<<<2048,256,0,stream>>>(x, norm_w, xnb);
  gemmb(stream, xnb, inT, zxb, nullptr, 2048, D_IN_PROJ, 1024, 0);
  hipLaunchKernelGGL(k_transpose_cvt, dim3(32,64), dim3(256), 0, stream, out_proj_w, outT, 2048, 1024);
  hipLaunchKernelGGL(k_transpose_cvt, dim3(32,64), dim3(256), 0, stream, gate_w, gateT, 2048, 1024);
  hipLaunchKernelGGL(k_transpose_cvt, dim3(8,32), dim3(256), 0, stream, scorer_w1, sc1T, 1024, 256);
  hipLaunchKernelGGL(k_transpose_cvt, dim3(2,32), dim3(256), 0, stream, summ_w, summT, 1024, 64);
  hipLaunchKernelGGL(k_transpose_cvt, dim3(2,32), dim3(256), 0, stream, q_w, qT, 1024, 64);
  k_dt<<<256,256,0,stream>>>(zxb, dt_bias, dtb);
  k_conv<<<18432,256,0,stream>>>(zxb, conv_w, conv_b, xbc);
  k_gt<<<2048,256,0,stream>>>(xbc, Gt);
  k_ssd1m<<<256,256,0,stream>>>(xbc, dtb, A_log, Gt, ybuf, states, csb, sdA);
  k_ssd2<<<2048,256,0,stream>>>(states, sdA, prevb);
  k_ssd3<<<256,256,0,stream>>>(xbc, csb, prevb, Dp, ybuf);
  k_gate_norm<<<2048,256,0,stream>>>(ybuf, zxb, ssm_norm_w, ybf);
  gemmb(stream, ybf, outT, yout, youtb, 2048, 1024, 2048, 0);
  // scorer stage 1 (bf16 MFMA, relu) + stage 2
  gemmb(stream, youtb, sc1T, h1, nullptr, 2048, 256, 1024, 1);
  k_scorer2<<<2048,64,0,stream>>>(h1, scorer_w2, scores);
  // summaries + queries fused: sq[2048][128]
  gemmb(stream, youtb, sqT, sq, nullptr, 2048, 128, 1024, 0);
  k_pool<<<1,64,0,stream>>>(scores, prios, counti, winners, miscf);
  k_poolg<<<POOL_N,64,0,stream>>>(sq, winners, poolb);
  k_kk<<<(64*POOL_N+255)/256,256,0,stream>>>(poolb, k_w, kkT);
  k_vv<<<(POOL_N*1024+255)/256,256,0,stream>>>(poolb, v_w, vvb);
  k_retr<<<2048,256,0,stream>>>(sq, kkT, vvb, counti, retr);
  k_concat<<<16384,256,0,stream>>>(yout, retr, ccb);
  gemmb(stream, ccb, gateT, gbuf, nullptr, 2048, 1024, 2048, 0);
  k_final<<<8192,256,0,stream>>>(x, yout, gbuf, retr, miscf, out);
  (void)in_sizes; (void)n_in; (void)out_size; (void)ws_size;
}

// Round 8
// 477.149 us; speedup vs baseline: 5.0801x; 1.2557x over previous
//
#include <hip/hip_runtime.h>
#include <math.h>

#define NHEADS 32
#define D_INNER 2048
#define CONV_DIM 2304
#define D_IN_PROJ 4384
#define POOL_N 50
#define BT 2048

typedef __attribute__((ext_vector_type(8))) short short8;
typedef __attribute__((ext_vector_type(4))) float f32x4;

__device__ __forceinline__ float sigmoidf_(float x){ return 1.f/(1.f+expf(-x)); }
__device__ __forceinline__ ushort f2bf(float f){
  union{float f; unsigned u;} v; v.f=f;
  unsigned r = v.u + 0x7fffu + ((v.u>>16)&1u);
  return (ushort)(r>>16);
}

// ---------------- RMSNorm on x (D=1024) -> bf16 ----------------
__global__ __launch_bounds__(256) void k_rmsnorm_x(const float* __restrict__ x, const float* __restrict__ w, ushort* __restrict__ xn){
  int r = blockIdx.x;
  const float* xr = x + (size_t)r*1024;
  float v[4]; float ss=0.f;
  for(int i=0;i<4;i++){ v[i]=xr[threadIdx.x+i*256]; ss+=v[i]*v[i]; }
  __shared__ float red[4];
  for(int off=32;off;off>>=1) ss += __shfl_down(ss,off,64);
  int wid=threadIdx.x>>6, lane=threadIdx.x&63;
  if(lane==0) red[wid]=ss;
  __syncthreads();
  float tot=red[0]+red[1]+red[2]+red[3];
  float rs=rsqrtf(tot*(1.f/1024.f)+1e-5f);
  for(int i=0;i<4;i++){ int c=threadIdx.x+i*256; xn[(size_t)r*1024+c]=f2bf(v[i]*rs*w[c]); }
}

// ---------------- transpose + cvt: src f32 [R][C] -> dst bf16 [C][R] ----------------
__global__ __launch_bounds__(256) void k_transpose_cvt(const float* __restrict__ src, ushort* __restrict__ dst, int R, int C){
  __shared__ float tile[32][33];
  int c0 = blockIdx.x*32, r0 = blockIdx.y*32;
  int tx = threadIdx.x&31, ty = threadIdx.x>>5;
  for(int i=0;i<4;i++){ int r = r0+ty+i*8; tile[ty+i*8][tx] = src[(size_t)r*C + c0+tx]; }
  __syncthreads();
  for(int i=0;i<4;i++){ int c = c0+ty+i*8; dst[(size_t)c*R + r0+tx] = f2bf(tile[tx][ty+i*8]); }
}

// ---------------- bf16 MFMA GEMM: C[M,N] f32 = A[M,K]bf16 @ Bt[N,K]bf16^T ----------------
__global__ __launch_bounds__(256) void gemm_bf16(const ushort* __restrict__ A, const ushort* __restrict__ Bt,
    float* __restrict__ C, ushort* __restrict__ Cb, int M, int N, int K, int act){
  __shared__ __align__(16) ushort As[128*32];
  __shared__ __align__(16) ushort Bs[128*32];
  int n0 = blockIdx.x*128, m0 = blockIdx.y*128;
  int tid = threadIdx.x;
  int lane = tid&63, w = tid>>6;
  int wr = (w>>1)*64, wc = (w&1)*64;
  f32x4 acc[4][4];
  for(int i=0;i<4;i++)for(int j=0;j<4;j++)acc[i][j]=(f32x4){0.f,0.f,0.f,0.f};
  int srow = tid>>2, skb = (tid&3)*8;
  const ushort* Ap0 = A + (size_t)(m0+srow)*K + skb;
  const ushort* Ap1 = A + (size_t)(m0+srow+64)*K + skb;
  bool bv0 = (n0+srow) < N, bv1 = (n0+srow+64) < N;
  const ushort* Bp0 = Bt + (size_t)(bv0 ? (n0+srow)    : 0)*K + skb;
  const ushort* Bp1 = Bt + (size_t)(bv1 ? (n0+srow+64) : 0)*K + skb;
  int fr = lane&15, fko = (lane>>4)*8;
  for(int k0=0;k0<K;k0+=32){
    uint4 a0 = *(const uint4*)(Ap0 + k0);
    uint4 a1 = *(const uint4*)(Ap1 + k0);
    uint4 b0 = bv0 ? *(const uint4*)(Bp0 + k0) : make_uint4(0u,0u,0u,0u);
    uint4 b1 = bv1 ? *(const uint4*)(Bp1 + k0) : make_uint4(0u,0u,0u,0u);
    *(uint4*)(As + srow*32 + skb)      = a0;
    *(uint4*)(As + (srow+64)*32 + skb) = a1;
    *(uint4*)(Bs + srow*32 + skb)      = b0;
    *(uint4*)(Bs + (srow+64)*32 + skb) = b1;
    __syncthreads();
    short8 af[4], bfr[4];
    for(int i=0;i<4;i++) af[i]  = *(const short8*)(As + (wr+i*16+fr)*32 + fko);
    for(int j=0;j<4;j++) bfr[j] = *(const short8*)(Bs + (wc+j*16+fr)*32 + fko);
    for(int i=0;i<4;i++)
      for(int j=0;j<4;j++)
        acc[i][j] = __builtin_amdgcn_mfma_f32_16x16x32_bf16(af[i], bfr[j], acc[i][j], 0,0,0);
    __syncthreads();
  }
  int rbase = m0 + wr + (lane>>4)*4;
  for(int i=0;i<4;i++){
    for(int j=0;j<4;j++){
      int col = n0 + wc + j*16 + fr;
      if(col < N){
        for(int r=0;r<4;r++){
          float v = acc[i][j][r];
          if(act) v = fmaxf(v,0.f);
          size_t idx = (size_t)(rbase + i*16 + r)*N + col;
          C[idx] = v;
          if(Cb) Cb[idx] = f2bf(v);
        }
      }
    }
  }
}

// ---------------- dt = softplus(zxb[:, -32:] + bias) ----------------
__global__ void k_dt(const float* __restrict__ zxb, const float* __restrict__ dt_bias, float* __restrict__ dtb){
  int o = blockIdx.x*256+threadIdx.x; // 2048*32
  int r = o>>5, h = o&31;
  float v = zxb[(size_t)r*D_IN_PROJ + 4352 + h] + dt_bias[h];
  dtb[o] = (v>20.f) ? v : log1pf(expf(v));
}

// ---------------- causal depthwise conv (k=4) + silu, 4 channels/thread ----------------
__global__ void k_conv4(const float* __restrict__ zxb, const float* __restrict__ cw, const float* __restrict__ cb, float* __restrict__ xbc){
  int o = blockIdx.x*256+threadIdx.x; // 2048*576
  if(o >= 2048*576) return;
  int ch4 = (o % 576)*4; int rt = o / 576;
  int b = rt>>10, t = rt&1023;
  float a[4];
  { float4 cbv = *(const float4*)(cb + ch4); a[0]=cbv.x; a[1]=cbv.y; a[2]=cbv.z; a[3]=cbv.w; }
  float cwa[4][4];
  for(int c2=0;c2<4;c2++){
    float4 v = *(const float4*)(cw + (ch4+c2)*4);
    cwa[c2][0]=v.x; cwa[c2][1]=v.y; cwa[c2][2]=v.z; cwa[c2][3]=v.w;
  }
  for(int k=0;k<4;k++){
    int tt = t-3+k;
    if(tt>=0){
      float4 v = *(const float4*)(zxb + (size_t)(b*1024+tt)*D_IN_PROJ + 2048 + ch4);
      a[0] += v.x*cwa[0][k]; a[1] += v.y*cwa[1][k];
      a[2] += v.z*cwa[2][k]; a[3] += v.w*cwa[3][k];
    }
  }
  float4 o4;
  o4.x = a[0]*sigmoidf_(a[0]); o4.y = a[1]*sigmoidf_(a[1]);
  o4.z = a[2]*sigmoidf_(a[2]); o4.w = a[3]*sigmoidf_(a[3]);
  *(float4*)(xbc + (size_t)rt*CONV_DIM + ch4) = o4;
}

// ---------------- G^T per (b,c): Gt[s*256+l] = dot(C[l], B[s]) ----------------
__global__ __launch_bounds__(256) void k_gt(const float* __restrict__ xbc, float* __restrict__ Gt){
  int bc = blockIdx.x >> 8;
  int tile = blockIdx.x & 255;
  int l0 = (tile>>4)<<4, s0 = (tile&15)<<4;
  int b = bc>>2, c = bc&3;
  int row0 = b*1024 + c*256;
  __shared__ float Cs[16][130], Bs2[16][130];
  int tid = threadIdx.x;
  for(int i=0;i<8;i++){ int e=tid+i*256; int rr=e>>7, n=e&127;
    Cs[rr][n]  = xbc[(size_t)(row0+l0+rr)*CONV_DIM + 2176 + n];
    Bs2[rr][n] = xbc[(size_t)(row0+s0+rr)*CONV_DIM + 2048 + n];
  }
  __syncthreads();
  int tx = tid&15, ty = tid>>4;
  float acc=0.f;
  for(int n=0;n<128;n++) acc += Cs[tx][n]*Bs2[ty][n];
  Gt[(size_t)bc*65536 + (size_t)(s0+ty)*256 + (l0+tx)] = acc;
}

// ---------------- SSD per (b,c,h): 512 threads, wave-specialized ----------------
// waves 0-3: y_diag (per-wave M-gen, no block barriers); waves 4-7: states (per-wave Bw staging)
__global__ __launch_bounds__(512) void k_ssd1w(const float* __restrict__ xbc, const float* __restrict__ dtb,
    const float* __restrict__ A_log, const float* __restrict__ Gt,
    float* __restrict__ ybuf, float* __restrict__ states, float* __restrict__ csb, float* __restrict__ sdA){
  int blk = blockIdx.x;      // (b*4+c)*32+h
  int bc = blk>>5, h = blk&31;
  int b = bc>>2, c = bc&3;
  int row0 = b*1024 + c*256;
  int tid = threadIdx.x;
  __shared__ float cs[256];
  __shared__ float dts[256];
  __shared__ float dec[256];
  __shared__ __align__(16) ushort xdT[64*256];   // 32KB [p][l] swizzled
  __shared__ __align__(16) ushort Mw[4*64*32];   // 16KB: per-y-wave 64x32 M chunk
  __shared__ __align__(16) ushort Bw[4*32*256];  // 64KB: per-states-wave 32x256 Bw
  float Ah = -expf(A_log[h]);
  if(tid < 256){
    float dtv = dtb[(size_t)(row0+tid)*32 + h];
    dts[tid] = dtv;
    cs[tid] = dtv*Ah;
  }
  __syncthreads();
  for(int o=1;o<256;o<<=1){
    float add = 0.f;
    if(tid<256 && tid>=o) add = cs[tid-o];
    __syncthreads();
    if(tid<256) cs[tid] += add;
    __syncthreads();
  }
  float cslast = cs[255];
  if(tid < 256){
    float csl = cs[tid];
    csb[blk*256+tid] = csl;
    dec[tid] = expf(cslast - csl);
    if(tid==0) sdA[blk] = cslast;
  }
  // stage xdT[p][l] = bf16(xs[l,p]*dt[l]) — all 512 threads, 32 elems each
  {
    int p = tid&63, g = tid>>6;   // g in 0..7
    for(int i=0;i<32;i++){
      int l = g + 8*i;
      float v = xbc[(size_t)(row0+l)*CONV_DIM + h*64 + p] * dts[l];
      int off = ((p<<9) + (l<<1)) ^ ((p&7)<<4);
      *(ushort*)((char*)xdT + off) = f2bf(v);
    }
  }
  __syncthreads();   // last block-wide barrier

  int w = tid>>6, lane = tid&63;
  int fr = lane&15, fq = lane>>4;
  const float* gt = Gt + (size_t)bc*65536;
  if(w < 4){
    // ---- y_diag wave: rows l = 64w + lane ----
    int rowl = w*64 + lane;
    float csl_w = cs[rowl];
    f32x4 accY[4][4];
    for(int i=0;i<4;i++)for(int j=0;j<4;j++)accY[i][j]=(f32x4){0.f,0.f,0.f,0.f};
    int nk = 2*(w+1);
    for(int ks=0; ks<nk; ks++){
      int s0 = ks*32;
      float cs_s0 = cs[s0];
      float ev = expf(cs_s0 - cs[s0 + (lane&31)]);
      float el = expf(csl_w - cs_s0);
      for(int j=0;j<4;j++){
        short8 mp;
        for(int k=0;k<8;k++){
          int s2 = j*8+k;
          int s = s0 + s2;
          float gv = gt[(size_t)s*256 + rowl];
          float esv = __shfl(ev, s2, 64);
          float m = (s <= rowl) ? gv*el*esv : 0.f;
          mp[k] = (short)f2bf(m);
        }
        int off = (w<<12) + ((((lane)<<6) + (j<<4)) ^ ((lane&7)<<4));
        *(short8*)((char*)Mw + off) = mp;
      }
      asm volatile("s_waitcnt lgkmcnt(0)" ::: "memory");
      __builtin_amdgcn_sched_barrier(0);
      short8 af[4], bv4[4];
      for(int i=0;i<4;i++){
        int lp = i*16 + fr;
        int off = (w<<12) + (((lp<<6) + (fq<<4)) ^ ((lp&7)<<4));
        af[i] = *(const short8*)((char*)Mw + off);
      }
      for(int j=0;j<4;j++){
        int p = j*16 + fr;
        int off = ((p<<9) + ((s0 + fq*8)<<1)) ^ ((p&7)<<4);
        bv4[j] = *(const short8*)((char*)xdT + off);
      }
      for(int i=0;i<4;i++)
        for(int j=0;j<4;j++)
          accY[i][j] = __builtin_amdgcn_mfma_f32_16x16x32_bf16(af[i], bv4[j], accY[i][j], 0,0,0);
      asm volatile("" ::: "memory");
    }
    for(int i=0;i<4;i++){
      int l = 64*w + i*16 + fq*4;
      for(int j=0;j<4;j++){
        int p = j*16 + fr;
        for(int r=0;r<4;r++)
          ybuf[(size_t)(row0+l+r)*2048 + h*64 + p] = accY[i][j][r];
      }
    }
  } else {
    // ---- states wave: n-range [32sw, 32sw+32) ----
    int sw = w-4, nbase = sw*32;
    {
      int nn = lane&31, half = lane>>5;
      for(int i=0;i<128;i++){
        int l = half + 2*i;
        float v = xbc[(size_t)(row0+l)*CONV_DIM + 2048 + nbase + nn] * dec[l];
        int off = (sw<<14) + (((nn<<9) + (l<<1)) ^ ((nn&7)<<4));
        *(ushort*)((char*)Bw + off) = f2bf(v);
      }
    }
    asm volatile("s_waitcnt lgkmcnt(0)" ::: "memory");
    __builtin_amdgcn_sched_barrier(0);
    f32x4 accS[4][2];
    for(int i=0;i<4;i++)for(int j=0;j<2;j++)accS[i][j]=(f32x4){0.f,0.f,0.f,0.f};
    for(int ks=0;ks<8;ks++){
      int l0 = ks*32;
      short8 aS[4], bS[2];
      for(int i=0;i<4;i++){
        int p = i*16 + fr;
        int off = ((p<<9) + ((l0+fq*8)<<1)) ^ ((p&7)<<4);
        aS[i] = *(const short8*)((char*)xdT + off);
      }
      for(int j=0;j<2;j++){
        int nn = j*16 + fr;
        int off = (sw<<14) + (((nn<<9) + ((l0+fq*8)<<1)) ^ ((nn&7)<<4));
        bS[j] = *(const short8*)((char*)Bw + off);
      }
      for(int i=0;i<4;i++)
        for(int j=0;j<2;j++)
          accS[i][j] = __builtin_amdgcn_mfma_f32_16x16x32_bf16(aS[i], bS[j], accS[i][j], 0,0,0);
    }
    for(int i=0;i<4;i++){
      int p = i*16 + fq*4;
      for(int j=0;j<2;j++){
        int n = nbase + j*16 + fr;
        for(int r=0;r<4;r++)
          states[(size_t)blk*8192 + (size_t)(p+r)*128 + n] = accS[i][j][r];
      }
    }
  }
}

// ---------------- chunk scan over c=0..3 (1 element per thread, full grid) ----------------
__global__ __launch_bounds__(256) void k_ssd2(const float* __restrict__ states, const float* __restrict__ sdA, float* __restrict__ prevb){
  int idx = blockIdx.x*256 + threadIdx.x;   // 2*32*8192 = 524288 total
  int e = idx & 8191;
  int h = (idx >> 13) & 31;
  int b = idx >> 18;
  float run = 0.f;
  for(int c=0;c<4;c++){
    int sblk = (b*4+c)*32 + h;
    size_t base = (size_t)sblk*8192 + e;
    prevb[base] = run;
    run = (run + states[base]) * expf(sdA[sblk]);
  }
}

// ---------------- y_off = C @ prev^T via MFMA; += xs*D into ybuf ----------------
__global__ __launch_bounds__(256) void k_ssd3m(const float* __restrict__ xbc, const float* __restrict__ csb,
    const float* __restrict__ prevb, const float* __restrict__ Dp, float* __restrict__ ybuf){
  int blk = blockIdx.x; int bc = blk>>5, h = blk&31; int b=bc>>2, c=bc&3;
  int row0 = b*1024+c*256;
  int tid = threadIdx.x;
  __shared__ __align__(16) ushort Cs[256*128];   // 64KB [l][n]
  __shared__ __align__(16) ushort Ps[64*128];    // 16KB [p][n]
  __shared__ float cse[256];
  for(int i=0;i<128;i++){
    int id = tid + i*256;
    int n = id & 127, l = id >> 7;
    float v = xbc[(size_t)(row0+l)*CONV_DIM + 2176 + n];
    int off = ((l<<8) + (n<<1)) ^ ((l&7)<<4);
    *(ushort*)((char*)Cs + off) = f2bf(v);
  }
  for(int i=0;i<32;i++){
    int id = tid + i*256;
    int n = id & 127, p = id >> 7;
    float v = prevb[(size_t)blk*8192 + id];
    int off = ((p<<8) + (n<<1)) ^ ((p&7)<<4);
    *(ushort*)((char*)Ps + off) = f2bf(v);
  }
  cse[tid] = expf(csb[blk*256+tid]);
  __syncthreads();
  int w=tid>>6, lane=tid&63, fr=lane&15, fq=lane>>4;
  f32x4 acc[4][4];
  for(int i=0;i<4;i++)for(int j=0;j<4;j++)acc[i][j]=(f32x4){0.f,0.f,0.f,0.f};
  for(int ks=0;ks<4;ks++){
    int n0 = ks*32;
    short8 af[4], bf_[4];
    for(int i=0;i<4;i++){
      int l = w*64 + i*16 + fr;
      int off = ((l<<8) + ((n0+fq*8)<<1)) ^ ((l&7)<<4);
      af[i] = *(const short8*)((char*)Cs + off);
    }
    for(int j=0;j<4;j++){
      int p = j*16 + fr;
      int off = ((p<<8) + ((n0+fq*8)<<1)) ^ ((p&7)<<4);
      bf_[j] = *(const short8*)((char*)Ps + off);
    }
    for(int i=0;i<4;i++)
      for(int j=0;j<4;j++)
        acc[i][j] = __builtin_amdgcn_mfma_f32_16x16x32_bf16(af[i], bf_[j], acc[i][j], 0,0,0);
  }
  float Dh = Dp[h];
  for(int i=0;i<4;i++){
    int lbase = 64*w + i*16 + fq*4;
    for(int r=0;r<4;r++){
      int l = lbase + r;
      float e = cse[l];
      size_t rowoff = (size_t)(row0+l)*CONV_DIM + h*64;
      size_t yb = (size_t)(row0+l)*2048 + h*64;
      for(int j=0;j<4;j++){
        int p = j*16 + fr;
        float xs = xbc[rowoff + p];
        ybuf[yb+p] += e*acc[i][j][r] + xs*Dh;
      }
    }
  }
}

// ---------------- y = rmsnorm(y * silu(z)) -> bf16 (D=2048) ----------------
__global__ __launch_bounds__(256) void k_gate_norm(const float* __restrict__ y, const float* __restrict__ zxb,
    const float* __restrict__ w, ushort* __restrict__ yb16){
  int r = blockIdx.x;
  const float* zr = zxb + (size_t)r*D_IN_PROJ;
  const float* yr = y + (size_t)r*2048;
  float v[8]; float ss=0.f;
  for(int i=0;i<8;i++){ int c=threadIdx.x+i*256; float z=zr[c]; float g=yr[c]*(z*sigmoidf_(z)); v[i]=g; ss+=g*g; }
  __shared__ float red[4];
  for(int off=32;off;off>>=1) ss += __shfl_down(ss,off,64);
  int wid=threadIdx.x>>6, lane=threadIdx.x&63;
  if(lane==0) red[wid]=ss;
  __syncthreads();
  float tot=red[0]+red[1]+red[2]+red[3];
  float rs=rsqrtf(tot*(1.f/2048.f)+1e-5f);
  for(int i=0;i<8;i++){ int c=threadIdx.x+i*256; yb16[(size_t)r*2048+c]=f2bf(v[i]*rs*w[c]); }
}

// ---------------- scorer stage 2: sigmoid(h1 @ w2) ----------------
__global__ void k_scorer2(const float* __restrict__ h1, const float* __restrict__ w2, float* __restrict__ scores){
  int r = blockIdx.x; int lane = threadIdx.x; // 64 threads
  float s=0.f;
  for(int k=0;k<4;k++){ int c=lane+k*64; s += h1[(size_t)r*256+c]*w2[c]; }
  for(int off=32;off;off>>=1) s += __shfl_down(s,off,64);
  if(lane==0) scores[r]=sigmoidf_(s);
}

// ---------------- serial pool scan: ballot-filtered, exact semantics; + flags ----------------
__global__ void k_pool(const float* __restrict__ scores,
                       float* __restrict__ priosws, int* __restrict__ countws, int* __restrict__ winners,
                       float* __restrict__ condf){
  __shared__ float scs[BT];
  int lane = threadIdx.x;
  float ssum = 0.f;
  for(int i=lane;i<BT;i+=64){ float s0 = scores[i]; scs[i]=s0; ssum += s0; }
  __syncthreads();
  float prio = 0.f;
  int winner = -1;
  int count = 0;
  float curmin = 0.f; int curargmin = 0;    // valid once count==POOL_N
  for(int b0=0;b0<BT;b0+=64){
    float own = scs[b0+lane];
    unsigned long long mask = (count < POOL_N) ? __ballot(own > 0.5f)
                                               : __ballot(own > curmin);
    while(mask){
      int j = __ffsll(mask) - 1;
      mask &= mask - 1ull;
      float sc = __shfl(own, j, 64);
      if(count < POOL_N){
        if(lane == count){ prio = sc; winner = b0+j; }
        count++;
        if(count == POOL_N){
          float v = (lane < POOL_N)? prio : INFINITY; int idx = lane;
          for(int off=32;off;off>>=1){
            float ov = __shfl_xor(v,off,64);
            int oi = __shfl_xor(idx,off,64);
            if(ov < v || (ov==v && oi<idx)){ v=ov; idx=oi; }
          }
          curmin = v; curargmin = idx;
        }
      } else if(sc > curmin){
        if(lane == curargmin){ prio = sc; winner = b0+j; }
        float v = (lane < POOL_N)? prio : INFINITY; int idx = lane;
        for(int off=32;off;off>>=1){
          float ov = __shfl_xor(v,off,64);
          int oi = __shfl_xor(idx,off,64);
          if(ov < v || (ov==v && oi<idx)){ v=ov; idx=oi; }
        }
        curmin = v; curargmin = idx;
      }
    }
  }
  if(lane < POOL_N){ winners[lane]=winner; priosws[lane]=prio; }
  for(int off=32;off;off>>=1) ssum += __shfl_xor(ssum,off,64);
  if(lane==0){
    countws[0]=count;
    float mean = ssum*(1.f/2048.f);
    condf[0] = (mean>0.3f && count>0)? 1.f : 0.f;
  }
}

// ---------------- gather pool rows from sq (stride 128, cols 0..63) ----------------
__global__ void k_poolg(const float* __restrict__ sq, const int* __restrict__ winners, float* __restrict__ poolb){
  int p = blockIdx.x; int lane = threadIdx.x;
  int wi = winners[p];
  poolb[p*64+lane] = (wi>=0)? sq[(size_t)wi*128+lane] : 0.f;
}

// ---------------- kkT[j*64+p] = (pool @ k_w)[p][j] ----------------
__global__ void k_kk(const float* __restrict__ pool, const float* __restrict__ k_w, float* __restrict__ kkT){
  int o = blockIdx.x*256+threadIdx.x;
  if(o >= 64*POOL_N) return;
  int j = o/POOL_N, p = o%POOL_N;
  float s=0.f;
  for(int k=0;k<64;k++) s += pool[p*64+k]*k_w[k*64+j];
  kkT[j*64+p]=s;
}

// ---------------- vv = pool @ v_w (50x1024) ----------------
__global__ void k_vv(const float* __restrict__ pool, const float* __restrict__ v_w, float* __restrict__ vv){
  int o = blockIdx.x*256+threadIdx.x;
  if(o >= POOL_N*1024) return;
  int p = o>>10, d = o&1023;
  float s=0.f;
  for(int k=0;k<64;k++) s += pool[p*64+k]*v_w[(size_t)k*1024+d];
  vv[o]=s;
}

// ---------------- retrieval: softmax(q·kkT/4, masked) @ vv; q from sq cols 64..127 ----------------
__global__ __launch_bounds__(256) void k_retr(const float* __restrict__ sq, const float* __restrict__ kkT,
   const float* __restrict__ vv, const int* __restrict__ counti, float* __restrict__ retr){
  int r = blockIdx.x;
  __shared__ float qs[64];
  __shared__ float probs[64];
  int tid = threadIdx.x;
  if(tid<64) qs[tid] = sq[(size_t)r*128 + 64 + tid];
  __syncthreads();
  int count = counti[0];
  if(tid<64){
    float logit = -1e9f;
    if(tid < POOL_N && tid < count){
      float s=0.f;
      for(int k=0;k<64;k++) s += qs[k]*kkT[k*64+tid];
      logit = s*0.25f;
    }
    float m = logit;
    for(int off=32;off;off>>=1) m = fmaxf(m, __shfl_xor(m,off,64));
    float e = expf(logit-m);
    float sum = e;
    for(int off=32;off;off>>=1) sum += __shfl_xor(sum,off,64);
    probs[tid] = e/sum;
  }
  __syncthreads();
  for(int d=tid; d<1024; d+=256){
    float acc=0.f;
    for(int p=0;p<POOL_N;p++) acc += probs[p]*vv[(size_t)p*1024+d];
    retr[(size_t)r*1024+d]=acc;
  }
}

// ---------------- concat [yout, retr] -> bf16 ----------------
__global__ void k_concat(const float* __restrict__ yout, const float* __restrict__ retr, ushort* __restrict__ cc){
  int o = blockIdx.x*256+threadIdx.x; // 2048*2048
  int r = o>>11, c2 = o&2047;
  cc[o] = f2bf((c2<1024)? yout[(size_t)r*1024+c2] : retr[(size_t)r*1024+(c2-1024)]);
}

// ---------------- out = x + yout + cond*sigmoid(g)*retr ----------------
__global__ void k_final(const float* __restrict__ x, const float* __restrict__ yout, const float* __restrict__ g,
   const float* __restrict__ retr, const float* __restrict__ condf, float* __restrict__ out){
  int o = blockIdx.x*256+threadIdx.x; // 2048*1024
  float gv = sigmoidf_(g[o]);
  out[o] = x[o] + yout[o] + condf[0]*gv*retr[o];
}

static inline void gemmb(hipStream_t s, const ushort*A,const ushort*Bt,float*C,ushort*Cb,int M,int N,int K,int act){
  dim3 g((N+127)/128, M/128);
  hipLaunchKernelGGL(gemm_bf16,g,dim3(256),0,s,A,Bt,C,Cb,M,N,K,act);
}

extern "C" void kernel_launch(void* const* d_in, const int* in_sizes, int n_in,
                              void* d_out, int out_size, void* d_ws, size_t ws_size,
                              hipStream_t stream) {
  const float* x        = (const float*)d_in[0];
  const float* norm_w   = (const float*)d_in[1];
  const float* in_proj_w= (const float*)d_in[2];
  const float* conv_w   = (const float*)d_in[3];
  const float* conv_b   = (const float*)d_in[4];
  const float* dt_bias  = (const float*)d_in[5];
  const float* A_log    = (const float*)d_in[6];
  const float* Dp       = (const float*)d_in[7];
  const float* ssm_norm_w=(const float*)d_in[8];
  const float* out_proj_w=(const float*)d_in[9];
  const float* scorer_w1= (const float*)d_in[10];
  const float* scorer_w2= (const float*)d_in[11];
  const float* summ_w   = (const float*)d_in[12];
  const float* q_w      = (const float*)d_in[13];
  const float* k_w      = (const float*)d_in[14];
  const float* v_w      = (const float*)d_in[15];
  const float* gate_w   = (const float*)d_in[16];
  float* out = (float*)d_out;

  unsigned char* base = (unsigned char*)d_ws;
  size_t off = 0;
  auto FB = [&](size_t bytes)->void*{ void* p = base+off; off = (off+bytes+255)&~(size_t)255; return p; };
  float* zxb   = (float*)FB((size_t)2048*D_IN_PROJ*4);
  float* dtb   = (float*)FB((size_t)2048*32*4);
  float* xbc   = (float*)FB((size_t)2048*CONV_DIM*4);
  float* csb   = (float*)FB((size_t)256*256*4);
  float* sdA   = (float*)FB(1024);
  float* states= (float*)FB((size_t)256*8192*4);
  float* prevb = (float*)FB((size_t)256*8192*4);
  float* ybuf  = (float*)FB((size_t)2048*2048*4);
  float* yout  = (float*)FB((size_t)2048*1024*4);
  float* scores= (float*)FB(2048*4);
  float* summ  = (float*)FB((size_t)2048*64*4);
  float* qb    = (float*)FB((size_t)2048*64*4);
  float* poolb = (float*)FB(POOL_N*64*4);
  float* prios = (float*)FB(256);
  float* miscf = (float*)FB(256);
  int*   counti= (int*)FB(256);
  int*   winners=(int*)FB(256);
  unsigned char* RX = (unsigned char*)FB((size_t)4194304);
  unsigned char* W1 = (unsigned char*)FB((size_t)8978432);

  ushort* xnb   = (ushort*)RX;
  ushort* sqT   = (ushort*)RX;                 // [128][1024] bf16: summT rows 0..63, qT rows 64..127
  ushort* summT = (ushort*)RX;
  ushort* qT    = (ushort*)(RX + 131072);
  float*  h1    = (float*) (RX + 262144);
  float*  kkT   = (float*) (RX + 2359296);
  float*  vvb   = (float*) (RX + 2375680);
  ushort* inT   = (ushort*)W1;
  ushort* outT  = (ushort*)W1;
  ushort* gateT = (ushort*)(W1 + 4194304);
  ushort* sc1T  = (ushort*)(W1 + 8388608);
  float*  Gt    = yout;
  ushort* ybf   = (ushort*)prevb;
  float*  gbuf  = prevb;
  float*  retr  = states;
  ushort* ccb   = (ushort*)ybuf;
  ushort* youtb = (ushort*)((unsigned char*)ybuf + 8388608);
  float*  sq    = summ;                        // [2048][128] f32 spans summ+qb (1 MB)
  (void)qb;

  hipLaunchKernelGGL(k_transpose_cvt, dim3(137,32), dim3(256), 0, stream, in_proj_w, inT, 1024, 4384);
  k_rmsnorm_x<<<2048,256,0,stream>>>(x, norm_w, xnb);
  gemmb(stream, xnb, inT, zxb, nullptr, 2048, D_IN_PROJ, 1024, 0);
  hipLaunchKernelGGL(k_transpose_cvt, dim3(32,64), dim3(256), 0, stream, out_proj_w, outT, 2048, 1024);
  hipLaunchKernelGGL(k_transpose_cvt, dim3(32,64), dim3(256), 0, stream, gate_w, gateT, 2048, 1024);
  hipLaunchKernelGGL(k_transpose_cvt, dim3(8,32), dim3(256), 0, stream, scorer_w1, sc1T, 1024, 256);
  hipLaunchKernelGGL(k_transpose_cvt, dim3(2,32), dim3(256), 0, stream, summ_w, summT, 1024, 64);
  hipLaunchKernelGGL(k_transpose_cvt, dim3(2,32), dim3(256), 0, stream, q_w, qT, 1024, 64);
  k_dt<<<256,256,0,stream>>>(zxb, dt_bias, dtb);
  k_conv4<<<4608,256,0,stream>>>(zxb, conv_w, conv_b, xbc);
  k_gt<<<2048,256,0,stream>>>(xbc, Gt);
  k_ssd1w<<<256,512,0,stream>>>(xbc, dtb, A_log, Gt, ybuf, states, csb, sdA);
  k_ssd2<<<2048,256,0,stream>>>(states, sdA, prevb);
  k_ssd3m<<<256,256,0,stream>>>(xbc, csb, prevb, Dp, ybuf);
  k_gate_norm<<<2048,256,0,stream>>>(ybuf, zxb, ssm_norm_w, ybf);
  gemmb(stream, ybf, outT, yout, youtb, 2048, 1024, 2048, 0);
  gemmb(stream, youtb, sc1T, h1, nullptr, 2048, 256, 1024, 1);
  k_scorer2<<<2048,64,0,stream>>>(h1, scorer_w2, scores);
  gemmb(stream, youtb, sqT, sq, nullptr, 2048, 128, 1024, 0);
  k_pool<<<1,64,0,stream>>>(scores, prios, counti, winners, miscf);
  k_poolg<<<POOL_N,64,0,stream>>>(sq, winners, poolb);
  k_kk<<<(64*POOL_N+255)/256,256,0,stream>>>(poolb, k_w, kkT);
  k_vv<<<(POOL_N*1024+255)/256,256,0,stream>>>(poolb, v_w, vvb);
  k_retr<<<2048,256,0,stream>>>(sq, kkT, vvb, counti, retr);
  k_concat<<<16384,256,0,stream>>>(yout, retr, ccb);
  gemmb(stream, ccb, gateT, gbuf, nullptr, 2048, 1024, 2048, 0);
  k_final<<<8192,256,0,stream>>>(x, yout, gbuf, retr, miscf, out);
  (void)in_sizes; (void)n_in; (void)out_size; (void)ws_size;
}

// Round 9
// 388.917 us; speedup vs baseline: 6.2326x; 1.2269x over previous
//
#include <hip/hip_runtime.h>
#include <math.h>

#define NHEADS 32
#define D_INNER 2048
#define CONV_DIM 2304
#define D_IN_PROJ 4384
#define POOL_N 50
#define BT 2048

typedef __attribute__((ext_vector_type(8))) short short8;
typedef __attribute__((ext_vector_type(4))) float f32x4;

__device__ __forceinline__ float sigmoidf_(float x){ return 1.f/(1.f+expf(-x)); }
__device__ __forceinline__ ushort f2bf(float f){
  union{float f; unsigned u;} v; v.f=f;
  unsigned r = v.u + 0x7fffu + ((v.u>>16)&1u);
  return (ushort)(r>>16);
}
__device__ __forceinline__ void gload16(const void* g, void* l){
  __builtin_amdgcn_global_load_lds(
    (const __attribute__((address_space(1))) unsigned int*)g,
    (__attribute__((address_space(3))) unsigned int*)l, 16, 0, 0);
}

// ---------------- RMSNorm on x (D=1024) -> bf16 ----------------
__global__ __launch_bounds__(256) void k_rmsnorm_x(const float* __restrict__ x, const float* __restrict__ w, ushort* __restrict__ xn){
  int r = blockIdx.x;
  const float* xr = x + (size_t)r*1024;
  float v[4]; float ss=0.f;
  for(int i=0;i<4;i++){ v[i]=xr[threadIdx.x+i*256]; ss+=v[i]*v[i]; }
  __shared__ float red[4];
  for(int off=32;off;off>>=1) ss += __shfl_down(ss,off,64);
  int wid=threadIdx.x>>6, lane=threadIdx.x&63;
  if(lane==0) red[wid]=ss;
  __syncthreads();
  float tot=red[0]+red[1]+red[2]+red[3];
  float rs=rsqrtf(tot*(1.f/1024.f)+1e-5f);
  for(int i=0;i<4;i++){ int c=threadIdx.x+i*256; xn[(size_t)r*1024+c]=f2bf(v[i]*rs*w[c]); }
}

// ---------------- transpose + cvt: src f32 [R][C] -> dst bf16 [C][R] ----------------
__global__ __launch_bounds__(256) void k_transpose_cvt(const float* __restrict__ src, ushort* __restrict__ dst, int R, int C){
  __shared__ float tile[32][33];
  int c0 = blockIdx.x*32, r0 = blockIdx.y*32;
  int tx = threadIdx.x&31, ty = threadIdx.x>>5;
  for(int i=0;i<4;i++){ int r = r0+ty+i*8; tile[ty+i*8][tx] = src[(size_t)r*C + c0+tx]; }
  __syncthreads();
  for(int i=0;i<4;i++){ int c = c0+ty+i*8; dst[(size_t)c*R + r0+tx] = f2bf(tile[tx][ty+i*8]); }
}

// ---------------- bf16 MFMA GEMM: C[M,N] f32 = A[M,K]bf16 @ Bt[N,K]bf16^T ----------------
// global_load_lds width-16 staging; XCD-aware swizzle when grid%8==0; 1-D grid (nbx * M/128).
__global__ __launch_bounds__(256) void gemm_bf16(const ushort* __restrict__ A, const ushort* __restrict__ Bt,
    float* __restrict__ C, ushort* __restrict__ Cb, int M, int N, int K, int act, int nbx){
  __shared__ __align__(16) ushort As[128*32];
  __shared__ __align__(16) ushort Bs[128*32];
  int wg = blockIdx.x, nwg = gridDim.x;
  if((nwg & 7)==0){ int cpx = nwg>>3; wg = (wg&7)*cpx + (wg>>3); }
  int bx = wg % nbx, by = wg / nbx;
  int n0 = bx*128, m0 = by*128;
  int tid = threadIdx.x;
  int lane = tid&63, w = tid>>6;
  int wr = (w>>1)*64, wc = (w&1)*64;
  f32x4 acc[4][4];
  for(int i=0;i<4;i++)for(int j=0;j<4;j++)acc[i][j]=(f32x4){0.f,0.f,0.f,0.f};
  int srow0 = w*32 + (lane>>2);
  int sbyte = (lane&3)*16;
  const char* AG0 = (const char*)(A + (size_t)(m0+srow0)*K) + sbyte;
  const char* AG1 = (const char*)(A + (size_t)(m0+srow0+16)*K) + sbyte;
  int brow0 = n0+srow0, brow1 = n0+srow0+16;
  bool bv0 = brow0 < N, bv1 = brow1 < N;
  const char* BG0 = (const char*)(Bt + (size_t)(bv0?brow0:0)*K) + sbyte;
  const char* BG1 = (const char*)(Bt + (size_t)(bv1?brow1:0)*K) + sbyte;
  char* Al0 = (char*)As + w*2048; char* Al1 = Al0 + 1024;
  char* Bl0 = (char*)Bs + w*2048; char* Bl1 = Bl0 + 1024;
  int fr = lane&15, fko = (lane>>4)*8;
  for(int k0=0;k0<K;k0+=32){
    gload16(AG0 + (size_t)k0*2, Al0);
    gload16(AG1 + (size_t)k0*2, Al1);
    if(bv0) gload16(BG0 + (size_t)k0*2, Bl0);
    if(bv1) gload16(BG1 + (size_t)k0*2, Bl1);
    __syncthreads();
    short8 af[4], bfr[4];
    for(int i=0;i<4;i++) af[i]  = *(const short8*)(As + (wr+i*16+fr)*32 + fko);
    for(int j=0;j<4;j++) bfr[j] = *(const short8*)(Bs + (wc+j*16+fr)*32 + fko);
    for(int i=0;i<4;i++)
      for(int j=0;j<4;j++)
        acc[i][j] = __builtin_amdgcn_mfma_f32_16x16x32_bf16(af[i], bfr[j], acc[i][j], 0,0,0);
    __syncthreads();
  }
  int rbase = m0 + wr + (lane>>4)*4;
  for(int i=0;i<4;i++){
    for(int j=0;j<4;j++){
      int col = n0 + wc + j*16 + fr;
      if(col < N){
        for(int r=0;r<4;r++){
          float v = acc[i][j][r];
          if(act) v = fmaxf(v,0.f);
          size_t idx = (size_t)(rbase + i*16 + r)*N + col;
          C[idx] = v;
          if(Cb) Cb[idx] = f2bf(v);
        }
      }
    }
  }
}

// ---------------- dt = softplus(zxb[:, -32:] + bias) ----------------
__global__ void k_dt(const float* __restrict__ zxb, const float* __restrict__ dt_bias, float* __restrict__ dtb){
  int o = blockIdx.x*256+threadIdx.x; // 2048*32
  int r = o>>5, h = o&31;
  float v = zxb[(size_t)r*D_IN_PROJ + 4352 + h] + dt_bias[h];
  dtb[o] = (v>20.f) ? v : log1pf(expf(v));
}

// ---------------- causal depthwise conv (k=4) + silu, 4 channels/thread ----------------
__global__ void k_conv4(const float* __restrict__ zxb, const float* __restrict__ cw, const float* __restrict__ cb, float* __restrict__ xbc){
  int o = blockIdx.x*256+threadIdx.x; // 2048*576
  if(o >= 2048*576) return;
  int ch4 = (o % 576)*4; int rt = o / 576;
  int b = rt>>10, t = rt&1023;
  float a[4];
  { float4 cbv = *(const float4*)(cb + ch4); a[0]=cbv.x; a[1]=cbv.y; a[2]=cbv.z; a[3]=cbv.w; }
  float cwa[4][4];
  for(int c2=0;c2<4;c2++){
    float4 v = *(const float4*)(cw + (ch4+c2)*4);
    cwa[c2][0]=v.x; cwa[c2][1]=v.y; cwa[c2][2]=v.z; cwa[c2][3]=v.w;
  }
  for(int k=0;k<4;k++){
    int tt = t-3+k;
    if(tt>=0){
      float4 v = *(const float4*)(zxb + (size_t)(b*1024+tt)*D_IN_PROJ + 2048 + ch4);
      a[0] += v.x*cwa[0][k]; a[1] += v.y*cwa[1][k];
      a[2] += v.z*cwa[2][k]; a[3] += v.w*cwa[3][k];
    }
  }
  float4 o4;
  o4.x = a[0]*sigmoidf_(a[0]); o4.y = a[1]*sigmoidf_(a[1]);
  o4.z = a[2]*sigmoidf_(a[2]); o4.w = a[3]*sigmoidf_(a[3]);
  *(float4*)(xbc + (size_t)rt*CONV_DIM + ch4) = o4;
}

// ---------------- G^T per (b,c): Gt[s*256+l] = dot(C[l], B[s]) ----------------
__global__ __launch_bounds__(256) void k_gt(const float* __restrict__ xbc, float* __restrict__ Gt){
  int bc = blockIdx.x >> 8;
  int tile = blockIdx.x & 255;
  int l0 = (tile>>4)<<4, s0 = (tile&15)<<4;
  int b = bc>>2, c = bc&3;
  int row0 = b*1024 + c*256;
  __shared__ float Cs[16][130], Bs2[16][130];
  int tid = threadIdx.x;
  for(int i=0;i<8;i++){ int e=tid+i*256; int rr=e>>7, n=e&127;
    Cs[rr][n]  = xbc[(size_t)(row0+l0+rr)*CONV_DIM + 2176 + n];
    Bs2[rr][n] = xbc[(size_t)(row0+s0+rr)*CONV_DIM + 2048 + n];
  }
  __syncthreads();
  int tx = tid&15, ty = tid>>4;
  float acc=0.f;
  for(int n=0;n<128;n++) acc += Cs[tx][n]*Bs2[ty][n];
  Gt[(size_t)bc*65536 + (size_t)(s0+ty)*256 + (l0+tx)] = acc;
}

// ---------------- SSD per (b,c,h): 512 threads, wave-specialized ----------------
__global__ __launch_bounds__(512) void k_ssd1w(const float* __restrict__ xbc, const float* __restrict__ dtb,
    const float* __restrict__ A_log, const float* __restrict__ Gt,
    float* __restrict__ ybuf, float* __restrict__ states, float* __restrict__ csb, float* __restrict__ sdA){
  int blk = blockIdx.x;      // (b*4+c)*32+h
  int bc = blk>>5, h = blk&31;
  int b = bc>>2, c = bc&3;
  int row0 = b*1024 + c*256;
  int tid = threadIdx.x;
  __shared__ float cs[256];
  __shared__ float dts[256];
  __shared__ float dec[256];
  __shared__ __align__(16) ushort xdT[64*256];
  __shared__ __align__(16) ushort Mw[4*64*32];
  __shared__ __align__(16) ushort Bw[4*32*256];
  float Ah = -expf(A_log[h]);
  if(tid < 256){
    float dtv = dtb[(size_t)(row0+tid)*32 + h];
    dts[tid] = dtv;
    cs[tid] = dtv*Ah;
  }
  __syncthreads();
  for(int o=1;o<256;o<<=1){
    float add = 0.f;
    if(tid<256 && tid>=o) add = cs[tid-o];
    __syncthreads();
    if(tid<256) cs[tid] += add;
    __syncthreads();
  }
  float cslast = cs[255];
  if(tid < 256){
    float csl = cs[tid];
    csb[blk*256+tid] = csl;
    dec[tid] = expf(cslast - csl);
    if(tid==0) sdA[blk] = cslast;
  }
  {
    int p = tid&63, g = tid>>6;
    for(int i=0;i<32;i++){
      int l = g + 8*i;
      float v = xbc[(size_t)(row0+l)*CONV_DIM + h*64 + p] * dts[l];
      int off = ((p<<9) + (l<<1)) ^ ((p&7)<<4);
      *(ushort*)((char*)xdT + off) = f2bf(v);
    }
  }
  __syncthreads();

  int w = tid>>6, lane = tid&63;
  int fr = lane&15, fq = lane>>4;
  const float* gt = Gt + (size_t)bc*65536;
  if(w < 4){
    int rowl = w*64 + lane;
    float csl_w = cs[rowl];
    f32x4 accY[4][4];
    for(int i=0;i<4;i++)for(int j=0;j<4;j++)accY[i][j]=(f32x4){0.f,0.f,0.f,0.f};
    int nk = 2*(w+1);
    for(int ks=0; ks<nk; ks++){
      int s0 = ks*32;
      float cs_s0 = cs[s0];
      float ev = expf(cs_s0 - cs[s0 + (lane&31)]);
      float el = expf(csl_w - cs_s0);
      for(int j=0;j<4;j++){
        short8 mp;
        for(int k=0;k<8;k++){
          int s2 = j*8+k;
          int s = s0 + s2;
          float gv = gt[(size_t)s*256 + rowl];
          float esv = __shfl(ev, s2, 64);
          float m = (s <= rowl) ? gv*el*esv : 0.f;
          mp[k] = (short)f2bf(m);
        }
        int off = (w<<12) + ((((lane)<<6) + (j<<4)) ^ ((lane&7)<<4));
        *(short8*)((char*)Mw + off) = mp;
      }
      asm volatile("s_waitcnt lgkmcnt(0)" ::: "memory");
      __builtin_amdgcn_sched_barrier(0);
      short8 af[4], bv4[4];
      for(int i=0;i<4;i++){
        int lp = i*16 + fr;
        int off = (w<<12) + (((lp<<6) + (fq<<4)) ^ ((lp&7)<<4));
        af[i] = *(const short8*)((char*)Mw + off);
      }
      for(int j=0;j<4;j++){
        int p = j*16 + fr;
        int off = ((p<<9) + ((s0 + fq*8)<<1)) ^ ((p&7)<<4);
        bv4[j] = *(const short8*)((char*)xdT + off);
      }
      for(int i=0;i<4;i++)
        for(int j=0;j<4;j++)
          accY[i][j] = __builtin_amdgcn_mfma_f32_16x16x32_bf16(af[i], bv4[j], accY[i][j], 0,0,0);
      asm volatile("" ::: "memory");
    }
    for(int i=0;i<4;i++){
      int l = 64*w + i*16 + fq*4;
      for(int j=0;j<4;j++){
        int p = j*16 + fr;
        for(int r=0;r<4;r++)
          ybuf[(size_t)(row0+l+r)*2048 + h*64 + p] = accY[i][j][r];
      }
    }
  } else {
    int sw = w-4, nbase = sw*32;
    {
      int nn = lane&31, half = lane>>5;
      for(int i=0;i<128;i++){
        int l = half + 2*i;
        float v = xbc[(size_t)(row0+l)*CONV_DIM + 2048 + nbase + nn] * dec[l];
        int off = (sw<<14) + (((nn<<9) + (l<<1)) ^ ((nn&7)<<4));
        *(ushort*)((char*)Bw + off) = f2bf(v);
      }
    }
    asm volatile("s_waitcnt lgkmcnt(0)" ::: "memory");
    __builtin_amdgcn_sched_barrier(0);
    f32x4 accS[4][2];
    for(int i=0;i<4;i++)for(int j=0;j<2;j++)accS[i][j]=(f32x4){0.f,0.f,0.f,0.f};
    for(int ks=0;ks<8;ks++){
      int l0 = ks*32;
      short8 aS[4], bS[2];
      for(int i=0;i<4;i++){
        int p = i*16 + fr;
        int off = ((p<<9) + ((l0+fq*8)<<1)) ^ ((p&7)<<4);
        aS[i] = *(const short8*)((char*)xdT + off);
      }
      for(int j=0;j<2;j++){
        int nn = j*16 + fr;
        int off = (sw<<14) + (((nn<<9) + ((l0+fq*8)<<1)) ^ ((nn&7)<<4));
        bS[j] = *(const short8*)((char*)Bw + off);
      }
      for(int i=0;i<4;i++)
        for(int j=0;j<2;j++)
          accS[i][j] = __builtin_amdgcn_mfma_f32_16x16x32_bf16(aS[i], bS[j], accS[i][j], 0,0,0);
    }
    for(int i=0;i<4;i++){
      int p = i*16 + fq*4;
      for(int j=0;j<2;j++){
        int n = nbase + j*16 + fr;
        for(int r=0;r<4;r++)
          states[(size_t)blk*8192 + (size_t)(p+r)*128 + n] = accS[i][j][r];
      }
    }
  }
}

// ---------------- chunk scan over c=0..3 ----------------
__global__ __launch_bounds__(256) void k_ssd2(const float* __restrict__ states, const float* __restrict__ sdA, float* __restrict__ prevb){
  int idx = blockIdx.x*256 + threadIdx.x;
  int e = idx & 8191;
  int h = (idx >> 13) & 31;
  int b = idx >> 18;
  float run = 0.f;
  for(int c=0;c<4;c++){
    int sblk = (b*4+c)*32 + h;
    size_t base = (size_t)sblk*8192 + e;
    prevb[base] = run;
    run = (run + states[base]) * expf(sdA[sblk]);
  }
}

// ---------------- y_off = C @ prev^T via MFMA; += xs*D into ybuf ----------------
__global__ __launch_bounds__(256) void k_ssd3m(const float* __restrict__ xbc, const float* __restrict__ csb,
    const float* __restrict__ prevb, const float* __restrict__ Dp, float* __restrict__ ybuf){
  int blk = blockIdx.x; int bc = blk>>5, h = blk&31; int b=bc>>2, c=bc&3;
  int row0 = b*1024+c*256;
  int tid = threadIdx.x;
  __shared__ __align__(16) ushort Cs[256*128];
  __shared__ __align__(16) ushort Ps[64*128];
  __shared__ float cse[256];
  for(int i=0;i<128;i++){
    int id = tid + i*256;
    int n = id & 127, l = id >> 7;
    float v = xbc[(size_t)(row0+l)*CONV_DIM + 2176 + n];
    int off = ((l<<8) + (n<<1)) ^ ((l&7)<<4);
    *(ushort*)((char*)Cs + off) = f2bf(v);
  }
  for(int i=0;i<32;i++){
    int id = tid + i*256;
    int n = id & 127, p = id >> 7;
    float v = prevb[(size_t)blk*8192 + id];
    int off = ((p<<8) + (n<<1)) ^ ((p&7)<<4);
    *(ushort*)((char*)Ps + off) = f2bf(v);
  }
  cse[tid] = expf(csb[blk*256+tid]);
  __syncthreads();
  int w=tid>>6, lane=tid&63, fr=lane&15, fq=lane>>4;
  f32x4 acc[4][4];
  for(int i=0;i<4;i++)for(int j=0;j<4;j++)acc[i][j]=(f32x4){0.f,0.f,0.f,0.f};
  for(int ks=0;ks<4;ks++){
    int n0 = ks*32;
    short8 af[4], bf_[4];
    for(int i=0;i<4;i++){
      int l = w*64 + i*16 + fr;
      int off = ((l<<8) + ((n0+fq*8)<<1)) ^ ((l&7)<<4);
      af[i] = *(const short8*)((char*)Cs + off);
    }
    for(int j=0;j<4;j++){
      int p = j*16 + fr;
      int off = ((p<<8) + ((n0+fq*8)<<1)) ^ ((p&7)<<4);
      bf_[j] = *(const short8*)((char*)Ps + off);
    }
    for(int i=0;i<4;i++)
      for(int j=0;j<4;j++)
        acc[i][j] = __builtin_amdgcn_mfma_f32_16x16x32_bf16(af[i], bf_[j], acc[i][j], 0,0,0);
  }
  float Dh = Dp[h];
  for(int i=0;i<4;i++){
    int lbase = 64*w + i*16 + fq*4;
    for(int r=0;r<4;r++){
      int l = lbase + r;
      float e = cse[l];
      size_t rowoff = (size_t)(row0+l)*CONV_DIM + h*64;
      size_t yb = (size_t)(row0+l)*2048 + h*64;
      for(int j=0;j<4;j++){
        int p = j*16 + fr;
        float xs = xbc[rowoff + p];
        ybuf[yb+p] += e*acc[i][j][r] + xs*Dh;
      }
    }
  }
}

// ---------------- y = rmsnorm(y * silu(z)) -> bf16 (D=2048) ----------------
__global__ __launch_bounds__(256) void k_gate_norm(const float* __restrict__ y, const float* __restrict__ zxb,
    const float* __restrict__ w, ushort* __restrict__ yb16){
  int r = blockIdx.x;
  const float* zr = zxb + (size_t)r*D_IN_PROJ;
  const float* yr = y + (size_t)r*2048;
  float v[8]; float ss=0.f;
  for(int i=0;i<8;i++){ int c=threadIdx.x+i*256; float z=zr[c]; float g=yr[c]*(z*sigmoidf_(z)); v[i]=g; ss+=g*g; }
  __shared__ float red[4];
  for(int off=32;off;off>>=1) ss += __shfl_down(ss,off,64);
  int wid=threadIdx.x>>6, lane=threadIdx.x&63;
  if(lane==0) red[wid]=ss;
  __syncthreads();
  float tot=red[0]+red[1]+red[2]+red[3];
  float rs=rsqrtf(tot*(1.f/2048.f)+1e-5f);
  for(int i=0;i<8;i++){ int c=threadIdx.x+i*256; yb16[(size_t)r*2048+c]=f2bf(v[i]*rs*w[c]); }
}

// ---------------- scorer stage 2: sigmoid(h1 @ w2) ----------------
__global__ void k_scorer2(const float* __restrict__ h1, const float* __restrict__ w2, float* __restrict__ scores){
  int r = blockIdx.x; int lane = threadIdx.x; // 64 threads
  float s=0.f;
  for(int k=0;k<4;k++){ int c=lane+k*64; s += h1[(size_t)r*256+c]*w2[c]; }
  for(int off=32;off;off>>=1) s += __shfl_down(s,off,64);
  if(lane==0) scores[r]=sigmoidf_(s);
}

// ---------------- pool: parallel top-50 via float-bit bisection; exact-seq fallback on boundary tie ----------------
__global__ void k_pool(const float* __restrict__ scores,
                       int* __restrict__ countws, int* __restrict__ winners, float* __restrict__ condf){
  __shared__ float scs[BT];
  int lane = threadIdx.x;  // 64 threads
  float own[32];
  float ssum = 0.f; int vcnt = 0;
  #pragma unroll
  for(int i=0;i<32;i++){
    float s0 = scores[i*64 + lane];
    own[i] = s0; scs[i*64+lane] = s0;
    ssum += s0; vcnt += (s0 > 0.5f) ? 1 : 0;
  }
  float ts = ssum; int tv = vcnt;
  for(int off=32;off;off>>=1){ ts += __shfl_xor(ts,off,64); tv += __shfl_xor(tv,off,64); }
  int count = tv < POOL_N ? tv : POOL_N;
  bool fallback = false;
  if(tv <= POOL_N){
    int base = 0;
    #pragma unroll
    for(int i=0;i<32;i++){
      bool sel = own[i] > 0.5f;
      unsigned long long mask = __ballot(sel);
      int pre = __popcll(mask & ((1ull<<lane)-1ull));
      if(sel) winners[base + pre] = i*64 + lane;
      base += __popcll(mask);
    }
    for(int r=base+lane; r<POOL_N; r+=64) winners[r] = -1;
  } else {
    unsigned lo = 0u, hi = 0x3F800000u;   // scores in (0,1): positive-float bits order = value order
    while(hi - lo > 1u){
      unsigned mid = (lo + hi) >> 1;
      float midf = __uint_as_float(mid);
      int cnt = 0;
      #pragma unroll
      for(int i=0;i<32;i++) cnt += (own[i] >= midf) ? 1 : 0;
      for(int off=32;off;off>>=1) cnt += __shfl_xor(cnt,off,64);
      if(cnt >= POOL_N) lo = mid; else hi = mid;
    }
    float v50 = __uint_as_float(lo);
    int cl = 0;
    #pragma unroll
    for(int i=0;i<32;i++) cl += (own[i] >= v50) ? 1 : 0;
    for(int off=32;off;off>>=1) cl += __shfl_xor(cl,off,64);
    if(cl == POOL_N){
      int base = 0;
      #pragma unroll
      for(int i=0;i<32;i++){
        bool sel = own[i] >= v50;
        unsigned long long mask = __ballot(sel);
        int pre = __popcll(mask & ((1ull<<lane)-1ull));
        if(sel) winners[base + pre] = i*64 + lane;
        base += __popcll(mask);
      }
    } else fallback = true;
  }
  if(fallback){
    float prio = 0.f; int winner = -1; int cnt2 = 0;
    float curmin = 0.f; int curargmin = 0;
    for(int b0=0;b0<BT;b0+=64){
      float ow = scs[b0+lane];
      unsigned long long mask = (cnt2 < POOL_N) ? __ballot(ow > 0.5f) : __ballot(ow > curmin);
      while(mask){
        int j = __ffsll(mask) - 1;
        mask &= mask - 1ull;
        float sc = __shfl(ow, j, 64);
        if(cnt2 < POOL_N){
          if(lane == cnt2){ prio = sc; winner = b0+j; }
          cnt2++;
          if(cnt2 == POOL_N){
            float v = (lane < POOL_N)? prio : INFINITY; int idx = lane;
            for(int off=32;off;off>>=1){
              float ov = __shfl_xor(v,off,64); int oi = __shfl_xor(idx,off,64);
              if(ov < v || (ov==v && oi<idx)){ v=ov; idx=oi; }
            }
            curmin = v; curargmin = idx;
          }
        } else if(sc > curmin){
          if(lane == curargmin){ prio = sc; winner = b0+j; }
          float v = (lane < POOL_N)? prio : INFINITY; int idx = lane;
          for(int off=32;off;off>>=1){
            float ov = __shfl_xor(v,off,64); int oi = __shfl_xor(idx,off,64);
            if(ov < v || (ov==v && oi<idx)){ v=ov; idx=oi; }
          }
          curmin = v; curargmin = idx;
        }
      }
    }
    if(lane < POOL_N) winners[lane] = winner;
  }
  if(lane==0){
    countws[0] = count;
    float mean = ts*(1.f/2048.f);
    condf[0] = (mean>0.3f && count>0)? 1.f : 0.f;
  }
}

// ---------------- gather pool rows from sq (stride 128, cols 0..63) ----------------
__global__ void k_poolg(const float* __restrict__ sq, const int* __restrict__ winners, float* __restrict__ poolb){
  int p = blockIdx.x; int lane = threadIdx.x;
  int wi = winners[p];
  poolb[p*64+lane] = (wi>=0)? sq[(size_t)wi*128+lane] : 0.f;
}

// ---------------- kkT[j*64+p] = (pool @ k_w)[p][j] ----------------
__global__ void k_kk(const float* __restrict__ pool, const float* __restrict__ k_w, float* __restrict__ kkT){
  int o = blockIdx.x*256+threadIdx.x;
  if(o >= 64*POOL_N) return;
  int j = o/POOL_N, p = o%POOL_N;
  float s=0.f;
  for(int k=0;k<64;k++) s += pool[p*64+k]*k_w[k*64+j];
  kkT[j*64+p]=s;
}

// ---------------- vv = pool @ v_w (50x1024) ----------------
__global__ void k_vv(const float* __restrict__ pool, const float* __restrict__ v_w, float* __restrict__ vv){
  int o = blockIdx.x*256+threadIdx.x;
  if(o >= POOL_N*1024) return;
  int p = o>>10, d = o&1023;
  float s=0.f;
  for(int k=0;k<64;k++) s += pool[p*64+k]*v_w[(size_t)k*1024+d];
  vv[o]=s;
}

// ---------------- retrieval ----------------
__global__ __launch_bounds__(256) void k_retr(const float* __restrict__ sq, const float* __restrict__ kkT,
   const float* __restrict__ vv, const int* __restrict__ counti, float* __restrict__ retr){
  int r = blockIdx.x;
  __shared__ float qs[64];
  __shared__ float probs[64];
  int tid = threadIdx.x;
  if(tid<64) qs[tid] = sq[(size_t)r*128 + 64 + tid];
  __syncthreads();
  int count = counti[0];
  if(tid<64){
    float logit = -1e9f;
    if(tid < POOL_N && tid < count){
      float s=0.f;
      for(int k=0;k<64;k++) s += qs[k]*kkT[k*64+tid];
      logit = s*0.25f;
    }
    float m = logit;
    for(int off=32;off;off>>=1) m = fmaxf(m, __shfl_xor(m,off,64));
    float e = expf(logit-m);
    float sum = e;
    for(int off=32;off;off>>=1) sum += __shfl_xor(sum,off,64);
    probs[tid] = e/sum;
  }
  __syncthreads();
  for(int d=tid; d<1024; d+=256){
    float acc=0.f;
    for(int p=0;p<POOL_N;p++) acc += probs[p]*vv[(size_t)p*1024+d];
    retr[(size_t)r*1024+d]=acc;
  }
}

// ---------------- concat [yout, retr] -> bf16 ----------------
__global__ void k_concat(const float* __restrict__ yout, const float* __restrict__ retr, ushort* __restrict__ cc){
  int o = blockIdx.x*256+threadIdx.x; // 2048*2048
  int r = o>>11, c2 = o&2047;
  cc[o] = f2bf((c2<1024)? yout[(size_t)r*1024+c2] : retr[(size_t)r*1024+(c2-1024)]);
}

// ---------------- out = x + yout + cond*sigmoid(g)*retr ----------------
__global__ void k_final(const float* __restrict__ x, const float* __restrict__ yout, const float* __restrict__ g,
   const float* __restrict__ retr, const float* __restrict__ condf, float* __restrict__ out){
  int o = blockIdx.x*256+threadIdx.x; // 2048*1024
  float gv = sigmoidf_(g[o]);
  out[o] = x[o] + yout[o] + condf[0]*gv*retr[o];
}

static inline void gemmb(hipStream_t s, const ushort*A,const ushort*Bt,float*C,ushort*Cb,int M,int N,int K,int act){
  int nbx = (N+127)/128;
  int nwg = nbx * (M/128);
  hipLaunchKernelGGL(gemm_bf16,dim3(nwg),dim3(256),0,s,A,Bt,C,Cb,M,N,K,act,nbx);
}

extern "C" void kernel_launch(void* const* d_in, const int* in_sizes, int n_in,
                              void* d_out, int out_size, void* d_ws, size_t ws_size,
                              hipStream_t stream) {
  const float* x        = (const float*)d_in[0];
  const float* norm_w   = (const float*)d_in[1];
  const float* in_proj_w= (const float*)d_in[2];
  const float* conv_w   = (const float*)d_in[3];
  const float* conv_b   = (const float*)d_in[4];
  const float* dt_bias  = (const float*)d_in[5];
  const float* A_log    = (const float*)d_in[6];
  const float* Dp       = (const float*)d_in[7];
  const float* ssm_norm_w=(const float*)d_in[8];
  const float* out_proj_w=(const float*)d_in[9];
  const float* scorer_w1= (const float*)d_in[10];
  const float* scorer_w2= (const float*)d_in[11];
  const float* summ_w   = (const float*)d_in[12];
  const float* q_w      = (const float*)d_in[13];
  const float* k_w      = (const float*)d_in[14];
  const float* v_w      = (const float*)d_in[15];
  const float* gate_w   = (const float*)d_in[16];
  float* out = (float*)d_out;

  unsigned char* base = (unsigned char*)d_ws;
  size_t off = 0;
  auto FB = [&](size_t bytes)->void*{ void* p = base+off; off = (off+bytes+255)&~(size_t)255; return p; };
  float* zxb   = (float*)FB((size_t)2048*D_IN_PROJ*4);
  float* dtb   = (float*)FB((size_t)2048*32*4);
  float* xbc   = (float*)FB((size_t)2048*CONV_DIM*4);
  float* csb   = (float*)FB((size_t)256*256*4);
  float* sdA   = (float*)FB(1024);
  float* states= (float*)FB((size_t)256*8192*4);
  float* prevb = (float*)FB((size_t)256*8192*4);
  float* ybuf  = (float*)FB((size_t)2048*2048*4);
  float* yout  = (float*)FB((size_t)2048*1024*4);
  float* scores= (float*)FB(2048*4);
  float* summ  = (float*)FB((size_t)2048*64*4);
  float* qb    = (float*)FB((size_t)2048*64*4);
  float* poolb = (float*)FB(POOL_N*64*4);
  float* prios = (float*)FB(256);
  float* miscf = (float*)FB(256);
  int*   counti= (int*)FB(256);
  int*   winners=(int*)FB(256);
  unsigned char* RX = (unsigned char*)FB((size_t)4194304);
  unsigned char* W1 = (unsigned char*)FB((size_t)8978432);

  ushort* xnb   = (ushort*)RX;
  ushort* sqT   = (ushort*)RX;
  ushort* summT = (ushort*)RX;
  ushort* qT    = (ushort*)(RX + 131072);
  float*  h1    = (float*) (RX + 262144);
  float*  kkT   = (float*) (RX + 2359296);
  float*  vvb   = (float*) (RX + 2375680);
  ushort* inT   = (ushort*)W1;
  ushort* outT  = (ushort*)W1;
  ushort* gateT = (ushort*)(W1 + 4194304);
  ushort* sc1T  = (ushort*)(W1 + 8388608);
  float*  Gt    = yout;
  ushort* ybf   = (ushort*)prevb;
  float*  gbuf  = prevb;
  float*  retr  = states;
  ushort* ccb   = (ushort*)ybuf;
  ushort* youtb = (ushort*)((unsigned char*)ybuf + 8388608);
  float*  sq    = summ;
  (void)qb; (void)prios;

  hipLaunchKernelGGL(k_transpose_cvt, dim3(137,32), dim3(256), 0, stream, in_proj_w, inT, 1024, 4384);
  k_rmsnorm_x<<<2048,256,0,stream>>>(x, norm_w, xnb);
  gemmb(stream, xnb, inT, zxb, nullptr, 2048, D_IN_PROJ, 1024, 0);
  hipLaunchKernelGGL(k_transpose_cvt, dim3(32,64), dim3(256), 0, stream, out_proj_w, outT, 2048, 1024);
  hipLaunchKernelGGL(k_transpose_cvt, dim3(32,64), dim3(256), 0, stream, gate_w, gateT, 2048, 1024);
  hipLaunchKernelGGL(k_transpose_cvt, dim3(8,32), dim3(256), 0, stream, scorer_w1, sc1T, 1024, 256);
  hipLaunchKernelGGL(k_transpose_cvt, dim3(2,32), dim3(256), 0, stream, summ_w, summT, 1024, 64);
  hipLaunchKernelGGL(k_transpose_cvt, dim3(2,32), dim3(256), 0, stream, q_w, qT, 1024, 64);
  k_dt<<<256,256,0,stream>>>(zxb, dt_bias, dtb);
  k_conv4<<<4608,256,0,stream>>>(zxb, conv_w, conv_b, xbc);
  k_gt<<<2048,256,0,stream>>>(xbc, Gt);
  k_ssd1w<<<256,512,0,stream>>>(xbc, dtb, A_log, Gt, ybuf, states, csb, sdA);
  k_ssd2<<<2048,256,0,stream>>>(states, sdA, prevb);
  k_ssd3m<<<256,256,0,stream>>>(xbc, csb, prevb, Dp, ybuf);
  k_gate_norm<<<2048,256,0,stream>>>(ybuf, zxb, ssm_norm_w, ybf);
  gemmb(stream, ybf, outT, yout, youtb, 2048, 1024, 2048, 0);
  gemmb(stream, youtb, sc1T, h1, nullptr, 2048, 256, 1024, 1);
  k_scorer2<<<2048,64,0,stream>>>(h1, scorer_w2, scores);
  gemmb(stream, youtb, sqT, sq, nullptr, 2048, 128, 1024, 0);
  k_pool<<<1,64,0,stream>>>(scores, counti, winners, miscf);
  k_poolg<<<POOL_N,64,0,stream>>>(sq, winners, poolb);
  k_kk<<<(64*POOL_N+255)/256,256,0,stream>>>(poolb, k_w, kkT);
  k_vv<<<(POOL_N*1024+255)/256,256,0,stream>>>(poolb, v_w, vvb);
  k_retr<<<2048,256,0,stream>>>(sq, kkT, vvb, counti, retr);
  k_concat<<<16384,256,0,stream>>>(yout, retr, ccb);
  gemmb(stream, ccb, gateT, gbuf, nullptr, 2048, 1024, 2048, 0);
  k_final<<<8192,256,0,stream>>>(x, yout, gbuf, retr, miscf, out);
  (void)in_sizes; (void)n_in; (void)out_size; (void)ws_size;
}